// Round 9
// baseline (996.279 us; speedup 1.0000x reference)
//
#include <hip/hip_runtime.h>
#include <math.h>

#define BB 2
#define CDIM 256
#define NQ 4096   // 16*16*16
#define NK 2048   // 8*16*16
#define BH 16
#define TOPK 1024
#define NPQ (BH*NQ)   // 65536
#define NPK (BH*NK)   // 32768

typedef __attribute__((ext_vector_type(8))) short bfx8;
typedef __attribute__((ext_vector_type(8))) _Float16 hfx8;
typedef __attribute__((ext_vector_type(4))) float fx4;
typedef __attribute__((ext_vector_type(4))) unsigned short us4;

__device__ inline unsigned short f2bf(float x) {
  unsigned u = __float_as_uint(x);
  return (unsigned short)((u + 0x7fffu + ((u >> 16) & 1u)) >> 16);
}
__device__ inline unsigned short f2h_bits(float x) {
  _Float16 h = (_Float16)x;
  unsigned short u;
  __builtin_memcpy(&u, &h, 2);
  return u;
}
__device__ inline float h_bits2f(unsigned short u) {
  _Float16 h;
  __builtin_memcpy(&h, &u, 2);
  return (float)h;
}

// ------- channel LayerNorm -> transposed split-f16 [b][n][C] (hi, lo*2048) ---
__global__ __launch_bounds__(256) void chan_ln_tsplit_k(
    const float* __restrict__ x, const float* __restrict__ g,
    const float* __restrict__ bta, unsigned short* __restrict__ yh,
    unsigned short* __restrict__ yl, int C, int N) {
  __shared__ float tile[4][64][65];
  __shared__ float p1[4][64], p2[4][64];
  __shared__ float mArr[64], invArr[64];
  int t = threadIdx.x, lane = t & 63, wv = t >> 6;
  int n0 = blockIdx.x * 64, bi = blockIdx.y;
  const float* xb = x + (size_t)bi * C * N + n0 + lane;
  float s = 0.f, s2 = 0.f;
  for (int cl = 0; cl < 64; ++cl) {
    float v = xb[(size_t)(wv * 64 + cl) * N];
    tile[wv][cl][lane] = v;
    s += v;
    s2 += v * v;
  }
  p1[wv][lane] = s;
  p2[wv][lane] = s2;
  __syncthreads();
  if (t < 64) {
    float ts = p1[0][t] + p1[1][t] + p1[2][t] + p1[3][t];
    float ts2 = p2[0][t] + p2[1][t] + p2[2][t] + p2[3][t];
    float m = ts / C;
    float var = ts2 / C - m * m;
    mArr[t] = m;
    invArr[t] = 1.f / (sqrtf(fmaxf(var, 0.f)) + 1e-6f);
  }
  __syncthreads();
  int c = wv * 64 + lane;  // lane = channel in phase 2
  float gc = g[c], bc = bta[c];
  unsigned short* ohb = yh + ((size_t)bi * N + n0) * C + c;
  unsigned short* olb = yl + ((size_t)bi * N + n0) * C + c;
  for (int pl = 0; pl < 64; ++pl) {
    float v = tile[wv][lane][pl];
    float ln = gc * (v - mArr[pl]) * invArr[pl] + bc;
    unsigned short hb = f2h_bits(ln);
    ohb[(size_t)pl * C] = hb;
    olb[(size_t)pl * C] = f2h_bits((ln - h_bits2f(hb)) * 2048.f);
  }
}

// ------- MFMA GEMM: Y[b][o][n] = sum_c W[o][c] * Xt[b][n][c] -----------------
__global__ __launch_bounds__(256) void gemm_mfma_k(
    const float* __restrict__ W, const unsigned short* __restrict__ Xh,
    const unsigned short* __restrict__ Xl, float* __restrict__ Y,
    int O, int C, int N) {
  int t = threadIdx.x, lane = t & 63, wv = t >> 6;
  int lq = lane & 15, lg = lane >> 4;
  int n0 = blockIdx.x * 64, o0 = blockIdx.y * 64 + wv * 16;
  int b = blockIdx.z;
  const unsigned short* xbh = Xh + ((size_t)b * N + n0) * C;
  const unsigned short* xbl = Xl + ((size_t)b * N + n0) * C;
  const float* wr = W + (size_t)(o0 + lq) * C;
  fx4 ahi[4], alo[4];
  for (int nt = 0; nt < 4; ++nt) {
    ahi[nt] = (fx4){0.f, 0.f, 0.f, 0.f};
    alo[nt] = (fx4){0.f, 0.f, 0.f, 0.f};
  }
  for (int k0 = 0; k0 < C; k0 += 32) {
    float4 w0 = *(const float4*)(wr + k0 + lg * 8);
    float4 w1 = *(const float4*)(wr + k0 + lg * 8 + 4);
    float wv8[8] = {w0.x, w0.y, w0.z, w0.w, w1.x, w1.y, w1.z, w1.w};
    hfx8 ah, al;
#pragma unroll
    for (int i = 0; i < 8; ++i) {
      _Float16 h = (_Float16)wv8[i];
      ah[i] = h;
      al[i] = (_Float16)((wv8[i] - (float)h) * 2048.f);
    }
#pragma unroll
    for (int nt = 0; nt < 4; ++nt) {
      const unsigned short* bph = xbh + (size_t)(nt * 16 + lq) * C + k0 + lg * 8;
      const unsigned short* bpl = xbl + (size_t)(nt * 16 + lq) * C + k0 + lg * 8;
      hfx8 bh = *(const hfx8*)bph;
      hfx8 bl = *(const hfx8*)bpl;
      ahi[nt] = __builtin_amdgcn_mfma_f32_16x16x32_f16(ah, bh, ahi[nt], 0, 0, 0);
      alo[nt] = __builtin_amdgcn_mfma_f32_16x16x32_f16(al, bh, alo[nt], 0, 0, 0);
      alo[nt] = __builtin_amdgcn_mfma_f32_16x16x32_f16(ah, bl, alo[nt], 0, 0, 0);
    }
  }
  float* yb = Y + ((size_t)b * O + o0) * N + n0;
#pragma unroll
  for (int nt = 0; nt < 4; ++nt)
#pragma unroll
    for (int r = 0; r < 4; ++r)
      yb[(size_t)(lg * 4 + r) * N + nt * 16 + lq] = ahi[nt][r] + alo[nt][r] * (1.f / 2048.f);
}

// ---------------- fold heads: (b, ch, n) -> (bh, n, 64), optional L2 norm ----
__global__ void fold_k(const float* __restrict__ src, float* __restrict__ dst,
                       int bstride, int choff, int N, int donorm) {
  __shared__ float tile[64 * 65];
  __shared__ float part[4 * 64];
  __shared__ float invn[64];
  int t = threadIdx.x;
  int lane = t & 63, wv = t >> 6;
  int n0 = blockIdx.x * 64;
  int h = blockIdx.y, bi = blockIdx.z;
  const float* sb = src + (size_t)bi * bstride + (size_t)(choff + h * 64) * N + n0;
  for (int r = 0; r < 16; ++r) {
    int d = r * 4 + wv;
    tile[d * 65 + lane] = sb[(size_t)d * N + lane];
  }
  __syncthreads();
  if (donorm) {
    float s = 0.f;
    for (int r = 0; r < 16; ++r) {
      float v = tile[(wv + 4 * r) * 65 + lane];
      s += v * v;
    }
    part[wv * 64 + lane] = s;
    __syncthreads();
    if (t < 64) {
      float tot = part[t] + part[64 + t] + part[128 + t] + part[192 + t];
      invn[t] = 1.f / fmaxf(sqrtf(tot), 1e-12f);
    }
    __syncthreads();
  }
  float* db = dst + ((size_t)(bi * 8 + h) * N + n0) * 64;
  for (int r = 0; r < 16; ++r) {
    int nn = r * 4 + wv;
    float v = tile[lane * 65 + nn];
    if (donorm) v *= invn[nn];
    db[(size_t)nn * 64 + lane] = v;
  }
}

// ---------------- f32 -> split f16 (hi + lo*2048) ----------------------------
__global__ void tof2_k(const float* __restrict__ x, unsigned short* __restrict__ yh,
                       unsigned short* __restrict__ yl) {
  int i = blockIdx.x * 256 + threadIdx.x;
  float4 v = ((const float4*)x)[i];
  us4 h = {f2h_bits(v.x), f2h_bits(v.y), f2h_bits(v.z), f2h_bits(v.w)};
  us4 l = {f2h_bits((v.x - h_bits2f(h.x)) * 2048.f),
           f2h_bits((v.y - h_bits2f(h.y)) * 2048.f),
           f2h_bits((v.z - h_bits2f(h.z)) * 2048.f),
           f2h_bits((v.w - h_bits2f(h.w)) * 2048.f)};
  *(us4*)(yh + (size_t)i * 4) = h;
  *(us4*)(yl + (size_t)i * 4) = l;
}

// ---------------- centroid prep: csq (f32), -2c split f16 --------------------
__global__ void centprep_k(const float* __restrict__ cent, float* __restrict__ csq,
                           unsigned short* __restrict__ cb2h, unsigned short* __restrict__ cb2l) {
  int j = blockIdx.x, lane = threadIdx.x;  // blockDim = 64
  float c = cent[j * 64 + lane];
  float s = c * c;
  for (int off = 32; off; off >>= 1) s += __shfl_xor(s, off);
  if (lane == 0) csq[j] = s;
  float m2 = -2.f * c;
  unsigned short h = f2h_bits(m2);
  cb2h[j * 64 + lane] = h;
  cb2l[j * 64 + lane] = f2h_bits((m2 - h_bits2f(h)) * 2048.f);
}

// ---------------- MFMA nearest-centroid assign (f16 split, LDS-staged) -------
// FUSE=1: fused segment-sum epilogue (exact f32 reload from xf + atomics),
// no asg write. FUSE=0: write argmin to aout.
template <int FUSE>
__global__ __launch_bounds__(256) void assign_mfma_k(
    const unsigned short* __restrict__ xh, const unsigned short* __restrict__ xl,
    const unsigned short* __restrict__ cb2h, const unsigned short* __restrict__ cb2l,
    const float* __restrict__ csq, int* __restrict__ aout,
    const float* __restrict__ xf, float* __restrict__ sums, float* __restrict__ cnt) {
  __shared__ __align__(16) unsigned short clds[2][2][1024];  // [buf][hi/lo][16x64]
  int t = threadIdx.x, lane = t & 63, wv = t >> 6;
  int lq = lane & 15, lg = lane >> 4;
  int p0 = blockIdx.x * 64 + wv * 16;
  const unsigned short* xb = xh + (size_t)(p0 + lq) * 64;
  const unsigned short* xlb = xl + (size_t)(p0 + lq) * 64;
  hfx8 bh0 = *(const hfx8*)(xb + lg * 8);
  hfx8 bh1 = *(const hfx8*)(xb + 32 + lg * 8);
  hfx8 bl0 = *(const hfx8*)(xlb + lg * 8);
  hfx8 bl1 = *(const hfx8*)(xlb + 32 + lg * 8);

  int part = t >> 7;
  int abyte = (t & 127) * 16;
  int wbyte = abyte ^ (((abyte >> 7) & 7) << 4);
  const unsigned short* gsrc = (part ? cb2l : cb2h) + (abyte >> 1);
  int rowoff = lq * 128;
  int x0 = (lg * 16) ^ ((lq & 7) << 4);
  int x1 = (64 + lg * 16) ^ ((lq & 7) << 4);

  float best = 3.4e38f;
  int bestj = 0;

  uint4 r0 = *(const uint4*)(gsrc);
  *(uint4*)((char*)&clds[0][part][0] + wbyte) = r0;

  for (int s = 0; s < 64; ++s) {
    int cur = s & 1;
    __syncthreads();
    uint4 rn;
    if (s < 63) rn = *(const uint4*)(gsrc + (size_t)(s + 1) * 1024);
    __builtin_amdgcn_sched_barrier(0);
    const char* ph = (const char*)&clds[cur][0][0];
    const char* pl = (const char*)&clds[cur][1][0];
    hfx8 ah0 = *(const hfx8*)(ph + rowoff + x0);
    hfx8 ah1 = *(const hfx8*)(ph + rowoff + x1);
    hfx8 al0 = *(const hfx8*)(pl + rowoff + x0);
    hfx8 al1 = *(const hfx8*)(pl + rowoff + x1);
    fx4 chi = *(const fx4*)(csq + s * 16 + lg * 4);
    chi = __builtin_amdgcn_mfma_f32_16x16x32_f16(ah0, bh0, chi, 0, 0, 0);
    chi = __builtin_amdgcn_mfma_f32_16x16x32_f16(ah1, bh1, chi, 0, 0, 0);
    fx4 clo = (fx4){0.f, 0.f, 0.f, 0.f};
    clo = __builtin_amdgcn_mfma_f32_16x16x32_f16(ah0, bl0, clo, 0, 0, 0);
    clo = __builtin_amdgcn_mfma_f32_16x16x32_f16(ah1, bl1, clo, 0, 0, 0);
    clo = __builtin_amdgcn_mfma_f32_16x16x32_f16(al0, bh0, clo, 0, 0, 0);
    clo = __builtin_amdgcn_mfma_f32_16x16x32_f16(al1, bh1, clo, 0, 0, 0);
#pragma unroll
    for (int r_ = 0; r_ < 4; ++r_) {
      int j_ = s * 16 + lg * 4 + r_;
      float d2_ = chi[r_] + clo[r_] * (1.f / 2048.f);
      if (d2_ < best) { best = d2_; bestj = j_; }
    }
    __builtin_amdgcn_sched_barrier(0);
    if (s < 63) *(uint4*)((char*)&clds[cur ^ 1][part][0] + wbyte) = rn;
  }

  // butterfly merge: afterwards ALL lanes hold the winning (best,bestj)
  {
    float o = __shfl_xor(best, 16);
    int oj = __shfl_xor(bestj, 16);
    if (o < best || (o == best && oj < bestj)) { best = o; bestj = oj; }
    o = __shfl_xor(best, 32);
    oj = __shfl_xor(bestj, 32);
    if (o < best || (o == best && oj < bestj)) { best = o; bestj = oj; }
  }
  if (FUSE) {
    // fused segment sum: lane (lq,lg) owns elements [lg*8,lg*8+8) u [32+lg*8,..)
    const float4* xf4 = (const float4*)(xf + (size_t)(p0 + lq) * 64);
    float4 v0 = xf4[lg * 2];
    float4 v1 = xf4[lg * 2 + 1];
    float4 v2 = xf4[8 + lg * 2];
    float4 v3 = xf4[8 + lg * 2 + 1];
    float* sb = sums + (size_t)bestj * 64;
    int e0 = lg * 8, e1 = 32 + lg * 8;
    atomicAdd(&sb[e0 + 0], v0.x); atomicAdd(&sb[e0 + 1], v0.y);
    atomicAdd(&sb[e0 + 2], v0.z); atomicAdd(&sb[e0 + 3], v0.w);
    atomicAdd(&sb[e0 + 4], v1.x); atomicAdd(&sb[e0 + 5], v1.y);
    atomicAdd(&sb[e0 + 6], v1.z); atomicAdd(&sb[e0 + 7], v1.w);
    atomicAdd(&sb[e1 + 0], v2.x); atomicAdd(&sb[e1 + 1], v2.y);
    atomicAdd(&sb[e1 + 2], v2.z); atomicAdd(&sb[e1 + 3], v2.w);
    atomicAdd(&sb[e1 + 4], v3.x); atomicAdd(&sb[e1 + 5], v3.y);
    atomicAdd(&sb[e1 + 6], v3.z); atomicAdd(&sb[e1 + 7], v3.w);
    if (lg == 0) atomicAdd(&cnt[bestj], 1.0f);
  } else {
    if (lg == 0) aout[p0 + lq] = bestj;
  }
}

// ---------------- exact f32 L1 distance to assigned centroid -----------------
__global__ void dist_k(const float* __restrict__ x, const float* __restrict__ cent,
                       const int* __restrict__ asg, float* __restrict__ dout) {
  int t = threadIdx.x, lane = t & 63, wv = t >> 6;
  int p = blockIdx.x * 4 + wv;
  int a = asg[p];
  float v = fabsf(cent[(size_t)a * 64 + lane] - x[(size_t)p * 64 + lane]);
  for (int off = 32; off; off >>= 1) v += __shfl_xor(v, off);
  if (lane == 0) dout[p] = v;
}

// ---------------- centroid update --------------------------------------------
__global__ void centup_k(float* __restrict__ cent, const float* __restrict__ sums,
                         const float* __restrict__ cnt) {
  int i = blockIdx.x * 256 + threadIdx.x;  // 65536 total
  int j = i >> 6;
  float c = cnt[j];
  if (c > 0.f) cent[i] = sums[i] / fmaxf(c, 1.f);
}

// ---------------- per-bh top-1024 by descending dist (stable ties) -----------
// 1024 threads: 2 LDS iterations per bitonic pass (was 8) -> 4x shorter chain.
__global__ __launch_bounds__(1024) void topk_k(const float* __restrict__ dist,
                                               int* __restrict__ sel) {
  __shared__ unsigned long long keys[2048];
  int bh = blockIdx.x, t = threadIdx.x;
  for (int i = t; i < 2048; i += 1024) {
    float d = dist[bh * 2048 + i];
    unsigned int db = __float_as_uint(d);  // d >= 0 -> monotonic
    keys[i] = ((unsigned long long)db << 32) | (unsigned int)(2047 - i);
  }
  __syncthreads();
  for (int k = 2; k <= 2048; k <<= 1) {
    for (int j = k >> 1; j > 0; j >>= 1) {
      for (int i = t; i < 2048; i += 1024) {
        int ixj = i ^ j;
        if (ixj > i) {
          unsigned long long a = keys[i], b = keys[ixj];
          bool up = ((i & k) == 0);
          bool sw = up ? (a < b) : (a > b);  // descending overall
          if (sw) { keys[i] = b; keys[ixj] = a; }
        }
      }
      __syncthreads();
    }
  }
  if (t < 1024) sel[bh * 1024 + t] = 2047 - (int)(keys[t] & 0xffffffffu);
}

// ---------------- gather selected rows -> kh (bf16 row-major), vT (bf16 d-major)
__global__ void gatherb_k(const float* __restrict__ kbuf, const float* __restrict__ vbuf,
                          const int* __restrict__ sel, unsigned short* __restrict__ kh,
                          unsigned short* __restrict__ vT) {
  __shared__ unsigned short tile[64][66];
  int t = threadIdx.x, lane = t & 63, wv = t >> 6;
  int bh = blockIdx.y, i0 = blockIdx.x * 64;
  for (int r = 0; r < 16; ++r) {
    int i = r * 4 + wv;
    int src = sel[bh * 1024 + i0 + i];
    float kvv = kbuf[((size_t)bh * 2048 + src) * 64 + lane];
    kh[((size_t)bh * 1024 + i0 + i) * 64 + lane] = f2bf(kvv);
    float vv = vbuf[((size_t)bh * 2048 + src) * 64 + lane];
    tile[i][lane] = f2bf(vv);
  }
  __syncthreads();
  for (int r = 0; r < 16; ++r) {
    int d = r * 4 + wv;
    vT[((size_t)bh * 64 + d) * 1024 + i0 + lane] = tile[lane][d];
  }
}

// ---------------- f32 -> bf16 bulk convert -----------------------------------
__global__ void tobf_k(const float* __restrict__ x, unsigned short* __restrict__ y) {
  int i = blockIdx.x * 256 + threadIdx.x;
  float4 v = ((const float4*)x)[i];
  us4 o = {f2bf(v.x), f2bf(v.y), f2bf(v.z), f2bf(v.w)};
  *(us4*)(y + (size_t)i * 4) = o;
}

// ---------------- MFMA flash attention (K/V LDS-staged, barrier-light) -------
__global__ __launch_bounds__(256) void attn_mfma_k(
    const unsigned short* __restrict__ qh, const unsigned short* __restrict__ kh,
    const unsigned short* __restrict__ vT,
    unsigned short* __restrict__ oh, unsigned short* __restrict__ ol) {
  __shared__ __align__(16) unsigned short kvlds[2][2][4096];  // [buf][K/V][64x64]
  __shared__ unsigned short plds[4][16][72];
  int t = threadIdx.x, lane = t & 63, wv = t >> 6;
  int lq = lane & 15, lg = lane >> 4;
  int bh = blockIdx.y;
  int q0 = blockIdx.x * 64 + wv * 16;
  const unsigned short* qbase = qh + ((size_t)bh * 4096 + q0 + lq) * 64;
  bfx8 qf0 = *(const bfx8*)(qbase + lg * 8);
  bfx8 qf1 = *(const bfx8*)(qbase + 32 + lg * 8);
  fx4 acc[4];
  for (int nt = 0; nt < 4; ++nt) acc[nt] = (fx4){0.f, 0.f, 0.f, 0.f};
  float lsum = 0.f;
  const unsigned short* kbase = kh + (size_t)bh * 1024 * 64;
  const unsigned short* vbase = vT + (size_t)bh * 64 * 1024;

  int srow = t >> 2;
  int scolb = (t & 3) * 32;
  const char* gK = (const char*)kbase + (size_t)srow * 128 + scolb;   // + s*8192
  const char* gV = (const char*)vbase + (size_t)srow * 2048 + scolb;  // + s*128
  int sw_w = (srow & 7) << 4;
  int wb0 = srow * 128 + (scolb ^ sw_w);
  int wb1 = srow * 128 + ((scolb + 16) ^ sw_w);

  {
    uint4 k0 = *(const uint4*)(gK);
    uint4 k1 = *(const uint4*)(gK + 16);
    uint4 v0 = *(const uint4*)(gV);
    uint4 v1 = *(const uint4*)(gV + 16);
    *(uint4*)((char*)&kvlds[0][0][0] + wb0) = k0;
    *(uint4*)((char*)&kvlds[0][0][0] + wb1) = k1;
    *(uint4*)((char*)&kvlds[0][1][0] + wb0) = v0;
    *(uint4*)((char*)&kvlds[0][1][0] + wb1) = v1;
  }

  int swr = (lq & 7) << 4;
  int rc0 = (lg * 16) ^ swr;
  int rc1 = (64 + lg * 16) ^ swr;

  for (int s = 0; s < 16; ++s) {
    int cur = s & 1;
    __syncthreads();
    uint4 nk0, nk1, nv0, nv1;
    if (s < 15) {
      const char* gKn = gK + (size_t)(s + 1) * 8192;
      const char* gVn = gV + (size_t)(s + 1) * 128;
      nk0 = *(const uint4*)(gKn);
      nk1 = *(const uint4*)(gKn + 16);
      nv0 = *(const uint4*)(gVn);
      nv1 = *(const uint4*)(gVn + 16);
    }
    __builtin_amdgcn_sched_barrier(0);
    const char* Kb = (const char*)&kvlds[cur][0][0];
    const char* Vb = (const char*)&kvlds[cur][1][0];
    fx4 sS[4];
#pragma unroll
    for (int mt = 0; mt < 4; ++mt) {
      int rowb = (mt * 16 + lq) * 128;
      bfx8 a0 = *(const bfx8*)(Kb + rowb + rc0);
      bfx8 a1 = *(const bfx8*)(Kb + rowb + rc1);
      fx4 c = (fx4){0.f, 0.f, 0.f, 0.f};
      c = __builtin_amdgcn_mfma_f32_16x16x32_bf16(a0, qf0, c, 0, 0, 0);
      c = __builtin_amdgcn_mfma_f32_16x16x32_bf16(a1, qf1, c, 0, 0, 0);
      sS[mt] = c;
    }
#pragma unroll
    for (int mt = 0; mt < 4; ++mt) {
      float p0 = __expf(sS[mt].x), p1 = __expf(sS[mt].y);
      float p2 = __expf(sS[mt].z), p3 = __expf(sS[mt].w);
      lsum += (p0 + p1) + (p2 + p3);
      us4 pk = {f2bf(p0), f2bf(p1), f2bf(p2), f2bf(p3)};
      *(us4*)&plds[wv][lq][mt * 16 + lg * 4] = pk;
    }
    bfx8 pa0 = *(const bfx8*)&plds[wv][lq][lg * 8];
    bfx8 pa1 = *(const bfx8*)&plds[wv][lq][32 + lg * 8];
#pragma unroll
    for (int nt = 0; nt < 4; ++nt) {
      int rowb = (nt * 16 + lq) * 128;
      bfx8 b0 = *(const bfx8*)(Vb + rowb + rc0);
      bfx8 b1 = *(const bfx8*)(Vb + rowb + rc1);
      acc[nt] = __builtin_amdgcn_mfma_f32_16x16x32_bf16(pa0, b0, acc[nt], 0, 0, 0);
      acc[nt] = __builtin_amdgcn_mfma_f32_16x16x32_bf16(pa1, b1, acc[nt], 0, 0, 0);
    }
    __builtin_amdgcn_sched_barrier(0);
    if (s < 15) {
      char* dK = (char*)&kvlds[cur ^ 1][0][0];
      char* dV = (char*)&kvlds[cur ^ 1][1][0];
      *(uint4*)(dK + wb0) = nk0;
      *(uint4*)(dK + wb1) = nk1;
      *(uint4*)(dV + wb0) = nv0;
      *(uint4*)(dV + wb1) = nv1;
    }
  }
  lsum += __shfl_xor(lsum, 16);
  lsum += __shfl_xor(lsum, 32);
  int bi = bh >> 3, hd = bh & 7;
  for (int r = 0; r < 4; ++r) {
    float inv = 1.f / __shfl(lsum, lg * 4 + r);
    size_t rowb = ((size_t)bi * 4096 + q0 + lg * 4 + r) * 512 + hd * 64;
    for (int nt = 0; nt < 4; ++nt) {
      float val = acc[nt][r] * inv;
      unsigned short hb = f2h_bits(val);
      oh[rowb + nt * 16 + lq] = hb;
      ol[rowb + nt * 16 + lq] = f2h_bits((val - h_bits2f(hb)) * 2048.f);
    }
  }
}

// ---------------- final LN + gamma*ln + residual (wave-split channels) -------
__global__ __launch_bounds__(256) void final_k(
    const float* __restrict__ y, const float* __restrict__ g,
    const float* __restrict__ bta, const float* __restrict__ gamma,
    const float* __restrict__ qs, float* __restrict__ out) {
  __shared__ float p1[4][64], p2[4][64];
  __shared__ float mArr[64], invArr[64];
  int t = threadIdx.x, lane = t & 63, wv = t >> 6;
  int n0 = blockIdx.x * 64, bi = blockIdx.y;
  const float* yb = y + (size_t)bi * CDIM * NQ + n0 + lane;
  float s = 0.f, s2 = 0.f;
  for (int cl = 0; cl < 64; ++cl) {
    float v = yb[(size_t)(wv * 64 + cl) * NQ];
    s += v;
    s2 += v * v;
  }
  p1[wv][lane] = s;
  p2[wv][lane] = s2;
  __syncthreads();
  if (t < 64) {
    float ts = p1[0][t] + p1[1][t] + p1[2][t] + p1[3][t];
    float ts2 = p2[0][t] + p2[1][t] + p2[2][t] + p2[3][t];
    float m = ts / CDIM;
    float var = ts2 / CDIM - m * m;
    mArr[t] = m;
    invArr[t] = 1.f / (sqrtf(fmaxf(var, 0.f)) + 1e-6f);
  }
  __syncthreads();
  float gm = gamma[0];
  float m = mArr[lane], inv = invArr[lane];
  const float* qb = qs + (size_t)bi * CDIM * NQ + n0 + lane;
  float* ob = out + (size_t)bi * CDIM * NQ + n0 + lane;
  for (int cl = 0; cl < 64; ++cl) {
    int c = wv * 64 + cl;
    float v = yb[(size_t)c * NQ];
    float ln = g[c] * (v - m) * inv + bta[c];
    ob[(size_t)c * NQ] = gm * ln + qb[(size_t)c * NQ];
  }
}

extern "C" void kernel_launch(void* const* d_in, const int* in_sizes, int n_in,
                              void* d_out, int out_size, void* d_ws, size_t ws_size,
                              hipStream_t stream) {
  const float* qsrc = (const float*)d_in[0];
  const float* ctx = (const float*)d_in[1];
  const float* w_q = (const float*)d_in[2];
  const float* w_kv = (const float*)d_in[3];
  const float* w_out = (const float*)d_in[4];
  const float* cn_g = (const float*)d_in[5];
  const float* cn_b = (const float*)d_in[6];
  const float* qn_g = (const float*)d_in[7];
  const float* qn_b = (const float*)d_in[8];
  const float* on_g = (const float*)d_in[9];
  const float* on_b = (const float*)d_in[10];
  const float* gamma = (const float*)d_in[11];

  // scratch layout (floats); total 22,267,904 floats = 89.1 MB
  if (ws_size < (size_t)22267904 * 4) return;
  float* ws = (float*)d_ws;
  float* r_ctx = ws;                      // 1,048,576 f: ctx split-f16; later kh/vT
  float* r_kv = r_ctx + 1048576;          // 4,194,304 f: kv f32; later kbh/kbl; later attnt split
  float* r_qs = r_kv + 4194304;           // 2,097,152 f: qs split-f16; later cb2h/l, ybuf
  float* r_q3 = r_qs + 2097152;           // 4,194,304 f: q3 f32; later qbh/qbl
  float* qbuf = r_q3 + 4194304;           // 4,194,304 f
  float* kbuf = qbuf + 4194304;           // 2,097,152 f
  float* vbuf = kbuf + 2097152;           // 2,097,152 f
  float* cent = vbuf + 2097152;           // 65,536 f
  float* csq = cent + 65536;              // 1,024 f
  float* sums = csq + 1024;               // 65,536 f
  float* cnt = sums + 65536;              // 1,024 f
  int* asg = (int*)(cnt + 1024);          // 65,536 i
  float* dist = (float*)(asg + 65536);    // 32,768 f
  int* sel = (int*)(dist + 32768);        // 16,384 i
  float* kgreg = (float*)(sel + 16384);   // 2,097,152 f (qh bf16)

  unsigned short* ctxth = (unsigned short*)r_ctx;   // [b][2048][256] f16 hi
  unsigned short* ctxtl = ctxth + (size_t)BB * NK * CDIM;  // lo
  unsigned short* qsth = (unsigned short*)r_qs;     // [b][4096][256] f16 hi
  unsigned short* qstl = qsth + (size_t)BB * NQ * CDIM;    // lo
  float* kvf = r_kv;                      // [b][1024][2048] f32
  float* q3f = r_q3;                      // [b][512][4096] f32
  unsigned short* qh = (unsigned short*)kgreg;      // 4M bf16
  unsigned short* kh = (unsigned short*)r_ctx;      // 1M bf16 (ctx split dead)
  unsigned short* vT = kh + 1048576;                // 1M bf16
  unsigned short* qbh = (unsigned short*)r_q3;      // 4M f16 (q split hi)
  unsigned short* qbl = qbh + (size_t)NPQ * 64;     // 4M f16 (lo)
  unsigned short* kbh = (unsigned short*)r_kv;      // 2M f16 (k split hi)
  unsigned short* kbl = kbh + (size_t)NPK * 64;     // 2M f16 (lo)
  unsigned short* cb2h = (unsigned short*)r_qs;     // 64K f16 (-2c hi)
  unsigned short* cb2l = cb2h + 65536;              // 64K f16 (lo)
  unsigned short* attnth = (unsigned short*)r_kv;   // [b][4096][512] f16 hi (kb split dead)
  unsigned short* attntl = attnth + (size_t)BB * NQ * 512;  // lo
  float* ybuf = r_qs;                     // [b][256][4096] f32 (cb2 dead)

  // 1. channel LayerNorms -> transposed split-f16
  chan_ln_tsplit_k<<<dim3(NK / 64, BB), 256, 0, stream>>>(ctx, cn_g, cn_b, ctxth, ctxtl, CDIM, NK);
  chan_ln_tsplit_k<<<dim3(NQ / 64, BB), 256, 0, stream>>>(qsrc, qn_g, qn_b, qsth, qstl, CDIM, NQ);
  // 2. MFMA projections
  gemm_mfma_k<<<dim3(NK / 64, 1024 / 64, BB), 256, 0, stream>>>(w_kv, ctxth, ctxtl, kvf, 1024, CDIM, NK);
  gemm_mfma_k<<<dim3(NQ / 64, 512 / 64, BB), 256, 0, stream>>>(w_q, qsth, qstl, q3f, 512, CDIM, NQ);
  // 3. fold heads (+L2-normalize q,k)
  fold_k<<<dim3(NQ / 64, 8, BB), 256, 0, stream>>>(q3f, qbuf, 512 * NQ, 0, NQ, 1);
  fold_k<<<dim3(NK / 64, 8, BB), 256, 0, stream>>>(kvf, kbuf, 1024 * NK, 0, NK, 1);
  fold_k<<<dim3(NK / 64, 8, BB), 256, 0, stream>>>(kvf, vbuf, 1024 * NK, 512, NK, 0);
  // 4. split-f16 conversions (q3/kv f32 regions now reusable)
  tof2_k<<<NPQ * 64 / 1024, 256, 0, stream>>>(qbuf, qbh, qbl);
  tof2_k<<<NPK * 64 / 1024, 256, 0, stream>>>(kbuf, kbh, kbl);
  // 5. k-means (init = first 1024 q rows); assign has fused segment-sum
  hipMemcpyAsync(cent, qbuf, 65536 * sizeof(float), hipMemcpyDeviceToDevice, stream);
  for (int it = 0; it < 4; ++it) {
    centprep_k<<<1024, 64, 0, stream>>>(cent, csq, cb2h, cb2l);
    hipMemsetAsync(sums, 0, (65536 + 1024) * sizeof(float), stream);
    assign_mfma_k<1><<<NPQ / 64, 256, 0, stream>>>(qbh, qbl, cb2h, cb2l, csq, nullptr, qbuf, sums, cnt);
    centup_k<<<65536 / 256, 256, 0, stream>>>(cent, sums, cnt);
  }
  // 6. score keys: argmin (MFMA) -> exact f32 L1 dist -> per-head top-1024
  centprep_k<<<1024, 64, 0, stream>>>(cent, csq, cb2h, cb2l);
  assign_mfma_k<0><<<NPK / 64, 256, 0, stream>>>(kbh, kbl, cb2h, cb2l, csq, asg, nullptr, nullptr, nullptr);
  dist_k<<<NPK / 4, 256, 0, stream>>>(kbuf, cent, asg, dist);
  topk_k<<<BH, 1024, 0, stream>>>(dist, sel);
  // 7. bf16 conversions + gather (kh row-major, vT transposed)
  tobf_k<<<NPQ * 64 / 1024, 256, 0, stream>>>(qbuf, qh);
  gatherb_k<<<dim3(TOPK / 64, BH), 256, 0, stream>>>(kbuf, vbuf, sel, kh, vT);
  // 8. MFMA attention -> split-f16 un-folded [b][n][512]
  attn_mfma_k<<<dim3(NQ / 64, BH), 256, 0, stream>>>(qh, kh, vT, attnth, attntl);
  // 9. output projection (MFMA)
  gemm_mfma_k<<<dim3(NQ / 64, 256 / 64, BB), 256, 0, stream>>>(w_out, attnth, attntl, ybuf, 256, 512, NQ);
  // 10. final LN + residual
  final_k<<<dim3(NQ / 64, BB), 256, 0, stream>>>(ybuf, on_g, on_b, gamma, qsrc, (float*)d_out);
}

// Round 10
// 619.514 us; speedup vs baseline: 1.6082x; 1.6082x over previous
//
#include <hip/hip_runtime.h>
#include <math.h>

#define BB 2
#define CDIM 256
#define NQ 4096   // 16*16*16
#define NK 2048   // 8*16*16
#define BH 16
#define TOPK 1024
#define NPQ (BH*NQ)   // 65536
#define NPK (BH*NK)   // 32768

typedef __attribute__((ext_vector_type(8))) short bfx8;
typedef __attribute__((ext_vector_type(8))) _Float16 hfx8;
typedef __attribute__((ext_vector_type(4))) float fx4;
typedef __attribute__((ext_vector_type(4))) unsigned short us4;

__device__ inline unsigned short f2bf(float x) {
  unsigned u = __float_as_uint(x);
  return (unsigned short)((u + 0x7fffu + ((u >> 16) & 1u)) >> 16);
}
__device__ inline unsigned short f2h_bits(float x) {
  _Float16 h = (_Float16)x;
  unsigned short u;
  __builtin_memcpy(&u, &h, 2);
  return u;
}
__device__ inline float h_bits2f(unsigned short u) {
  _Float16 h;
  __builtin_memcpy(&h, &u, 2);
  return (float)h;
}

// ------- channel LayerNorm -> transposed split-f16 [b][n][C] (hi, lo*2048) ---
__global__ __launch_bounds__(256) void chan_ln_tsplit_k(
    const float* __restrict__ x, const float* __restrict__ g,
    const float* __restrict__ bta, unsigned short* __restrict__ yh,
    unsigned short* __restrict__ yl, int C, int N) {
  __shared__ float tile[4][64][65];
  __shared__ float p1[4][64], p2[4][64];
  __shared__ float mArr[64], invArr[64];
  int t = threadIdx.x, lane = t & 63, wv = t >> 6;
  int n0 = blockIdx.x * 64, bi = blockIdx.y;
  const float* xb = x + (size_t)bi * C * N + n0 + lane;
  float s = 0.f, s2 = 0.f;
  for (int cl = 0; cl < 64; ++cl) {
    float v = xb[(size_t)(wv * 64 + cl) * N];
    tile[wv][cl][lane] = v;
    s += v;
    s2 += v * v;
  }
  p1[wv][lane] = s;
  p2[wv][lane] = s2;
  __syncthreads();
  if (t < 64) {
    float ts = p1[0][t] + p1[1][t] + p1[2][t] + p1[3][t];
    float ts2 = p2[0][t] + p2[1][t] + p2[2][t] + p2[3][t];
    float m = ts / C;
    float var = ts2 / C - m * m;
    mArr[t] = m;
    invArr[t] = 1.f / (sqrtf(fmaxf(var, 0.f)) + 1e-6f);
  }
  __syncthreads();
  int c = wv * 64 + lane;  // lane = channel in phase 2
  float gc = g[c], bc = bta[c];
  unsigned short* ohb = yh + ((size_t)bi * N + n0) * C + c;
  unsigned short* olb = yl + ((size_t)bi * N + n0) * C + c;
  for (int pl = 0; pl < 64; ++pl) {
    float v = tile[wv][lane][pl];
    float ln = gc * (v - mArr[pl]) * invArr[pl] + bc;
    unsigned short hb = f2h_bits(ln);
    ohb[(size_t)pl * C] = hb;
    olb[(size_t)pl * C] = f2h_bits((ln - h_bits2f(hb)) * 2048.f);
  }
}

// ------- MFMA GEMM: Y[b][o][n] = sum_c W[o][c] * Xt[b][n][c] -----------------
__global__ __launch_bounds__(256) void gemm_mfma_k(
    const float* __restrict__ W, const unsigned short* __restrict__ Xh,
    const unsigned short* __restrict__ Xl, float* __restrict__ Y,
    int O, int C, int N) {
  int t = threadIdx.x, lane = t & 63, wv = t >> 6;
  int lq = lane & 15, lg = lane >> 4;
  int n0 = blockIdx.x * 64, o0 = blockIdx.y * 64 + wv * 16;
  int b = blockIdx.z;
  const unsigned short* xbh = Xh + ((size_t)b * N + n0) * C;
  const unsigned short* xbl = Xl + ((size_t)b * N + n0) * C;
  const float* wr = W + (size_t)(o0 + lq) * C;
  fx4 ahi[4], alo[4];
  for (int nt = 0; nt < 4; ++nt) {
    ahi[nt] = (fx4){0.f, 0.f, 0.f, 0.f};
    alo[nt] = (fx4){0.f, 0.f, 0.f, 0.f};
  }
  for (int k0 = 0; k0 < C; k0 += 32) {
    float4 w0 = *(const float4*)(wr + k0 + lg * 8);
    float4 w1 = *(const float4*)(wr + k0 + lg * 8 + 4);
    float wv8[8] = {w0.x, w0.y, w0.z, w0.w, w1.x, w1.y, w1.z, w1.w};
    hfx8 ah, al;
#pragma unroll
    for (int i = 0; i < 8; ++i) {
      _Float16 h = (_Float16)wv8[i];
      ah[i] = h;
      al[i] = (_Float16)((wv8[i] - (float)h) * 2048.f);
    }
#pragma unroll
    for (int nt = 0; nt < 4; ++nt) {
      const unsigned short* bph = xbh + (size_t)(nt * 16 + lq) * C + k0 + lg * 8;
      const unsigned short* bpl = xbl + (size_t)(nt * 16 + lq) * C + k0 + lg * 8;
      hfx8 bh = *(const hfx8*)bph;
      hfx8 bl = *(const hfx8*)bpl;
      ahi[nt] = __builtin_amdgcn_mfma_f32_16x16x32_f16(ah, bh, ahi[nt], 0, 0, 0);
      alo[nt] = __builtin_amdgcn_mfma_f32_16x16x32_f16(al, bh, alo[nt], 0, 0, 0);
      alo[nt] = __builtin_amdgcn_mfma_f32_16x16x32_f16(ah, bl, alo[nt], 0, 0, 0);
    }
  }
  float* yb = Y + ((size_t)b * O + o0) * N + n0;
#pragma unroll
  for (int nt = 0; nt < 4; ++nt)
#pragma unroll
    for (int r = 0; r < 4; ++r)
      yb[(size_t)(lg * 4 + r) * N + nt * 16 + lq] = ahi[nt][r] + alo[nt][r] * (1.f / 2048.f);
}

// ---------------- fold heads: (b, ch, n) -> (bh, n, 64), optional L2 norm ----
__global__ void fold_k(const float* __restrict__ src, float* __restrict__ dst,
                       int bstride, int choff, int N, int donorm) {
  __shared__ float tile[64 * 65];
  __shared__ float part[4 * 64];
  __shared__ float invn[64];
  int t = threadIdx.x;
  int lane = t & 63, wv = t >> 6;
  int n0 = blockIdx.x * 64;
  int h = blockIdx.y, bi = blockIdx.z;
  const float* sb = src + (size_t)bi * bstride + (size_t)(choff + h * 64) * N + n0;
  for (int r = 0; r < 16; ++r) {
    int d = r * 4 + wv;
    tile[d * 65 + lane] = sb[(size_t)d * N + lane];
  }
  __syncthreads();
  if (donorm) {
    float s = 0.f;
    for (int r = 0; r < 16; ++r) {
      float v = tile[(wv + 4 * r) * 65 + lane];
      s += v * v;
    }
    part[wv * 64 + lane] = s;
    __syncthreads();
    if (t < 64) {
      float tot = part[t] + part[64 + t] + part[128 + t] + part[192 + t];
      invn[t] = 1.f / fmaxf(sqrtf(tot), 1e-12f);
    }
    __syncthreads();
  }
  float* db = dst + ((size_t)(bi * 8 + h) * N + n0) * 64;
  for (int r = 0; r < 16; ++r) {
    int nn = r * 4 + wv;
    float v = tile[lane * 65 + nn];
    if (donorm) v *= invn[nn];
    db[(size_t)nn * 64 + lane] = v;
  }
}

// ---------------- f32 -> split f16 (hi + lo*2048) ----------------------------
__global__ void tof2_k(const float* __restrict__ x, unsigned short* __restrict__ yh,
                       unsigned short* __restrict__ yl) {
  int i = blockIdx.x * 256 + threadIdx.x;
  float4 v = ((const float4*)x)[i];
  us4 h = {f2h_bits(v.x), f2h_bits(v.y), f2h_bits(v.z), f2h_bits(v.w)};
  us4 l = {f2h_bits((v.x - h_bits2f(h.x)) * 2048.f),
           f2h_bits((v.y - h_bits2f(h.y)) * 2048.f),
           f2h_bits((v.z - h_bits2f(h.z)) * 2048.f),
           f2h_bits((v.w - h_bits2f(h.w)) * 2048.f)};
  *(us4*)(yh + (size_t)i * 4) = h;
  *(us4*)(yl + (size_t)i * 4) = l;
}

// ---------------- centroid prep: csq (f32), -2c split f16 --------------------
__global__ void centprep_k(const float* __restrict__ cent, float* __restrict__ csq,
                           unsigned short* __restrict__ cb2h, unsigned short* __restrict__ cb2l) {
  int j = blockIdx.x, lane = threadIdx.x;  // blockDim = 64
  float c = cent[j * 64 + lane];
  float s = c * c;
  for (int off = 32; off; off >>= 1) s += __shfl_xor(s, off);
  if (lane == 0) csq[j] = s;
  float m2 = -2.f * c;
  unsigned short h = f2h_bits(m2);
  cb2h[j * 64 + lane] = h;
  cb2l[j * 64 + lane] = f2h_bits((m2 - h_bits2f(h)) * 2048.f);
}

// ---------------- MFMA nearest-centroid assign (f16 split, LDS-staged) -------
__global__ __launch_bounds__(256) void assign_mfma_k(
    const unsigned short* __restrict__ xh, const unsigned short* __restrict__ xl,
    const unsigned short* __restrict__ cb2h, const unsigned short* __restrict__ cb2l,
    const float* __restrict__ csq, int* __restrict__ aout) {
  __shared__ __align__(16) unsigned short clds[2][2][1024];  // [buf][hi/lo][16x64]
  int t = threadIdx.x, lane = t & 63, wv = t >> 6;
  int lq = lane & 15, lg = lane >> 4;
  int p0 = blockIdx.x * 64 + wv * 16;
  const unsigned short* xb = xh + (size_t)(p0 + lq) * 64;
  const unsigned short* xlb = xl + (size_t)(p0 + lq) * 64;
  hfx8 bh0 = *(const hfx8*)(xb + lg * 8);
  hfx8 bh1 = *(const hfx8*)(xb + 32 + lg * 8);
  hfx8 bl0 = *(const hfx8*)(xlb + lg * 8);
  hfx8 bl1 = *(const hfx8*)(xlb + 32 + lg * 8);

  int part = t >> 7;
  int abyte = (t & 127) * 16;
  int wbyte = abyte ^ (((abyte >> 7) & 7) << 4);
  const unsigned short* gsrc = (part ? cb2l : cb2h) + (abyte >> 1);
  int rowoff = lq * 128;
  int x0 = (lg * 16) ^ ((lq & 7) << 4);
  int x1 = (64 + lg * 16) ^ ((lq & 7) << 4);

  float best = 3.4e38f;
  int bestj = 0;

  uint4 r0 = *(const uint4*)(gsrc);
  *(uint4*)((char*)&clds[0][part][0] + wbyte) = r0;

  for (int s = 0; s < 64; ++s) {
    int cur = s & 1;
    __syncthreads();
    uint4 rn;
    if (s < 63) rn = *(const uint4*)(gsrc + (size_t)(s + 1) * 1024);
    __builtin_amdgcn_sched_barrier(0);
    const char* ph = (const char*)&clds[cur][0][0];
    const char* pl = (const char*)&clds[cur][1][0];
    hfx8 ah0 = *(const hfx8*)(ph + rowoff + x0);
    hfx8 ah1 = *(const hfx8*)(ph + rowoff + x1);
    hfx8 al0 = *(const hfx8*)(pl + rowoff + x0);
    hfx8 al1 = *(const hfx8*)(pl + rowoff + x1);
    fx4 chi = *(const fx4*)(csq + s * 16 + lg * 4);
    chi = __builtin_amdgcn_mfma_f32_16x16x32_f16(ah0, bh0, chi, 0, 0, 0);
    chi = __builtin_amdgcn_mfma_f32_16x16x32_f16(ah1, bh1, chi, 0, 0, 0);
    fx4 clo = (fx4){0.f, 0.f, 0.f, 0.f};
    clo = __builtin_amdgcn_mfma_f32_16x16x32_f16(ah0, bl0, clo, 0, 0, 0);
    clo = __builtin_amdgcn_mfma_f32_16x16x32_f16(ah1, bl1, clo, 0, 0, 0);
    clo = __builtin_amdgcn_mfma_f32_16x16x32_f16(al0, bh0, clo, 0, 0, 0);
    clo = __builtin_amdgcn_mfma_f32_16x16x32_f16(al1, bh1, clo, 0, 0, 0);
#pragma unroll
    for (int r_ = 0; r_ < 4; ++r_) {
      int j_ = s * 16 + lg * 4 + r_;
      float d2_ = chi[r_] + clo[r_] * (1.f / 2048.f);
      if (d2_ < best) { best = d2_; bestj = j_; }
    }
    __builtin_amdgcn_sched_barrier(0);
    if (s < 63) *(uint4*)((char*)&clds[cur ^ 1][part][0] + wbyte) = rn;
  }

  {
    float o = __shfl_xor(best, 16);
    int oj = __shfl_xor(bestj, 16);
    if (o < best || (o == best && oj < bestj)) { best = o; bestj = oj; }
    o = __shfl_xor(best, 32);
    oj = __shfl_xor(bestj, 32);
    if (o < best || (o == best && oj < bestj)) { best = o; bestj = oj; }
  }
  if (lg == 0) aout[p0 + lq] = bestj;
}

// ---------------- exact f32 L1 distance to assigned centroid -----------------
__global__ void dist_k(const float* __restrict__ x, const float* __restrict__ cent,
                       const int* __restrict__ asg, float* __restrict__ dout) {
  int t = threadIdx.x, lane = t & 63, wv = t >> 6;
  int p = blockIdx.x * 4 + wv;
  int a = asg[p];
  float v = fabsf(cent[(size_t)a * 64 + lane] - x[(size_t)p * 64 + lane]);
  for (int off = 32; off; off >>= 1) v += __shfl_xor(v, off);
  if (lane == 0) dout[p] = v;
}

// ---------------- segment sum via atomics (wave=point: coalesced) ------------
__global__ void segsum_k(const float* __restrict__ x, const int* __restrict__ asg,
                         float* __restrict__ sums, float* __restrict__ cnt) {
  int t = threadIdx.x, lane = t & 63, wv = t >> 6;
  int p = blockIdx.x * 4 + wv;
  int a = asg[p];
  float v = x[(size_t)p * 64 + lane];
  atomicAdd(&sums[a * 64 + lane], v);
  if (lane == 0) atomicAdd(&cnt[a], 1.0f);
}

// ---------------- centroid update --------------------------------------------
__global__ void centup_k(float* __restrict__ cent, const float* __restrict__ sums,
                         const float* __restrict__ cnt) {
  int i = blockIdx.x * 256 + threadIdx.x;  // 65536 total
  int j = i >> 6;
  float c = cnt[j];
  if (c > 0.f) cent[i] = sums[i] / fmaxf(c, 1.f);
}

// ---------------- per-bh top-1024 by descending dist (stable ties) -----------
__global__ __launch_bounds__(1024) void topk_k(const float* __restrict__ dist,
                                               int* __restrict__ sel) {
  __shared__ unsigned long long keys[2048];
  int bh = blockIdx.x, t = threadIdx.x;
  for (int i = t; i < 2048; i += 1024) {
    float d = dist[bh * 2048 + i];
    unsigned int db = __float_as_uint(d);  // d >= 0 -> monotonic
    keys[i] = ((unsigned long long)db << 32) | (unsigned int)(2047 - i);
  }
  __syncthreads();
  for (int k = 2; k <= 2048; k <<= 1) {
    for (int j = k >> 1; j > 0; j >>= 1) {
      for (int i = t; i < 2048; i += 1024) {
        int ixj = i ^ j;
        if (ixj > i) {
          unsigned long long a = keys[i], b = keys[ixj];
          bool up = ((i & k) == 0);
          bool sw = up ? (a < b) : (a > b);  // descending overall
          if (sw) { keys[i] = b; keys[ixj] = a; }
        }
      }
      __syncthreads();
    }
  }
  if (t < 1024) sel[bh * 1024 + t] = 2047 - (int)(keys[t] & 0xffffffffu);
}

// ---------------- gather selected rows -> kh (bf16 row-major), vT (bf16 d-major)
__global__ void gatherb_k(const float* __restrict__ kbuf, const float* __restrict__ vbuf,
                          const int* __restrict__ sel, unsigned short* __restrict__ kh,
                          unsigned short* __restrict__ vT) {
  __shared__ unsigned short tile[64][66];
  int t = threadIdx.x, lane = t & 63, wv = t >> 6;
  int bh = blockIdx.y, i0 = blockIdx.x * 64;
  for (int r = 0; r < 16; ++r) {
    int i = r * 4 + wv;
    int src = sel[bh * 1024 + i0 + i];
    float kvv = kbuf[((size_t)bh * 2048 + src) * 64 + lane];
    kh[((size_t)bh * 1024 + i0 + i) * 64 + lane] = f2bf(kvv);
    float vv = vbuf[((size_t)bh * 2048 + src) * 64 + lane];
    tile[i][lane] = f2bf(vv);
  }
  __syncthreads();
  for (int r = 0; r < 16; ++r) {
    int d = r * 4 + wv;
    vT[((size_t)bh * 64 + d) * 1024 + i0 + lane] = tile[lane][d];
  }
}

// ---------------- f32 -> bf16 bulk convert -----------------------------------
__global__ void tobf_k(const float* __restrict__ x, unsigned short* __restrict__ y) {
  int i = blockIdx.x * 256 + threadIdx.x;
  float4 v = ((const float4*)x)[i];
  us4 o = {f2bf(v.x), f2bf(v.y), f2bf(v.z), f2bf(v.w)};
  *(us4*)(y + (size_t)i * 4) = o;
}

// ---------------- MFMA flash attention (K/V LDS-staged, barrier-light) -------
__global__ __launch_bounds__(256) void attn_mfma_k(
    const unsigned short* __restrict__ qh, const unsigned short* __restrict__ kh,
    const unsigned short* __restrict__ vT,
    unsigned short* __restrict__ oh, unsigned short* __restrict__ ol) {
  __shared__ __align__(16) unsigned short kvlds[2][2][4096];  // [buf][K/V][64x64]
  __shared__ unsigned short plds[4][16][72];
  int t = threadIdx.x, lane = t & 63, wv = t >> 6;
  int lq = lane & 15, lg = lane >> 4;
  int bh = blockIdx.y;
  int q0 = blockIdx.x * 64 + wv * 16;
  const unsigned short* qbase = qh + ((size_t)bh * 4096 + q0 + lq) * 64;
  bfx8 qf0 = *(const bfx8*)(qbase + lg * 8);
  bfx8 qf1 = *(const bfx8*)(qbase + 32 + lg * 8);
  fx4 acc[4];
  for (int nt = 0; nt < 4; ++nt) acc[nt] = (fx4){0.f, 0.f, 0.f, 0.f};
  float lsum = 0.f;
  const unsigned short* kbase = kh + (size_t)bh * 1024 * 64;
  const unsigned short* vbase = vT + (size_t)bh * 64 * 1024;

  int srow = t >> 2;
  int scolb = (t & 3) * 32;
  const char* gK = (const char*)kbase + (size_t)srow * 128 + scolb;   // + s*8192
  const char* gV = (const char*)vbase + (size_t)srow * 2048 + scolb;  // + s*128
  int sw_w = (srow & 7) << 4;
  int wb0 = srow * 128 + (scolb ^ sw_w);
  int wb1 = srow * 128 + ((scolb + 16) ^ sw_w);

  {
    uint4 k0 = *(const uint4*)(gK);
    uint4 k1 = *(const uint4*)(gK + 16);
    uint4 v0 = *(const uint4*)(gV);
    uint4 v1 = *(const uint4*)(gV + 16);
    *(uint4*)((char*)&kvlds[0][0][0] + wb0) = k0;
    *(uint4*)((char*)&kvlds[0][0][0] + wb1) = k1;
    *(uint4*)((char*)&kvlds[0][1][0] + wb0) = v0;
    *(uint4*)((char*)&kvlds[0][1][0] + wb1) = v1;
  }

  int swr = (lq & 7) << 4;
  int rc0 = (lg * 16) ^ swr;
  int rc1 = (64 + lg * 16) ^ swr;

  for (int s = 0; s < 16; ++s) {
    int cur = s & 1;
    __syncthreads();
    uint4 nk0, nk1, nv0, nv1;
    if (s < 15) {
      const char* gKn = gK + (size_t)(s + 1) * 8192;
      const char* gVn = gV + (size_t)(s + 1) * 128;
      nk0 = *(const uint4*)(gKn);
      nk1 = *(const uint4*)(gKn + 16);
      nv0 = *(const uint4*)(gVn);
      nv1 = *(const uint4*)(gVn + 16);
    }
    __builtin_amdgcn_sched_barrier(0);
    const char* Kb = (const char*)&kvlds[cur][0][0];
    const char* Vb = (const char*)&kvlds[cur][1][0];
    fx4 sS[4];
#pragma unroll
    for (int mt = 0; mt < 4; ++mt) {
      int rowb = (mt * 16 + lq) * 128;
      bfx8 a0 = *(const bfx8*)(Kb + rowb + rc0);
      bfx8 a1 = *(const bfx8*)(Kb + rowb + rc1);
      fx4 c = (fx4){0.f, 0.f, 0.f, 0.f};
      c = __builtin_amdgcn_mfma_f32_16x16x32_bf16(a0, qf0, c, 0, 0, 0);
      c = __builtin_amdgcn_mfma_f32_16x16x32_bf16(a1, qf1, c, 0, 0, 0);
      sS[mt] = c;
    }
#pragma unroll
    for (int mt = 0; mt < 4; ++mt) {
      float p0 = __expf(sS[mt].x), p1 = __expf(sS[mt].y);
      float p2 = __expf(sS[mt].z), p3 = __expf(sS[mt].w);
      lsum += (p0 + p1) + (p2 + p3);
      us4 pk = {f2bf(p0), f2bf(p1), f2bf(p2), f2bf(p3)};
      *(us4*)&plds[wv][lq][mt * 16 + lg * 4] = pk;
    }
    bfx8 pa0 = *(const bfx8*)&plds[wv][lq][lg * 8];
    bfx8 pa1 = *(const bfx8*)&plds[wv][lq][32 + lg * 8];
#pragma unroll
    for (int nt = 0; nt < 4; ++nt) {
      int rowb = (nt * 16 + lq) * 128;
      bfx8 b0 = *(const bfx8*)(Vb + rowb + rc0);
      bfx8 b1 = *(const bfx8*)(Vb + rowb + rc1);
      acc[nt] = __builtin_amdgcn_mfma_f32_16x16x32_bf16(pa0, b0, acc[nt], 0, 0, 0);
      acc[nt] = __builtin_amdgcn_mfma_f32_16x16x32_bf16(pa1, b1, acc[nt], 0, 0, 0);
    }
    __builtin_amdgcn_sched_barrier(0);
    if (s < 15) {
      char* dK = (char*)&kvlds[cur ^ 1][0][0];
      char* dV = (char*)&kvlds[cur ^ 1][1][0];
      *(uint4*)(dK + wb0) = nk0;
      *(uint4*)(dK + wb1) = nk1;
      *(uint4*)(dV + wb0) = nv0;
      *(uint4*)(dV + wb1) = nv1;
    }
  }
  lsum += __shfl_xor(lsum, 16);
  lsum += __shfl_xor(lsum, 32);
  int bi = bh >> 3, hd = bh & 7;
  for (int r = 0; r < 4; ++r) {
    float inv = 1.f / __shfl(lsum, lg * 4 + r);
    size_t rowb = ((size_t)bi * 4096 + q0 + lg * 4 + r) * 512 + hd * 64;
    for (int nt = 0; nt < 4; ++nt) {
      float val = acc[nt][r] * inv;
      unsigned short hb = f2h_bits(val);
      oh[rowb + nt * 16 + lq] = hb;
      ol[rowb + nt * 16 + lq] = f2h_bits((val - h_bits2f(hb)) * 2048.f);
    }
  }
}

// ---------------- final LN + gamma*ln + residual (wave-split channels) -------
__global__ __launch_bounds__(256) void final_k(
    const float* __restrict__ y, const float* __restrict__ g,
    const float* __restrict__ bta, const float* __restrict__ gamma,
    const float* __restrict__ qs, float* __restrict__ out) {
  __shared__ float p1[4][64], p2[4][64];
  __shared__ float mArr[64], invArr[64];
  int t = threadIdx.x, lane = t & 63, wv = t >> 6;
  int n0 = blockIdx.x * 64, bi = blockIdx.y;
  const float* yb = y + (size_t)bi * CDIM * NQ + n0 + lane;
  float s = 0.f, s2 = 0.f;
  for (int cl = 0; cl < 64; ++cl) {
    float v = yb[(size_t)(wv * 64 + cl) * NQ];
    s += v;
    s2 += v * v;
  }
  p1[wv][lane] = s;
  p2[wv][lane] = s2;
  __syncthreads();
  if (t < 64) {
    float ts = p1[0][t] + p1[1][t] + p1[2][t] + p1[3][t];
    float ts2 = p2[0][t] + p2[1][t] + p2[2][t] + p2[3][t];
    float m = ts / CDIM;
    float var = ts2 / CDIM - m * m;
    mArr[t] = m;
    invArr[t] = 1.f / (sqrtf(fmaxf(var, 0.f)) + 1e-6f);
  }
  __syncthreads();
  float gm = gamma[0];
  float m = mArr[lane], inv = invArr[lane];
  const float* qb = qs + (size_t)bi * CDIM * NQ + n0 + lane;
  float* ob = out + (size_t)bi * CDIM * NQ + n0 + lane;
  for (int cl = 0; cl < 64; ++cl) {
    int c = wv * 64 + cl;
    float v = yb[(size_t)c * NQ];
    float ln = g[c] * (v - m) * inv + bta[c];
    ob[(size_t)c * NQ] = gm * ln + qb[(size_t)c * NQ];
  }
}

extern "C" void kernel_launch(void* const* d_in, const int* in_sizes, int n_in,
                              void* d_out, int out_size, void* d_ws, size_t ws_size,
                              hipStream_t stream) {
  const float* qsrc = (const float*)d_in[0];
  const float* ctx = (const float*)d_in[1];
  const float* w_q = (const float*)d_in[2];
  const float* w_kv = (const float*)d_in[3];
  const float* w_out = (const float*)d_in[4];
  const float* cn_g = (const float*)d_in[5];
  const float* cn_b = (const float*)d_in[6];
  const float* qn_g = (const float*)d_in[7];
  const float* qn_b = (const float*)d_in[8];
  const float* on_g = (const float*)d_in[9];
  const float* on_b = (const float*)d_in[10];
  const float* gamma = (const float*)d_in[11];

  // scratch layout (floats); total 22,267,904 floats = 89.1 MB
  if (ws_size < (size_t)22267904 * 4) return;
  float* ws = (float*)d_ws;
  float* r_ctx = ws;                      // 1,048,576 f: ctx split-f16; later kh/vT
  float* r_kv = r_ctx + 1048576;          // 4,194,304 f: kv f32; later kbh/kbl; later attnt split
  float* r_qs = r_kv + 4194304;           // 2,097,152 f: qs split-f16; later cb2h/l, ybuf
  float* r_q3 = r_qs + 2097152;           // 4,194,304 f: q3 f32; later qbh/qbl
  float* qbuf = r_q3 + 4194304;           // 4,194,304 f
  float* kbuf = qbuf + 4194304;           // 2,097,152 f
  float* vbuf = kbuf + 2097152;           // 2,097,152 f
  float* cent = vbuf + 2097152;           // 65,536 f
  float* csq = cent + 65536;              // 1,024 f
  float* sums = csq + 1024;               // 65,536 f
  float* cnt = sums + 65536;              // 1,024 f
  int* asg = (int*)(cnt + 1024);          // 65,536 i
  float* dist = (float*)(asg + 65536);    // 32,768 f
  int* sel = (int*)(dist + 32768);        // 16,384 i
  float* kgreg = (float*)(sel + 16384);   // 2,097,152 f (qh bf16)

  unsigned short* ctxth = (unsigned short*)r_ctx;   // [b][2048][256] f16 hi
  unsigned short* ctxtl = ctxth + (size_t)BB * NK * CDIM;  // lo
  unsigned short* qsth = (unsigned short*)r_qs;     // [b][4096][256] f16 hi
  unsigned short* qstl = qsth + (size_t)BB * NQ * CDIM;    // lo
  float* kvf = r_kv;                      // [b][1024][2048] f32
  float* q3f = r_q3;                      // [b][512][4096] f32
  unsigned short* qh = (unsigned short*)kgreg;      // 4M bf16
  unsigned short* kh = (unsigned short*)r_ctx;      // 1M bf16 (ctx split dead)
  unsigned short* vT = kh + 1048576;                // 1M bf16
  unsigned short* qbh = (unsigned short*)r_q3;      // 4M f16 (q split hi)
  unsigned short* qbl = qbh + (size_t)NPQ * 64;     // 4M f16 (lo)
  unsigned short* kbh = (unsigned short*)r_kv;      // 2M f16 (k split hi)
  unsigned short* kbl = kbh + (size_t)NPK * 64;     // 2M f16 (lo)
  unsigned short* cb2h = (unsigned short*)r_qs;     // 64K f16 (-2c hi)
  unsigned short* cb2l = cb2h + 65536;              // 64K f16 (lo)
  unsigned short* attnth = (unsigned short*)r_kv;   // [b][4096][512] f16 hi (kb split dead)
  unsigned short* attntl = attnth + (size_t)BB * NQ * 512;  // lo
  float* ybuf = r_qs;                     // [b][256][4096] f32 (cb2 dead)

  // 1. channel LayerNorms -> transposed split-f16
  chan_ln_tsplit_k<<<dim3(NK / 64, BB), 256, 0, stream>>>(ctx, cn_g, cn_b, ctxth, ctxtl, CDIM, NK);
  chan_ln_tsplit_k<<<dim3(NQ / 64, BB), 256, 0, stream>>>(qsrc, qn_g, qn_b, qsth, qstl, CDIM, NQ);
  // 2. MFMA projections
  gemm_mfma_k<<<dim3(NK / 64, 1024 / 64, BB), 256, 0, stream>>>(w_kv, ctxth, ctxtl, kvf, 1024, CDIM, NK);
  gemm_mfma_k<<<dim3(NQ / 64, 512 / 64, BB), 256, 0, stream>>>(w_q, qsth, qstl, q3f, 512, CDIM, NQ);
  // 3. fold heads (+L2-normalize q,k)
  fold_k<<<dim3(NQ / 64, 8, BB), 256, 0, stream>>>(q3f, qbuf, 512 * NQ, 0, NQ, 1);
  fold_k<<<dim3(NK / 64, 8, BB), 256, 0, stream>>>(kvf, kbuf, 1024 * NK, 0, NK, 1);
  fold_k<<<dim3(NK / 64, 8, BB), 256, 0, stream>>>(kvf, vbuf, 1024 * NK, 512, NK, 0);
  // 4. split-f16 conversions (q3/kv f32 regions now reusable)
  tof2_k<<<NPQ * 64 / 1024, 256, 0, stream>>>(qbuf, qbh, qbl);
  tof2_k<<<NPK * 64 / 1024, 256, 0, stream>>>(kbuf, kbh, kbl);
  // 5. k-means (init = first 1024 q rows); separate coalesced segsum
  hipMemcpyAsync(cent, qbuf, 65536 * sizeof(float), hipMemcpyDeviceToDevice, stream);
  for (int it = 0; it < 4; ++it) {
    centprep_k<<<1024, 64, 0, stream>>>(cent, csq, cb2h, cb2l);
    hipMemsetAsync(sums, 0, (65536 + 1024) * sizeof(float), stream);
    assign_mfma_k<<<NPQ / 64, 256, 0, stream>>>(qbh, qbl, cb2h, cb2l, csq, asg);
    segsum_k<<<NPQ / 4, 256, 0, stream>>>(qbuf, asg, sums, cnt);
    centup_k<<<65536 / 256, 256, 0, stream>>>(cent, sums, cnt);
  }
  // 6. score keys: argmin (MFMA) -> exact f32 L1 dist -> per-head top-1024
  centprep_k<<<1024, 64, 0, stream>>>(cent, csq, cb2h, cb2l);
  assign_mfma_k<<<NPK / 64, 256, 0, stream>>>(kbh, kbl, cb2h, cb2l, csq, asg);
  dist_k<<<NPK / 4, 256, 0, stream>>>(kbuf, cent, asg, dist);
  topk_k<<<BH, 1024, 0, stream>>>(dist, sel);
  // 7. bf16 conversions + gather (kh row-major, vT transposed)
  tobf_k<<<NPQ * 64 / 1024, 256, 0, stream>>>(qbuf, qh);
  gatherb_k<<<dim3(TOPK / 64, BH), 256, 0, stream>>>(kbuf, vbuf, sel, kh, vT);
  // 8. MFMA attention -> split-f16 un-folded [b][n][512]
  attn_mfma_k<<<dim3(NQ / 64, BH), 256, 0, stream>>>(qh, kh, vT, attnth, attntl);
  // 9. output projection (MFMA)
  gemm_mfma_k<<<dim3(NQ / 64, 256 / 64, BB), 256, 0, stream>>>(w_out, attnth, attntl, ybuf, 256, 512, NQ);
  // 10. final LN + residual
  final_k<<<dim3(NQ / 64, BB), 256, 0, stream>>>(ybuf, on_g, on_b, gamma, qsrc, (float*)d_out);
}

// Round 11
// 616.783 us; speedup vs baseline: 1.6153x; 1.0044x over previous
//
#include <hip/hip_runtime.h>
#include <math.h>

#define BB 2
#define CDIM 256
#define NQ 4096   // 16*16*16
#define NK 2048   // 8*16*16
#define BH 16
#define TOPK 1024
#define NPQ (BH*NQ)   // 65536
#define NPK (BH*NK)   // 32768

typedef __attribute__((ext_vector_type(8))) short bfx8;
typedef __attribute__((ext_vector_type(8))) _Float16 hfx8;
typedef __attribute__((ext_vector_type(4))) float fx4;
typedef __attribute__((ext_vector_type(4))) unsigned short us4;

__device__ inline unsigned short f2bf(float x) {
  unsigned u = __float_as_uint(x);
  return (unsigned short)((u + 0x7fffu + ((u >> 16) & 1u)) >> 16);
}
__device__ inline unsigned short f2h_bits(float x) {
  _Float16 h = (_Float16)x;
  unsigned short u;
  __builtin_memcpy(&u, &h, 2);
  return u;
}
__device__ inline float h_bits2f(unsigned short u) {
  _Float16 h;
  __builtin_memcpy(&h, &u, 2);
  return (float)h;
}

// ------- channel LayerNorm -> transposed split-f16 [b][n][C] (hi, lo*2048) ---
__global__ __launch_bounds__(256) void chan_ln_tsplit_k(
    const float* __restrict__ x, const float* __restrict__ g,
    const float* __restrict__ bta, unsigned short* __restrict__ yh,
    unsigned short* __restrict__ yl, int C, int N) {
  __shared__ float tile[4][64][65];
  __shared__ float p1[4][64], p2[4][64];
  __shared__ float mArr[64], invArr[64];
  int t = threadIdx.x, lane = t & 63, wv = t >> 6;
  int n0 = blockIdx.x * 64, bi = blockIdx.y;
  const float* xb = x + (size_t)bi * C * N + n0 + lane;
  float s = 0.f, s2 = 0.f;
  for (int cl = 0; cl < 64; ++cl) {
    float v = xb[(size_t)(wv * 64 + cl) * N];
    tile[wv][cl][lane] = v;
    s += v;
    s2 += v * v;
  }
  p1[wv][lane] = s;
  p2[wv][lane] = s2;
  __syncthreads();
  if (t < 64) {
    float ts = p1[0][t] + p1[1][t] + p1[2][t] + p1[3][t];
    float ts2 = p2[0][t] + p2[1][t] + p2[2][t] + p2[3][t];
    float m = ts / C;
    float var = ts2 / C - m * m;
    mArr[t] = m;
    invArr[t] = 1.f / (sqrtf(fmaxf(var, 0.f)) + 1e-6f);
  }
  __syncthreads();
  int c = wv * 64 + lane;  // lane = channel in phase 2
  float gc = g[c], bc = bta[c];
  unsigned short* ohb = yh + ((size_t)bi * N + n0) * C + c;
  unsigned short* olb = yl + ((size_t)bi * N + n0) * C + c;
  for (int pl = 0; pl < 64; ++pl) {
    float v = tile[wv][lane][pl];
    float ln = gc * (v - mArr[pl]) * invArr[pl] + bc;
    unsigned short hb = f2h_bits(ln);
    ohb[(size_t)pl * C] = hb;
    olb[(size_t)pl * C] = f2h_bits((ln - h_bits2f(hb)) * 2048.f);
  }
}

// ------- MFMA GEMM: Y[b][o][n] = sum_c W[o][c] * Xt[b][n][c] -----------------
__global__ __launch_bounds__(256) void gemm_mfma_k(
    const float* __restrict__ W, const unsigned short* __restrict__ Xh,
    const unsigned short* __restrict__ Xl, float* __restrict__ Y,
    int O, int C, int N) {
  int t = threadIdx.x, lane = t & 63, wv = t >> 6;
  int lq = lane & 15, lg = lane >> 4;
  int n0 = blockIdx.x * 64, o0 = blockIdx.y * 64 + wv * 16;
  int b = blockIdx.z;
  const unsigned short* xbh = Xh + ((size_t)b * N + n0) * C;
  const unsigned short* xbl = Xl + ((size_t)b * N + n0) * C;
  const float* wr = W + (size_t)(o0 + lq) * C;
  fx4 ahi[4], alo[4];
  for (int nt = 0; nt < 4; ++nt) {
    ahi[nt] = (fx4){0.f, 0.f, 0.f, 0.f};
    alo[nt] = (fx4){0.f, 0.f, 0.f, 0.f};
  }
  for (int k0 = 0; k0 < C; k0 += 32) {
    float4 w0 = *(const float4*)(wr + k0 + lg * 8);
    float4 w1 = *(const float4*)(wr + k0 + lg * 8 + 4);
    float wv8[8] = {w0.x, w0.y, w0.z, w0.w, w1.x, w1.y, w1.z, w1.w};
    hfx8 ah, al;
#pragma unroll
    for (int i = 0; i < 8; ++i) {
      _Float16 h = (_Float16)wv8[i];
      ah[i] = h;
      al[i] = (_Float16)((wv8[i] - (float)h) * 2048.f);
    }
#pragma unroll
    for (int nt = 0; nt < 4; ++nt) {
      const unsigned short* bph = xbh + (size_t)(nt * 16 + lq) * C + k0 + lg * 8;
      const unsigned short* bpl = xbl + (size_t)(nt * 16 + lq) * C + k0 + lg * 8;
      hfx8 bh = *(const hfx8*)bph;
      hfx8 bl = *(const hfx8*)bpl;
      ahi[nt] = __builtin_amdgcn_mfma_f32_16x16x32_f16(ah, bh, ahi[nt], 0, 0, 0);
      alo[nt] = __builtin_amdgcn_mfma_f32_16x16x32_f16(al, bh, alo[nt], 0, 0, 0);
      alo[nt] = __builtin_amdgcn_mfma_f32_16x16x32_f16(ah, bl, alo[nt], 0, 0, 0);
    }
  }
  float* yb = Y + ((size_t)b * O + o0) * N + n0;
#pragma unroll
  for (int nt = 0; nt < 4; ++nt)
#pragma unroll
    for (int r = 0; r < 4; ++r)
      yb[(size_t)(lg * 4 + r) * N + nt * 16 + lq] = ahi[nt][r] + alo[nt][r] * (1.f / 2048.f);
}

// ---------------- fold heads: (b, ch, n) -> (bh, n, 64), optional L2 norm ----
__global__ void fold_k(const float* __restrict__ src, float* __restrict__ dst,
                       int bstride, int choff, int N, int donorm) {
  __shared__ float tile[64 * 65];
  __shared__ float part[4 * 64];
  __shared__ float invn[64];
  int t = threadIdx.x;
  int lane = t & 63, wv = t >> 6;
  int n0 = blockIdx.x * 64;
  int h = blockIdx.y, bi = blockIdx.z;
  const float* sb = src + (size_t)bi * bstride + (size_t)(choff + h * 64) * N + n0;
  for (int r = 0; r < 16; ++r) {
    int d = r * 4 + wv;
    tile[d * 65 + lane] = sb[(size_t)d * N + lane];
  }
  __syncthreads();
  if (donorm) {
    float s = 0.f;
    for (int r = 0; r < 16; ++r) {
      float v = tile[(wv + 4 * r) * 65 + lane];
      s += v * v;
    }
    part[wv * 64 + lane] = s;
    __syncthreads();
    if (t < 64) {
      float tot = part[t] + part[64 + t] + part[128 + t] + part[192 + t];
      invn[t] = 1.f / fmaxf(sqrtf(tot), 1e-12f);
    }
    __syncthreads();
  }
  float* db = dst + ((size_t)(bi * 8 + h) * N + n0) * 64;
  for (int r = 0; r < 16; ++r) {
    int nn = r * 4 + wv;
    float v = tile[lane * 65 + nn];
    if (donorm) v *= invn[nn];
    db[(size_t)nn * 64 + lane] = v;
  }
}

// ---------------- f32 -> split f16 (hi + lo*2048) ----------------------------
__global__ void tof2_k(const float* __restrict__ x, unsigned short* __restrict__ yh,
                       unsigned short* __restrict__ yl) {
  int i = blockIdx.x * 256 + threadIdx.x;
  float4 v = ((const float4*)x)[i];
  us4 h = {f2h_bits(v.x), f2h_bits(v.y), f2h_bits(v.z), f2h_bits(v.w)};
  us4 l = {f2h_bits((v.x - h_bits2f(h.x)) * 2048.f),
           f2h_bits((v.y - h_bits2f(h.y)) * 2048.f),
           f2h_bits((v.z - h_bits2f(h.z)) * 2048.f),
           f2h_bits((v.w - h_bits2f(h.w)) * 2048.f)};
  *(us4*)(yh + (size_t)i * 4) = h;
  *(us4*)(yl + (size_t)i * 4) = l;
}

// ---------------- centroid prep (initial only): csq, -2c split f16 -----------
__global__ void centprep_k(const float* __restrict__ cent, float* __restrict__ csq,
                           unsigned short* __restrict__ cb2h, unsigned short* __restrict__ cb2l) {
  int j = blockIdx.x, lane = threadIdx.x;  // blockDim = 64
  float c = cent[j * 64 + lane];
  float s = c * c;
  for (int off = 32; off; off >>= 1) s += __shfl_xor(s, off);
  if (lane == 0) csq[j] = s;
  float m2 = -2.f * c;
  unsigned short h = f2h_bits(m2);
  cb2h[j * 64 + lane] = h;
  cb2l[j * 64 + lane] = f2h_bits((m2 - h_bits2f(h)) * 2048.f);
}

// ---------------- MFMA nearest-centroid assign (f16 split, LDS-staged) -------
// DUO=1: each wave owns TWO 16-point groups sharing the staged centroid tile
// (12 MFMA per barrier, 128 pts/block). DUO=0: 64 pts/block (key scoring).
// Per-candidate arithmetic identical to the verified R7 kernel.
template <int DUO>
__global__ __launch_bounds__(256) void assign_mfma_k(
    const unsigned short* __restrict__ xh, const unsigned short* __restrict__ xl,
    const unsigned short* __restrict__ cb2h, const unsigned short* __restrict__ cb2l,
    const float* __restrict__ csq, int* __restrict__ aout) {
  __shared__ __align__(16) unsigned short clds[2][2][1024];  // [buf][hi/lo][16x64]
  int t = threadIdx.x, lane = t & 63, wv = t >> 6;
  int lq = lane & 15, lg = lane >> 4;
  int p0 = blockIdx.x * (DUO ? 128 : 64) + wv * (DUO ? 32 : 16);
  const unsigned short* xbA = xh + (size_t)(p0 + lq) * 64;
  const unsigned short* xlA = xl + (size_t)(p0 + lq) * 64;
  hfx8 ba0 = *(const hfx8*)(xbA + lg * 8);
  hfx8 ba1 = *(const hfx8*)(xbA + 32 + lg * 8);
  hfx8 la0 = *(const hfx8*)(xlA + lg * 8);
  hfx8 la1 = *(const hfx8*)(xlA + 32 + lg * 8);
  hfx8 bb0, bb1, lb0, lb1;
  if (DUO) {
    const unsigned short* xbB = xh + (size_t)(p0 + 16 + lq) * 64;
    const unsigned short* xlB = xl + (size_t)(p0 + 16 + lq) * 64;
    bb0 = *(const hfx8*)(xbB + lg * 8);
    bb1 = *(const hfx8*)(xbB + 32 + lg * 8);
    lb0 = *(const hfx8*)(xlB + lg * 8);
    lb1 = *(const hfx8*)(xlB + 32 + lg * 8);
  }

  int part = t >> 7;
  int abyte = (t & 127) * 16;
  int wbyte = abyte ^ (((abyte >> 7) & 7) << 4);
  const unsigned short* gsrc = (part ? cb2l : cb2h) + (abyte >> 1);
  int rowoff = lq * 128;
  int x0 = (lg * 16) ^ ((lq & 7) << 4);
  int x1 = (64 + lg * 16) ^ ((lq & 7) << 4);

  float bestA = 3.4e38f, bestB = 3.4e38f;
  int jA = 0, jB = 0;

  uint4 r0 = *(const uint4*)(gsrc);
  *(uint4*)((char*)&clds[0][part][0] + wbyte) = r0;

  for (int s = 0; s < 64; ++s) {
    int cur = s & 1;
    __syncthreads();
    uint4 rn;
    if (s < 63) rn = *(const uint4*)(gsrc + (size_t)(s + 1) * 1024);
    __builtin_amdgcn_sched_barrier(0);
    const char* ph = (const char*)&clds[cur][0][0];
    const char* pl = (const char*)&clds[cur][1][0];
    hfx8 ah0 = *(const hfx8*)(ph + rowoff + x0);
    hfx8 ah1 = *(const hfx8*)(ph + rowoff + x1);
    hfx8 al0 = *(const hfx8*)(pl + rowoff + x0);
    hfx8 al1 = *(const hfx8*)(pl + rowoff + x1);
    fx4 cq = *(const fx4*)(csq + s * 16 + lg * 4);
    {
      fx4 chi = cq;
      chi = __builtin_amdgcn_mfma_f32_16x16x32_f16(ah0, ba0, chi, 0, 0, 0);
      chi = __builtin_amdgcn_mfma_f32_16x16x32_f16(ah1, ba1, chi, 0, 0, 0);
      fx4 clo = (fx4){0.f, 0.f, 0.f, 0.f};
      clo = __builtin_amdgcn_mfma_f32_16x16x32_f16(ah0, la0, clo, 0, 0, 0);
      clo = __builtin_amdgcn_mfma_f32_16x16x32_f16(ah1, la1, clo, 0, 0, 0);
      clo = __builtin_amdgcn_mfma_f32_16x16x32_f16(al0, ba0, clo, 0, 0, 0);
      clo = __builtin_amdgcn_mfma_f32_16x16x32_f16(al1, ba1, clo, 0, 0, 0);
#pragma unroll
      for (int r_ = 0; r_ < 4; ++r_) {
        int j_ = s * 16 + lg * 4 + r_;
        float d2_ = chi[r_] + clo[r_] * (1.f / 2048.f);
        if (d2_ < bestA) { bestA = d2_; jA = j_; }
      }
    }
    if (DUO) {
      fx4 chi = cq;
      chi = __builtin_amdgcn_mfma_f32_16x16x32_f16(ah0, bb0, chi, 0, 0, 0);
      chi = __builtin_amdgcn_mfma_f32_16x16x32_f16(ah1, bb1, chi, 0, 0, 0);
      fx4 clo = (fx4){0.f, 0.f, 0.f, 0.f};
      clo = __builtin_amdgcn_mfma_f32_16x16x32_f16(ah0, lb0, clo, 0, 0, 0);
      clo = __builtin_amdgcn_mfma_f32_16x16x32_f16(ah1, lb1, clo, 0, 0, 0);
      clo = __builtin_amdgcn_mfma_f32_16x16x32_f16(al0, bb0, clo, 0, 0, 0);
      clo = __builtin_amdgcn_mfma_f32_16x16x32_f16(al1, bb1, clo, 0, 0, 0);
#pragma unroll
      for (int r_ = 0; r_ < 4; ++r_) {
        int j_ = s * 16 + lg * 4 + r_;
        float d2_ = chi[r_] + clo[r_] * (1.f / 2048.f);
        if (d2_ < bestB) { bestB = d2_; jB = j_; }
      }
    }
    __builtin_amdgcn_sched_barrier(0);
    if (s < 63) *(uint4*)((char*)&clds[cur ^ 1][part][0] + wbyte) = rn;
  }

  {
    float o = __shfl_xor(bestA, 16);
    int oj = __shfl_xor(jA, 16);
    if (o < bestA || (o == bestA && oj < jA)) { bestA = o; jA = oj; }
    o = __shfl_xor(bestA, 32);
    oj = __shfl_xor(jA, 32);
    if (o < bestA || (o == bestA && oj < jA)) { bestA = o; jA = oj; }
  }
  if (DUO) {
    float o = __shfl_xor(bestB, 16);
    int oj = __shfl_xor(jB, 16);
    if (o < bestB || (o == bestB && oj < jB)) { bestB = o; jB = oj; }
    o = __shfl_xor(bestB, 32);
    oj = __shfl_xor(jB, 32);
    if (o < bestB || (o == bestB && oj < jB)) { bestB = o; jB = oj; }
  }
  if (lg == 0) {
    aout[p0 + lq] = jA;
    if (DUO) aout[p0 + 16 + lq] = jB;
  }
}

// ---------------- exact f32 L1 distance to assigned centroid -----------------
__global__ void dist_k(const float* __restrict__ x, const float* __restrict__ cent,
                       const int* __restrict__ asg, float* __restrict__ dout) {
  int t = threadIdx.x, lane = t & 63, wv = t >> 6;
  int p = blockIdx.x * 4 + wv;
  int a = asg[p];
  float v = fabsf(cent[(size_t)a * 64 + lane] - x[(size_t)p * 64 + lane]);
  for (int off = 32; off; off >>= 1) v += __shfl_xor(v, off);
  if (lane == 0) dout[p] = v;
}

// ---------------- segment sum via atomics (wave=point: coalesced) ------------
__global__ void segsum_k(const float* __restrict__ x, const int* __restrict__ asg,
                         float* __restrict__ sums, float* __restrict__ cnt) {
  int t = threadIdx.x, lane = t & 63, wv = t >> 6;
  int p = blockIdx.x * 4 + wv;
  int a = asg[p];
  float v = x[(size_t)p * 64 + lane];
  atomicAdd(&sums[a * 64 + lane], v);
  if (lane == 0) atomicAdd(&cnt[a], 1.0f);
}

// ---------------- centroid update + prep + zero (fused) ----------------------
// Computes new centroid, csq (identical 64-lane butterfly as centprep_k),
// -2c split-f16, then zeroes sums/cnt for the next iteration.
__global__ __launch_bounds__(256) void centup_prep_k(
    float* __restrict__ cent, float* __restrict__ sums, float* __restrict__ cnt,
    float* __restrict__ csq, unsigned short* __restrict__ cb2h,
    unsigned short* __restrict__ cb2l) {
  int i = blockIdx.x * 256 + threadIdx.x;  // 65536 total; rows never span blocks
  int j = i >> 6, lane = threadIdx.x & 63;
  float c = cnt[j];
  float oldc = cent[i];
  float newc = (c > 0.f) ? sums[i] / fmaxf(c, 1.f) : oldc;
  cent[i] = newc;
  float s = newc * newc;
  for (int off = 32; off; off >>= 1) s += __shfl_xor(s, off);
  if (lane == 0) csq[j] = s;
  float m2 = -2.f * newc;
  unsigned short h = f2h_bits(m2);
  cb2h[i] = h;
  cb2l[i] = f2h_bits((m2 - h_bits2f(h)) * 2048.f);
  // zero for next iteration (all reads above precede these writes in-wave)
  sums[i] = 0.f;
  if (lane == 0) cnt[j] = 0.f;
}

// ---------------- per-bh top-1024 by descending dist (stable ties) -----------
__global__ __launch_bounds__(1024) void topk_k(const float* __restrict__ dist,
                                               int* __restrict__ sel) {
  __shared__ unsigned long long keys[2048];
  int bh = blockIdx.x, t = threadIdx.x;
  for (int i = t; i < 2048; i += 1024) {
    float d = dist[bh * 2048 + i];
    unsigned int db = __float_as_uint(d);  // d >= 0 -> monotonic
    keys[i] = ((unsigned long long)db << 32) | (unsigned int)(2047 - i);
  }
  __syncthreads();
  for (int k = 2; k <= 2048; k <<= 1) {
    for (int j = k >> 1; j > 0; j >>= 1) {
      for (int i = t; i < 2048; i += 1024) {
        int ixj = i ^ j;
        if (ixj > i) {
          unsigned long long a = keys[i], b = keys[ixj];
          bool up = ((i & k) == 0);
          bool sw = up ? (a < b) : (a > b);  // descending overall
          if (sw) { keys[i] = b; keys[ixj] = a; }
        }
      }
      __syncthreads();
    }
  }
  if (t < 1024) sel[bh * 1024 + t] = 2047 - (int)(keys[t] & 0xffffffffu);
}

// ---------------- gather selected rows -> kh (bf16 row-major), vT (bf16 d-major)
__global__ void gatherb_k(const float* __restrict__ kbuf, const float* __restrict__ vbuf,
                          const int* __restrict__ sel, unsigned short* __restrict__ kh,
                          unsigned short* __restrict__ vT) {
  __shared__ unsigned short tile[64][66];
  int t = threadIdx.x, lane = t & 63, wv = t >> 6;
  int bh = blockIdx.y, i0 = blockIdx.x * 64;
  for (int r = 0; r < 16; ++r) {
    int i = r * 4 + wv;
    int src = sel[bh * 1024 + i0 + i];
    float kvv = kbuf[((size_t)bh * 2048 + src) * 64 + lane];
    kh[((size_t)bh * 1024 + i0 + i) * 64 + lane] = f2bf(kvv);
    float vv = vbuf[((size_t)bh * 2048 + src) * 64 + lane];
    tile[i][lane] = f2bf(vv);
  }
  __syncthreads();
  for (int r = 0; r < 16; ++r) {
    int d = r * 4 + wv;
    vT[((size_t)bh * 64 + d) * 1024 + i0 + lane] = tile[lane][d];
  }
}

// ---------------- f32 -> bf16 bulk convert -----------------------------------
__global__ void tobf_k(const float* __restrict__ x, unsigned short* __restrict__ y) {
  int i = blockIdx.x * 256 + threadIdx.x;
  float4 v = ((const float4*)x)[i];
  us4 o = {f2bf(v.x), f2bf(v.y), f2bf(v.z), f2bf(v.w)};
  *(us4*)(y + (size_t)i * 4) = o;
}

// ---------------- MFMA flash attention (K/V LDS-staged, barrier-light) -------
__global__ __launch_bounds__(256) void attn_mfma_k(
    const unsigned short* __restrict__ qh, const unsigned short* __restrict__ kh,
    const unsigned short* __restrict__ vT,
    unsigned short* __restrict__ oh, unsigned short* __restrict__ ol) {
  __shared__ __align__(16) unsigned short kvlds[2][2][4096];  // [buf][K/V][64x64]
  __shared__ unsigned short plds[4][16][72];
  int t = threadIdx.x, lane = t & 63, wv = t >> 6;
  int lq = lane & 15, lg = lane >> 4;
  int bh = blockIdx.y;
  int q0 = blockIdx.x * 64 + wv * 16;
  const unsigned short* qbase = qh + ((size_t)bh * 4096 + q0 + lq) * 64;
  bfx8 qf0 = *(const bfx8*)(qbase + lg * 8);
  bfx8 qf1 = *(const bfx8*)(qbase + 32 + lg * 8);
  fx4 acc[4];
  for (int nt = 0; nt < 4; ++nt) acc[nt] = (fx4){0.f, 0.f, 0.f, 0.f};
  float lsum = 0.f;
  const unsigned short* kbase = kh + (size_t)bh * 1024 * 64;
  const unsigned short* vbase = vT + (size_t)bh * 64 * 1024;

  int srow = t >> 2;
  int scolb = (t & 3) * 32;
  const char* gK = (const char*)kbase + (size_t)srow * 128 + scolb;   // + s*8192
  const char* gV = (const char*)vbase + (size_t)srow * 2048 + scolb;  // + s*128
  int sw_w = (srow & 7) << 4;
  int wb0 = srow * 128 + (scolb ^ sw_w);
  int wb1 = srow * 128 + ((scolb + 16) ^ sw_w);

  {
    uint4 k0 = *(const uint4*)(gK);
    uint4 k1 = *(const uint4*)(gK + 16);
    uint4 v0 = *(const uint4*)(gV);
    uint4 v1 = *(const uint4*)(gV + 16);
    *(uint4*)((char*)&kvlds[0][0][0] + wb0) = k0;
    *(uint4*)((char*)&kvlds[0][0][0] + wb1) = k1;
    *(uint4*)((char*)&kvlds[0][1][0] + wb0) = v0;
    *(uint4*)((char*)&kvlds[0][1][0] + wb1) = v1;
  }

  int swr = (lq & 7) << 4;
  int rc0 = (lg * 16) ^ swr;
  int rc1 = (64 + lg * 16) ^ swr;

  for (int s = 0; s < 16; ++s) {
    int cur = s & 1;
    __syncthreads();
    uint4 nk0, nk1, nv0, nv1;
    if (s < 15) {
      const char* gKn = gK + (size_t)(s + 1) * 8192;
      const char* gVn = gV + (size_t)(s + 1) * 128;
      nk0 = *(const uint4*)(gKn);
      nk1 = *(const uint4*)(gKn + 16);
      nv0 = *(const uint4*)(gVn);
      nv1 = *(const uint4*)(gVn + 16);
    }
    __builtin_amdgcn_sched_barrier(0);
    const char* Kb = (const char*)&kvlds[cur][0][0];
    const char* Vb = (const char*)&kvlds[cur][1][0];
    fx4 sS[4];
#pragma unroll
    for (int mt = 0; mt < 4; ++mt) {
      int rowb = (mt * 16 + lq) * 128;
      bfx8 a0 = *(const bfx8*)(Kb + rowb + rc0);
      bfx8 a1 = *(const bfx8*)(Kb + rowb + rc1);
      fx4 c = (fx4){0.f, 0.f, 0.f, 0.f};
      c = __builtin_amdgcn_mfma_f32_16x16x32_bf16(a0, qf0, c, 0, 0, 0);
      c = __builtin_amdgcn_mfma_f32_16x16x32_bf16(a1, qf1, c, 0, 0, 0);
      sS[mt] = c;
    }
#pragma unroll
    for (int mt = 0; mt < 4; ++mt) {
      float p0 = __expf(sS[mt].x), p1 = __expf(sS[mt].y);
      float p2 = __expf(sS[mt].z), p3 = __expf(sS[mt].w);
      lsum += (p0 + p1) + (p2 + p3);
      us4 pk = {f2bf(p0), f2bf(p1), f2bf(p2), f2bf(p3)};
      *(us4*)&plds[wv][lq][mt * 16 + lg * 4] = pk;
    }
    bfx8 pa0 = *(const bfx8*)&plds[wv][lq][lg * 8];
    bfx8 pa1 = *(const bfx8*)&plds[wv][lq][32 + lg * 8];
#pragma unroll
    for (int nt = 0; nt < 4; ++nt) {
      int rowb = (nt * 16 + lq) * 128;
      bfx8 b0 = *(const bfx8*)(Vb + rowb + rc0);
      bfx8 b1 = *(const bfx8*)(Vb + rowb + rc1);
      acc[nt] = __builtin_amdgcn_mfma_f32_16x16x32_bf16(pa0, b0, acc[nt], 0, 0, 0);
      acc[nt] = __builtin_amdgcn_mfma_f32_16x16x32_bf16(pa1, b1, acc[nt], 0, 0, 0);
    }
    __builtin_amdgcn_sched_barrier(0);
    if (s < 15) {
      char* dK = (char*)&kvlds[cur ^ 1][0][0];
      char* dV = (char*)&kvlds[cur ^ 1][1][0];
      *(uint4*)(dK + wb0) = nk0;
      *(uint4*)(dK + wb1) = nk1;
      *(uint4*)(dV + wb0) = nv0;
      *(uint4*)(dV + wb1) = nv1;
    }
  }
  lsum += __shfl_xor(lsum, 16);
  lsum += __shfl_xor(lsum, 32);
  int bi = bh >> 3, hd = bh & 7;
  for (int r = 0; r < 4; ++r) {
    float inv = 1.f / __shfl(lsum, lg * 4 + r);
    size_t rowb = ((size_t)bi * 4096 + q0 + lg * 4 + r) * 512 + hd * 64;
    for (int nt = 0; nt < 4; ++nt) {
      float val = acc[nt][r] * inv;
      unsigned short hb = f2h_bits(val);
      oh[rowb + nt * 16 + lq] = hb;
      ol[rowb + nt * 16 + lq] = f2h_bits((val - h_bits2f(hb)) * 2048.f);
    }
  }
}

// ---------------- final LN + gamma*ln + residual (wave-split channels) -------
__global__ __launch_bounds__(256) void final_k(
    const float* __restrict__ y, const float* __restrict__ g,
    const float* __restrict__ bta, const float* __restrict__ gamma,
    const float* __restrict__ qs, float* __restrict__ out) {
  __shared__ float p1[4][64], p2[4][64];
  __shared__ float mArr[64], invArr[64];
  int t = threadIdx.x, lane = t & 63, wv = t >> 6;
  int n0 = blockIdx.x * 64, bi = blockIdx.y;
  const float* yb = y + (size_t)bi * CDIM * NQ + n0 + lane;
  float s = 0.f, s2 = 0.f;
  for (int cl = 0; cl < 64; ++cl) {
    float v = yb[(size_t)(wv * 64 + cl) * NQ];
    s += v;
    s2 += v * v;
  }
  p1[wv][lane] = s;
  p2[wv][lane] = s2;
  __syncthreads();
  if (t < 64) {
    float ts = p1[0][t] + p1[1][t] + p1[2][t] + p1[3][t];
    float ts2 = p2[0][t] + p2[1][t] + p2[2][t] + p2[3][t];
    float m = ts / CDIM;
    float var = ts2 / CDIM - m * m;
    mArr[t] = m;
    invArr[t] = 1.f / (sqrtf(fmaxf(var, 0.f)) + 1e-6f);
  }
  __syncthreads();
  float gm = gamma[0];
  float m = mArr[lane], inv = invArr[lane];
  const float* qb = qs + (size_t)bi * CDIM * NQ + n0 + lane;
  float* ob = out + (size_t)bi * CDIM * NQ + n0 + lane;
  for (int cl = 0; cl < 64; ++cl) {
    int c = wv * 64 + cl;
    float v = yb[(size_t)c * NQ];
    float ln = g[c] * (v - m) * inv + bta[c];
    ob[(size_t)c * NQ] = gm * ln + qb[(size_t)c * NQ];
  }
}

extern "C" void kernel_launch(void* const* d_in, const int* in_sizes, int n_in,
                              void* d_out, int out_size, void* d_ws, size_t ws_size,
                              hipStream_t stream) {
  const float* qsrc = (const float*)d_in[0];
  const float* ctx = (const float*)d_in[1];
  const float* w_q = (const float*)d_in[2];
  const float* w_kv = (const float*)d_in[3];
  const float* w_out = (const float*)d_in[4];
  const float* cn_g = (const float*)d_in[5];
  const float* cn_b = (const float*)d_in[6];
  const float* qn_g = (const float*)d_in[7];
  const float* qn_b = (const float*)d_in[8];
  const float* on_g = (const float*)d_in[9];
  const float* on_b = (const float*)d_in[10];
  const float* gamma = (const float*)d_in[11];

  // scratch layout (floats); total 22,267,904 floats = 89.1 MB
  if (ws_size < (size_t)22267904 * 4) return;
  float* ws = (float*)d_ws;
  float* r_ctx = ws;                      // 1,048,576 f: ctx split-f16; later kh/vT
  float* r_kv = r_ctx + 1048576;          // 4,194,304 f: kv f32; later kbh/kbl; later attnt split
  float* r_qs = r_kv + 4194304;           // 2,097,152 f: qs split-f16; later cb2h/l, ybuf
  float* r_q3 = r_qs + 2097152;           // 4,194,304 f: q3 f32; later qbh/qbl
  float* qbuf = r_q3 + 4194304;           // 4,194,304 f
  float* kbuf = qbuf + 4194304;           // 2,097,152 f
  float* vbuf = kbuf + 2097152;           // 2,097,152 f
  float* cent = vbuf + 2097152;           // 65,536 f
  float* csq = cent + 65536;              // 1,024 f
  float* sums = csq + 1024;               // 65,536 f
  float* cnt = sums + 65536;              // 1,024 f
  int* asg = (int*)(cnt + 1024);          // 65,536 i
  float* dist = (float*)(asg + 65536);    // 32,768 f
  int* sel = (int*)(dist + 32768);        // 16,384 i
  float* kgreg = (float*)(sel + 16384);   // 2,097,152 f (qh bf16)

  unsigned short* ctxth = (unsigned short*)r_ctx;   // [b][2048][256] f16 hi
  unsigned short* ctxtl = ctxth + (size_t)BB * NK * CDIM;  // lo
  unsigned short* qsth = (unsigned short*)r_qs;     // [b][4096][256] f16 hi
  unsigned short* qstl = qsth + (size_t)BB * NQ * CDIM;    // lo
  float* kvf = r_kv;                      // [b][1024][2048] f32
  float* q3f = r_q3;                      // [b][512][4096] f32
  unsigned short* qh = (unsigned short*)kgreg;      // 4M bf16
  unsigned short* kh = (unsigned short*)r_ctx;      // 1M bf16 (ctx split dead)
  unsigned short* vT = kh + 1048576;                // 1M bf16
  unsigned short* qbh = (unsigned short*)r_q3;      // 4M f16 (q split hi)
  unsigned short* qbl = qbh + (size_t)NPQ * 64;     // 4M f16 (lo)
  unsigned short* kbh = (unsigned short*)r_kv;      // 2M f16 (k split hi)
  unsigned short* kbl = kbh + (size_t)NPK * 64;     // 2M f16 (lo)
  unsigned short* cb2h = (unsigned short*)r_qs;     // 64K f16 (-2c hi)
  unsigned short* cb2l = cb2h + 65536;              // 64K f16 (lo)
  unsigned short* attnth = (unsigned short*)r_kv;   // [b][4096][512] f16 hi (kb split dead)
  unsigned short* attntl = attnth + (size_t)BB * NQ * 512;  // lo
  float* ybuf = r_qs;                     // [b][256][4096] f32 (cb2 dead)

  // 1. channel LayerNorms -> transposed split-f16
  chan_ln_tsplit_k<<<dim3(NK / 64, BB), 256, 0, stream>>>(ctx, cn_g, cn_b, ctxth, ctxtl, CDIM, NK);
  chan_ln_tsplit_k<<<dim3(NQ / 64, BB), 256, 0, stream>>>(qsrc, qn_g, qn_b, qsth, qstl, CDIM, NQ);
  // 2. MFMA projections
  gemm_mfma_k<<<dim3(NK / 64, 1024 / 64, BB), 256, 0, stream>>>(w_kv, ctxth, ctxtl, kvf, 1024, CDIM, NK);
  gemm_mfma_k<<<dim3(NQ / 64, 512 / 64, BB), 256, 0, stream>>>(w_q, qsth, qstl, q3f, 512, CDIM, NQ);
  // 3. fold heads (+L2-normalize q,k)
  fold_k<<<dim3(NQ / 64, 8, BB), 256, 0, stream>>>(q3f, qbuf, 512 * NQ, 0, NQ, 1);
  fold_k<<<dim3(NK / 64, 8, BB), 256, 0, stream>>>(kvf, kbuf, 1024 * NK, 0, NK, 1);
  fold_k<<<dim3(NK / 64, 8, BB), 256, 0, stream>>>(kvf, vbuf, 1024 * NK, 512, NK, 0);
  // 4. split-f16 conversions (q3/kv f32 regions now reusable)
  tof2_k<<<NPQ * 64 / 1024, 256, 0, stream>>>(qbuf, qbh, qbl);
  tof2_k<<<NPK * 64 / 1024, 256, 0, stream>>>(kbuf, kbh, kbl);
  // 5. k-means: initial prep + one memset; centup_prep fuses update/prep/zero
  hipMemcpyAsync(cent, qbuf, 65536 * sizeof(float), hipMemcpyDeviceToDevice, stream);
  centprep_k<<<1024, 64, 0, stream>>>(cent, csq, cb2h, cb2l);
  hipMemsetAsync(sums, 0, (65536 + 1024) * sizeof(float), stream);
  for (int it = 0; it < 4; ++it) {
    assign_mfma_k<1><<<NPQ / 128, 256, 0, stream>>>(qbh, qbl, cb2h, cb2l, csq, asg);
    segsum_k<<<NPQ / 4, 256, 0, stream>>>(qbuf, asg, sums, cnt);
    centup_prep_k<<<65536 / 256, 256, 0, stream>>>(cent, sums, cnt, csq, cb2h, cb2l);
  }
  // 6. score keys: argmin (MFMA) -> exact f32 L1 dist -> per-head top-1024
  assign_mfma_k<0><<<NPK / 64, 256, 0, stream>>>(kbh, kbl, cb2h, cb2l, csq, asg);
  dist_k<<<NPK / 4, 256, 0, stream>>>(kbuf, cent, asg, dist);
  topk_k<<<BH, 1024, 0, stream>>>(dist, sel);
  // 7. bf16 conversions + gather (kh row-major, vT transposed)
  tobf_k<<<NPQ * 64 / 1024, 256, 0, stream>>>(qbuf, qh);
  gatherb_k<<<dim3(TOPK / 64, BH), 256, 0, stream>>>(kbuf, vbuf, sel, kh, vT);
  // 8. MFMA attention -> split-f16 un-folded [b][n][512]
  attn_mfma_k<<<dim3(NQ / 64, BH), 256, 0, stream>>>(qh, kh, vT, attnth, attntl);
  // 9. output projection (MFMA)
  gemm_mfma_k<<<dim3(NQ / 64, 256 / 64, BB), 256, 0, stream>>>(w_out, attnth, attntl, ybuf, 256, 512, NQ);
  // 10. final LN + residual
  final_k<<<dim3(NQ / 64, BB), 256, 0, stream>>>(ybuf, on_g, on_b, gamma, qsrc, (float*)d_out);
}

// Round 12
// 588.449 us; speedup vs baseline: 1.6931x; 1.0481x over previous
//
#include <hip/hip_runtime.h>
#include <math.h>

#define BB 2
#define CDIM 256
#define NQ 4096   // 16*16*16
#define NK 2048   // 8*16*16
#define BH 16
#define TOPK 1024
#define NPQ (BH*NQ)   // 65536
#define NPK (BH*NK)   // 32768

typedef __attribute__((ext_vector_type(8))) short bfx8;
typedef __attribute__((ext_vector_type(8))) _Float16 hfx8;
typedef __attribute__((ext_vector_type(4))) float fx4;
typedef __attribute__((ext_vector_type(4))) unsigned short us4;

__device__ inline unsigned short f2bf(float x) {
  unsigned u = __float_as_uint(x);
  return (unsigned short)((u + 0x7fffu + ((u >> 16) & 1u)) >> 16);
}
__device__ inline unsigned short f2h_bits(float x) {
  _Float16 h = (_Float16)x;
  unsigned short u;
  __builtin_memcpy(&u, &h, 2);
  return u;
}
__device__ inline float h_bits2f(unsigned short u) {
  _Float16 h;
  __builtin_memcpy(&h, &u, 2);
  return (float)h;
}

// ------- channel LayerNorm -> transposed split-f16 [b][n][C] (hi, lo*2048) ---
__global__ __launch_bounds__(256) void chan_ln_tsplit_k(
    const float* __restrict__ x, const float* __restrict__ g,
    const float* __restrict__ bta, unsigned short* __restrict__ yh,
    unsigned short* __restrict__ yl, int C, int N) {
  __shared__ float tile[4][64][65];
  __shared__ float p1[4][64], p2[4][64];
  __shared__ float mArr[64], invArr[64];
  int t = threadIdx.x, lane = t & 63, wv = t >> 6;
  int n0 = blockIdx.x * 64, bi = blockIdx.y;
  const float* xb = x + (size_t)bi * C * N + n0 + lane;
  float s = 0.f, s2 = 0.f;
  for (int cl = 0; cl < 64; ++cl) {
    float v = xb[(size_t)(wv * 64 + cl) * N];
    tile[wv][cl][lane] = v;
    s += v;
    s2 += v * v;
  }
  p1[wv][lane] = s;
  p2[wv][lane] = s2;
  __syncthreads();
  if (t < 64) {
    float ts = p1[0][t] + p1[1][t] + p1[2][t] + p1[3][t];
    float ts2 = p2[0][t] + p2[1][t] + p2[2][t] + p2[3][t];
    float m = ts / C;
    float var = ts2 / C - m * m;
    mArr[t] = m;
    invArr[t] = 1.f / (sqrtf(fmaxf(var, 0.f)) + 1e-6f);
  }
  __syncthreads();
  int c = wv * 64 + lane;  // lane = channel in phase 2
  float gc = g[c], bc = bta[c];
  unsigned short* ohb = yh + ((size_t)bi * N + n0) * C + c;
  unsigned short* olb = yl + ((size_t)bi * N + n0) * C + c;
  for (int pl = 0; pl < 64; ++pl) {
    float v = tile[wv][lane][pl];
    float ln = gc * (v - mArr[pl]) * invArr[pl] + bc;
    unsigned short hb = f2h_bits(ln);
    ohb[(size_t)pl * C] = hb;
    olb[(size_t)pl * C] = f2h_bits((ln - h_bits2f(hb)) * 2048.f);
  }
}

// ------- plain MFMA GEMM (w_out): Y[b][o][n] = sum_c W[o][c]*Xt[b][n][c] -----
__global__ __launch_bounds__(256) void gemm_mfma_k(
    const float* __restrict__ W, const unsigned short* __restrict__ Xh,
    const unsigned short* __restrict__ Xl, float* __restrict__ Y,
    int O, int C, int N) {
  int t = threadIdx.x, lane = t & 63, wv = t >> 6;
  int lq = lane & 15, lg = lane >> 4;
  int n0 = blockIdx.x * 64, o0 = blockIdx.y * 64 + wv * 16;
  int b = blockIdx.z;
  const unsigned short* xbh = Xh + ((size_t)b * N + n0) * C;
  const unsigned short* xbl = Xl + ((size_t)b * N + n0) * C;
  const float* wr = W + (size_t)(o0 + lq) * C;
  fx4 ahi[4], alo[4];
  for (int nt = 0; nt < 4; ++nt) {
    ahi[nt] = (fx4){0.f, 0.f, 0.f, 0.f};
    alo[nt] = (fx4){0.f, 0.f, 0.f, 0.f};
  }
  for (int k0 = 0; k0 < C; k0 += 32) {
    float4 w0 = *(const float4*)(wr + k0 + lg * 8);
    float4 w1 = *(const float4*)(wr + k0 + lg * 8 + 4);
    float wv8[8] = {w0.x, w0.y, w0.z, w0.w, w1.x, w1.y, w1.z, w1.w};
    hfx8 ah, al;
#pragma unroll
    for (int i = 0; i < 8; ++i) {
      _Float16 h = (_Float16)wv8[i];
      ah[i] = h;
      al[i] = (_Float16)((wv8[i] - (float)h) * 2048.f);
    }
#pragma unroll
    for (int nt = 0; nt < 4; ++nt) {
      const unsigned short* bph = xbh + (size_t)(nt * 16 + lq) * C + k0 + lg * 8;
      const unsigned short* bpl = xbl + (size_t)(nt * 16 + lq) * C + k0 + lg * 8;
      hfx8 bh = *(const hfx8*)bph;
      hfx8 bl = *(const hfx8*)bpl;
      ahi[nt] = __builtin_amdgcn_mfma_f32_16x16x32_f16(ah, bh, ahi[nt], 0, 0, 0);
      alo[nt] = __builtin_amdgcn_mfma_f32_16x16x32_f16(al, bh, alo[nt], 0, 0, 0);
      alo[nt] = __builtin_amdgcn_mfma_f32_16x16x32_f16(ah, bl, alo[nt], 0, 0, 0);
    }
  }
  float* yb = Y + ((size_t)b * O + o0) * N + n0;
#pragma unroll
  for (int nt = 0; nt < 4; ++nt)
#pragma unroll
    for (int r = 0; r < 4; ++r)
      yb[(size_t)(lg * 4 + r) * N + nt * 16 + lq] = ahi[nt][r] + alo[nt][r] * (1.f / 2048.f);
}

// ------- fused GEMM + head-fold + L2-norm + multi-format emit ---------------
// PATH 0 (q-proj, O=512): blockIdx.y = head 0..7; norm; emit folded f32 (fq),
//   split-f16 (sh/sl), bf16 (b16).
// PATH 1 (kv-proj, O=1024): blockIdx.y 0..7 = K head (norm; fq,sh,sl);
//   8..15 = V head (no norm; fv only).
template <int PATH>
__global__ __launch_bounds__(256) void gemmfold_k(
    const float* __restrict__ W, const unsigned short* __restrict__ Xh,
    const unsigned short* __restrict__ Xl, float* __restrict__ fq,
    unsigned short* __restrict__ sh, unsigned short* __restrict__ sl,
    unsigned short* __restrict__ b16, float* __restrict__ fv,
    int C, int N) {
  __shared__ float ftile[64][65];
  __shared__ float part[4][64];
  __shared__ float invArr[64];
  int t = threadIdx.x, lane = t & 63, wv = t >> 6;
  int lq = lane & 15, lg = lane >> 4;
  int n0 = blockIdx.x * 64, o0 = blockIdx.y * 64 + wv * 16;
  int b = blockIdx.z;
  bool isV = (PATH == 1) && (blockIdx.y >= 8);
  int h = (PATH == 1) ? (blockIdx.y & 7) : blockIdx.y;
  const unsigned short* xbh = Xh + ((size_t)b * N + n0) * C;
  const unsigned short* xbl = Xl + ((size_t)b * N + n0) * C;
  const float* wr = W + (size_t)(o0 + lq) * C;
  fx4 ahi[4], alo[4];
  for (int nt = 0; nt < 4; ++nt) {
    ahi[nt] = (fx4){0.f, 0.f, 0.f, 0.f};
    alo[nt] = (fx4){0.f, 0.f, 0.f, 0.f};
  }
  for (int k0 = 0; k0 < C; k0 += 32) {
    float4 w0 = *(const float4*)(wr + k0 + lg * 8);
    float4 w1 = *(const float4*)(wr + k0 + lg * 8 + 4);
    float wv8[8] = {w0.x, w0.y, w0.z, w0.w, w1.x, w1.y, w1.z, w1.w};
    hfx8 ah, al;
#pragma unroll
    for (int i = 0; i < 8; ++i) {
      _Float16 hh = (_Float16)wv8[i];
      ah[i] = hh;
      al[i] = (_Float16)((wv8[i] - (float)hh) * 2048.f);
    }
#pragma unroll
    for (int nt = 0; nt < 4; ++nt) {
      const unsigned short* bph = xbh + (size_t)(nt * 16 + lq) * C + k0 + lg * 8;
      const unsigned short* bpl = xbl + (size_t)(nt * 16 + lq) * C + k0 + lg * 8;
      hfx8 bh = *(const hfx8*)bph;
      hfx8 bl = *(const hfx8*)bpl;
      ahi[nt] = __builtin_amdgcn_mfma_f32_16x16x32_f16(ah, bh, ahi[nt], 0, 0, 0);
      alo[nt] = __builtin_amdgcn_mfma_f32_16x16x32_f16(al, bh, alo[nt], 0, 0, 0);
      alo[nt] = __builtin_amdgcn_mfma_f32_16x16x32_f16(ah, bl, alo[nt], 0, 0, 0);
    }
  }
  float val[4][4];
#pragma unroll
  for (int nt = 0; nt < 4; ++nt)
#pragma unroll
    for (int r = 0; r < 4; ++r)
      val[nt][r] = ahi[nt][r] + alo[nt][r] * (1.f / 2048.f);
  if (!isV) {
    // L2 norm over the 64 head channels per position n = nt*16+lq
#pragma unroll
    for (int nt = 0; nt < 4; ++nt) {
      float ss = val[nt][0] * val[nt][0] + val[nt][1] * val[nt][1] +
                 val[nt][2] * val[nt][2] + val[nt][3] * val[nt][3];
      ss += __shfl_xor(ss, 16);
      ss += __shfl_xor(ss, 32);
      if (lg == 0) part[wv][nt * 16 + lq] = ss;
    }
    __syncthreads();
    if (t < 64) {
      float tot = part[0][t] + part[1][t] + part[2][t] + part[3][t];
      invArr[t] = 1.f / fmaxf(sqrtf(tot), 1e-12f);
    }
    __syncthreads();
#pragma unroll
    for (int nt = 0; nt < 4; ++nt) {
      float iv = invArr[nt * 16 + lq];
#pragma unroll
      for (int r = 0; r < 4; ++r) val[nt][r] *= iv;
    }
    __syncthreads();  // invArr reads done before ftile writes reuse LDS flow
  }
  // transpose via LDS: ftile[n][d]
#pragma unroll
  for (int nt = 0; nt < 4; ++nt)
#pragma unroll
    for (int r = 0; r < 4; ++r)
      ftile[nt * 16 + lq][wv * 16 + lg * 4 + r] = val[nt][r];
  __syncthreads();
  size_t rowb = (size_t)(b * 8 + h) * N + n0;
  for (int r2 = 0; r2 < 16; ++r2) {
    int n = r2 * 4 + wv;
    float v = ftile[n][lane];
    size_t idx = (rowb + n) * 64 + lane;
    if (PATH == 1 && isV) {
      fv[idx] = v;
    } else {
      fq[idx] = v;
      unsigned short hb = f2h_bits(v);
      sh[idx] = hb;
      sl[idx] = f2h_bits((v - h_bits2f(hb)) * 2048.f);
      if (PATH == 0) b16[idx] = f2bf(v);
    }
  }
}

// ---------------- centroid prep (initial only): csq, -2c split f16 -----------
__global__ void centprep_k(const float* __restrict__ cent, float* __restrict__ csq,
                           unsigned short* __restrict__ cb2h, unsigned short* __restrict__ cb2l) {
  int j = blockIdx.x, lane = threadIdx.x;  // blockDim = 64
  float c = cent[j * 64 + lane];
  float s = c * c;
  for (int off = 32; off; off >>= 1) s += __shfl_xor(s, off);
  if (lane == 0) csq[j] = s;
  float m2 = -2.f * c;
  unsigned short h = f2h_bits(m2);
  cb2h[j * 64 + lane] = h;
  cb2l[j * 64 + lane] = f2h_bits((m2 - h_bits2f(h)) * 2048.f);
}

// ---------------- MFMA nearest-centroid assign (f16 split, LDS-staged) -------
template <int DUO>
__global__ __launch_bounds__(256) void assign_mfma_k(
    const unsigned short* __restrict__ xh, const unsigned short* __restrict__ xl,
    const unsigned short* __restrict__ cb2h, const unsigned short* __restrict__ cb2l,
    const float* __restrict__ csq, int* __restrict__ aout) {
  __shared__ __align__(16) unsigned short clds[2][2][1024];  // [buf][hi/lo][16x64]
  int t = threadIdx.x, lane = t & 63, wv = t >> 6;
  int lq = lane & 15, lg = lane >> 4;
  int p0 = blockIdx.x * (DUO ? 128 : 64) + wv * (DUO ? 32 : 16);
  const unsigned short* xbA = xh + (size_t)(p0 + lq) * 64;
  const unsigned short* xlA = xl + (size_t)(p0 + lq) * 64;
  hfx8 ba0 = *(const hfx8*)(xbA + lg * 8);
  hfx8 ba1 = *(const hfx8*)(xbA + 32 + lg * 8);
  hfx8 la0 = *(const hfx8*)(xlA + lg * 8);
  hfx8 la1 = *(const hfx8*)(xlA + 32 + lg * 8);
  hfx8 bb0, bb1, lb0, lb1;
  if (DUO) {
    const unsigned short* xbB = xh + (size_t)(p0 + 16 + lq) * 64;
    const unsigned short* xlB = xl + (size_t)(p0 + 16 + lq) * 64;
    bb0 = *(const hfx8*)(xbB + lg * 8);
    bb1 = *(const hfx8*)(xbB + 32 + lg * 8);
    lb0 = *(const hfx8*)(xlB + lg * 8);
    lb1 = *(const hfx8*)(xlB + 32 + lg * 8);
  }

  int part = t >> 7;
  int abyte = (t & 127) * 16;
  int wbyte = abyte ^ (((abyte >> 7) & 7) << 4);
  const unsigned short* gsrc = (part ? cb2l : cb2h) + (abyte >> 1);
  int rowoff = lq * 128;
  int x0 = (lg * 16) ^ ((lq & 7) << 4);
  int x1 = (64 + lg * 16) ^ ((lq & 7) << 4);

  float bestA = 3.4e38f, bestB = 3.4e38f;
  int jA = 0, jB = 0;

  uint4 r0 = *(const uint4*)(gsrc);
  *(uint4*)((char*)&clds[0][part][0] + wbyte) = r0;

  for (int s = 0; s < 64; ++s) {
    int cur = s & 1;
    __syncthreads();
    uint4 rn;
    if (s < 63) rn = *(const uint4*)(gsrc + (size_t)(s + 1) * 1024);
    __builtin_amdgcn_sched_barrier(0);
    const char* ph = (const char*)&clds[cur][0][0];
    const char* pl = (const char*)&clds[cur][1][0];
    hfx8 ah0 = *(const hfx8*)(ph + rowoff + x0);
    hfx8 ah1 = *(const hfx8*)(ph + rowoff + x1);
    hfx8 al0 = *(const hfx8*)(pl + rowoff + x0);
    hfx8 al1 = *(const hfx8*)(pl + rowoff + x1);
    fx4 cq = *(const fx4*)(csq + s * 16 + lg * 4);
    {
      fx4 chi = cq;
      chi = __builtin_amdgcn_mfma_f32_16x16x32_f16(ah0, ba0, chi, 0, 0, 0);
      chi = __builtin_amdgcn_mfma_f32_16x16x32_f16(ah1, ba1, chi, 0, 0, 0);
      fx4 clo = (fx4){0.f, 0.f, 0.f, 0.f};
      clo = __builtin_amdgcn_mfma_f32_16x16x32_f16(ah0, la0, clo, 0, 0, 0);
      clo = __builtin_amdgcn_mfma_f32_16x16x32_f16(ah1, la1, clo, 0, 0, 0);
      clo = __builtin_amdgcn_mfma_f32_16x16x32_f16(al0, ba0, clo, 0, 0, 0);
      clo = __builtin_amdgcn_mfma_f32_16x16x32_f16(al1, ba1, clo, 0, 0, 0);
#pragma unroll
      for (int r_ = 0; r_ < 4; ++r_) {
        int j_ = s * 16 + lg * 4 + r_;
        float d2_ = chi[r_] + clo[r_] * (1.f / 2048.f);
        if (d2_ < bestA) { bestA = d2_; jA = j_; }
      }
    }
    if (DUO) {
      fx4 chi = cq;
      chi = __builtin_amdgcn_mfma_f32_16x16x32_f16(ah0, bb0, chi, 0, 0, 0);
      chi = __builtin_amdgcn_mfma_f32_16x16x32_f16(ah1, bb1, chi, 0, 0, 0);
      fx4 clo = (fx4){0.f, 0.f, 0.f, 0.f};
      clo = __builtin_amdgcn_mfma_f32_16x16x32_f16(ah0, lb0, clo, 0, 0, 0);
      clo = __builtin_amdgcn_mfma_f32_16x16x32_f16(ah1, lb1, clo, 0, 0, 0);
      clo = __builtin_amdgcn_mfma_f32_16x16x32_f16(al0, bb0, clo, 0, 0, 0);
      clo = __builtin_amdgcn_mfma_f32_16x16x32_f16(al1, bb1, clo, 0, 0, 0);
#pragma unroll
      for (int r_ = 0; r_ < 4; ++r_) {
        int j_ = s * 16 + lg * 4 + r_;
        float d2_ = chi[r_] + clo[r_] * (1.f / 2048.f);
        if (d2_ < bestB) { bestB = d2_; jB = j_; }
      }
    }
    __builtin_amdgcn_sched_barrier(0);
    if (s < 63) *(uint4*)((char*)&clds[cur ^ 1][part][0] + wbyte) = rn;
  }

  {
    float o = __shfl_xor(bestA, 16);
    int oj = __shfl_xor(jA, 16);
    if (o < bestA || (o == bestA && oj < jA)) { bestA = o; jA = oj; }
    o = __shfl_xor(bestA, 32);
    oj = __shfl_xor(jA, 32);
    if (o < bestA || (o == bestA && oj < jA)) { bestA = o; jA = oj; }
  }
  if (DUO) {
    float o = __shfl_xor(bestB, 16);
    int oj = __shfl_xor(jB, 16);
    if (o < bestB || (o == bestB && oj < jB)) { bestB = o; jB = oj; }
    o = __shfl_xor(bestB, 32);
    oj = __shfl_xor(jB, 32);
    if (o < bestB || (o == bestB && oj < jB)) { bestB = o; jB = oj; }
  }
  if (lg == 0) {
    aout[p0 + lq] = jA;
    if (DUO) aout[p0 + 16 + lq] = jB;
  }
}

// ---------------- exact f32 L1 distance to assigned centroid -----------------
__global__ void dist_k(const float* __restrict__ x, const float* __restrict__ cent,
                       const int* __restrict__ asg, float* __restrict__ dout) {
  int t = threadIdx.x, lane = t & 63, wv = t >> 6;
  int p = blockIdx.x * 4 + wv;
  int a = asg[p];
  float v = fabsf(cent[(size_t)a * 64 + lane] - x[(size_t)p * 64 + lane]);
  for (int off = 32; off; off >>= 1) v += __shfl_xor(v, off);
  if (lane == 0) dout[p] = v;
}

// ---------------- segment sum via atomics (wave=point: coalesced) ------------
__global__ void segsum_k(const float* __restrict__ x, const int* __restrict__ asg,
                         float* __restrict__ sums, float* __restrict__ cnt) {
  int t = threadIdx.x, lane = t & 63, wv = t >> 6;
  int p = blockIdx.x * 4 + wv;
  int a = asg[p];
  float v = x[(size_t)p * 64 + lane];
  atomicAdd(&sums[a * 64 + lane], v);
  if (lane == 0) atomicAdd(&cnt[a], 1.0f);
}

// ---------------- centroid update + prep + zero (fused) ----------------------
__global__ __launch_bounds__(256) void centup_prep_k(
    float* __restrict__ cent, float* __restrict__ sums, float* __restrict__ cnt,
    float* __restrict__ csq, unsigned short* __restrict__ cb2h,
    unsigned short* __restrict__ cb2l) {
  int i = blockIdx.x * 256 + threadIdx.x;  // 65536 total; rows never span blocks
  int j = i >> 6, lane = threadIdx.x & 63;
  float c = cnt[j];
  float oldc = cent[i];
  float newc = (c > 0.f) ? sums[i] / fmaxf(c, 1.f) : oldc;
  cent[i] = newc;
  float s = newc * newc;
  for (int off = 32; off; off >>= 1) s += __shfl_xor(s, off);
  if (lane == 0) csq[j] = s;
  float m2 = -2.f * newc;
  unsigned short h = f2h_bits(m2);
  cb2h[i] = h;
  cb2l[i] = f2h_bits((m2 - h_bits2f(h)) * 2048.f);
  sums[i] = 0.f;
  if (lane == 0) cnt[j] = 0.f;
}

// ---------------- per-bh top-1024 by descending dist (stable ties) -----------
__global__ __launch_bounds__(1024) void topk_k(const float* __restrict__ dist,
                                               int* __restrict__ sel) {
  __shared__ unsigned long long keys[2048];
  int bh = blockIdx.x, t = threadIdx.x;
  for (int i = t; i < 2048; i += 1024) {
    float d = dist[bh * 2048 + i];
    unsigned int db = __float_as_uint(d);  // d >= 0 -> monotonic
    keys[i] = ((unsigned long long)db << 32) | (unsigned int)(2047 - i);
  }
  __syncthreads();
  for (int k = 2; k <= 2048; k <<= 1) {
    for (int j = k >> 1; j > 0; j >>= 1) {
      for (int i = t; i < 2048; i += 1024) {
        int ixj = i ^ j;
        if (ixj > i) {
          unsigned long long a = keys[i], b = keys[ixj];
          bool up = ((i & k) == 0);
          bool sw = up ? (a < b) : (a > b);  // descending overall
          if (sw) { keys[i] = b; keys[ixj] = a; }
        }
      }
      __syncthreads();
    }
  }
  if (t < 1024) sel[bh * 1024 + t] = 2047 - (int)(keys[t] & 0xffffffffu);
}

// ---------------- gather selected rows -> kh (bf16 row-major), vT (bf16 d-major)
__global__ void gatherb_k(const float* __restrict__ kbuf, const float* __restrict__ vbuf,
                          const int* __restrict__ sel, unsigned short* __restrict__ kh,
                          unsigned short* __restrict__ vT) {
  __shared__ unsigned short tile[64][66];
  int t = threadIdx.x, lane = t & 63, wv = t >> 6;
  int bh = blockIdx.y, i0 = blockIdx.x * 64;
  for (int r = 0; r < 16; ++r) {
    int i = r * 4 + wv;
    int src = sel[bh * 1024 + i0 + i];
    float kvv = kbuf[((size_t)bh * 2048 + src) * 64 + lane];
    kh[((size_t)bh * 1024 + i0 + i) * 64 + lane] = f2bf(kvv);
    float vv = vbuf[((size_t)bh * 2048 + src) * 64 + lane];
    tile[i][lane] = f2bf(vv);
  }
  __syncthreads();
  for (int r = 0; r < 16; ++r) {
    int d = r * 4 + wv;
    vT[((size_t)bh * 64 + d) * 1024 + i0 + lane] = tile[lane][d];
  }
}

// ---------------- MFMA flash attention (K/V LDS-staged, barrier-light) -------
__global__ __launch_bounds__(256) void attn_mfma_k(
    const unsigned short* __restrict__ qh, const unsigned short* __restrict__ kh,
    const unsigned short* __restrict__ vT,
    unsigned short* __restrict__ oh, unsigned short* __restrict__ ol) {
  __shared__ __align__(16) unsigned short kvlds[2][2][4096];  // [buf][K/V][64x64]
  __shared__ unsigned short plds[4][16][72];
  int t = threadIdx.x, lane = t & 63, wv = t >> 6;
  int lq = lane & 15, lg = lane >> 4;
  int bh = blockIdx.y;
  int q0 = blockIdx.x * 64 + wv * 16;
  const unsigned short* qbase = qh + ((size_t)bh * 4096 + q0 + lq) * 64;
  bfx8 qf0 = *(const bfx8*)(qbase + lg * 8);
  bfx8 qf1 = *(const bfx8*)(qbase + 32 + lg * 8);
  fx4 acc[4];
  for (int nt = 0; nt < 4; ++nt) acc[nt] = (fx4){0.f, 0.f, 0.f, 0.f};
  float lsum = 0.f;
  const unsigned short* kbase = kh + (size_t)bh * 1024 * 64;
  const unsigned short* vbase = vT + (size_t)bh * 64 * 1024;

  int srow = t >> 2;
  int scolb = (t & 3) * 32;
  const char* gK = (const char*)kbase + (size_t)srow * 128 + scolb;   // + s*8192
  const char* gV = (const char*)vbase + (size_t)srow * 2048 + scolb;  // + s*128
  int sw_w = (srow & 7) << 4;
  int wb0 = srow * 128 + (scolb ^ sw_w);
  int wb1 = srow * 128 + ((scolb + 16) ^ sw_w);

  {
    uint4 k0 = *(const uint4*)(gK);
    uint4 k1 = *(const uint4*)(gK + 16);
    uint4 v0 = *(const uint4*)(gV);
    uint4 v1 = *(const uint4*)(gV + 16);
    *(uint4*)((char*)&kvlds[0][0][0] + wb0) = k0;
    *(uint4*)((char*)&kvlds[0][0][0] + wb1) = k1;
    *(uint4*)((char*)&kvlds[0][1][0] + wb0) = v0;
    *(uint4*)((char*)&kvlds[0][1][0] + wb1) = v1;
  }

  int swr = (lq & 7) << 4;
  int rc0 = (lg * 16) ^ swr;
  int rc1 = (64 + lg * 16) ^ swr;

  for (int s = 0; s < 16; ++s) {
    int cur = s & 1;
    __syncthreads();
    uint4 nk0, nk1, nv0, nv1;
    if (s < 15) {
      const char* gKn = gK + (size_t)(s + 1) * 8192;
      const char* gVn = gV + (size_t)(s + 1) * 128;
      nk0 = *(const uint4*)(gKn);
      nk1 = *(const uint4*)(gKn + 16);
      nv0 = *(const uint4*)(gVn);
      nv1 = *(const uint4*)(gVn + 16);
    }
    __builtin_amdgcn_sched_barrier(0);
    const char* Kb = (const char*)&kvlds[cur][0][0];
    const char* Vb = (const char*)&kvlds[cur][1][0];
    fx4 sS[4];
#pragma unroll
    for (int mt = 0; mt < 4; ++mt) {
      int rowb = (mt * 16 + lq) * 128;
      bfx8 a0 = *(const bfx8*)(Kb + rowb + rc0);
      bfx8 a1 = *(const bfx8*)(Kb + rowb + rc1);
      fx4 c = (fx4){0.f, 0.f, 0.f, 0.f};
      c = __builtin_amdgcn_mfma_f32_16x16x32_bf16(a0, qf0, c, 0, 0, 0);
      c = __builtin_amdgcn_mfma_f32_16x16x32_bf16(a1, qf1, c, 0, 0, 0);
      sS[mt] = c;
    }
#pragma unroll
    for (int mt = 0; mt < 4; ++mt) {
      float p0 = __expf(sS[mt].x), p1 = __expf(sS[mt].y);
      float p2 = __expf(sS[mt].z), p3 = __expf(sS[mt].w);
      lsum += (p0 + p1) + (p2 + p3);
      us4 pk = {f2bf(p0), f2bf(p1), f2bf(p2), f2bf(p3)};
      *(us4*)&plds[wv][lq][mt * 16 + lg * 4] = pk;
    }
    bfx8 pa0 = *(const bfx8*)&plds[wv][lq][lg * 8];
    bfx8 pa1 = *(const bfx8*)&plds[wv][lq][32 + lg * 8];
#pragma unroll
    for (int nt = 0; nt < 4; ++nt) {
      int rowb = (nt * 16 + lq) * 128;
      bfx8 b0 = *(const bfx8*)(Vb + rowb + rc0);
      bfx8 b1 = *(const bfx8*)(Vb + rowb + rc1);
      acc[nt] = __builtin_amdgcn_mfma_f32_16x16x32_bf16(pa0, b0, acc[nt], 0, 0, 0);
      acc[nt] = __builtin_amdgcn_mfma_f32_16x16x32_bf16(pa1, b1, acc[nt], 0, 0, 0);
    }
    __builtin_amdgcn_sched_barrier(0);
    if (s < 15) {
      char* dK = (char*)&kvlds[cur ^ 1][0][0];
      char* dV = (char*)&kvlds[cur ^ 1][1][0];
      *(uint4*)(dK + wb0) = nk0;
      *(uint4*)(dK + wb1) = nk1;
      *(uint4*)(dV + wb0) = nv0;
      *(uint4*)(dV + wb1) = nv1;
    }
  }
  lsum += __shfl_xor(lsum, 16);
  lsum += __shfl_xor(lsum, 32);
  int bi = bh >> 3, hd = bh & 7;
  for (int r = 0; r < 4; ++r) {
    float inv = 1.f / __shfl(lsum, lg * 4 + r);
    size_t rowb = ((size_t)bi * 4096 + q0 + lg * 4 + r) * 512 + hd * 64;
    for (int nt = 0; nt < 4; ++nt) {
      float val = acc[nt][r] * inv;
      unsigned short hb = f2h_bits(val);
      oh[rowb + nt * 16 + lq] = hb;
      ol[rowb + nt * 16 + lq] = f2h_bits((val - h_bits2f(hb)) * 2048.f);
    }
  }
}

// ---------------- final LN + gamma*ln + residual (wave-split channels) -------
__global__ __launch_bounds__(256) void final_k(
    const float* __restrict__ y, const float* __restrict__ g,
    const float* __restrict__ bta, const float* __restrict__ gamma,
    const float* __restrict__ qs, float* __restrict__ out) {
  __shared__ float p1[4][64], p2[4][64];
  __shared__ float mArr[64], invArr[64];
  int t = threadIdx.x, lane = t & 63, wv = t >> 6;
  int n0 = blockIdx.x * 64, bi = blockIdx.y;
  const float* yb = y + (size_t)bi * CDIM * NQ + n0 + lane;
  float s = 0.f, s2 = 0.f;
  for (int cl = 0; cl < 64; ++cl) {
    float v = yb[(size_t)(wv * 64 + cl) * NQ];
    s += v;
    s2 += v * v;
  }
  p1[wv][lane] = s;
  p2[wv][lane] = s2;
  __syncthreads();
  if (t < 64) {
    float ts = p1[0][t] + p1[1][t] + p1[2][t] + p1[3][t];
    float ts2 = p2[0][t] + p2[1][t] + p2[2][t] + p2[3][t];
    float m = ts / CDIM;
    float var = ts2 / CDIM - m * m;
    mArr[t] = m;
    invArr[t] = 1.f / (sqrtf(fmaxf(var, 0.f)) + 1e-6f);
  }
  __syncthreads();
  float gm = gamma[0];
  float m = mArr[lane], inv = invArr[lane];
  const float* qb = qs + (size_t)bi * CDIM * NQ + n0 + lane;
  float* ob = out + (size_t)bi * CDIM * NQ + n0 + lane;
  for (int cl = 0; cl < 64; ++cl) {
    int c = wv * 64 + cl;
    float v = yb[(size_t)c * NQ];
    float ln = g[c] * (v - m) * inv + bta[c];
    ob[(size_t)c * NQ] = gm * ln + qb[(size_t)c * NQ];
  }
}

extern "C" void kernel_launch(void* const* d_in, const int* in_sizes, int n_in,
                              void* d_out, int out_size, void* d_ws, size_t ws_size,
                              hipStream_t stream) {
  const float* qsrc = (const float*)d_in[0];
  const float* ctx = (const float*)d_in[1];
  const float* w_q = (const float*)d_in[2];
  const float* w_kv = (const float*)d_in[3];
  const float* w_out = (const float*)d_in[4];
  const float* cn_g = (const float*)d_in[5];
  const float* cn_b = (const float*)d_in[6];
  const float* qn_g = (const float*)d_in[7];
  const float* qn_b = (const float*)d_in[8];
  const float* on_g = (const float*)d_in[9];
  const float* on_b = (const float*)d_in[10];
  const float* gamma = (const float*)d_in[11];

  // scratch layout (floats); total 22,267,904 floats = 89.1 MB
  if (ws_size < (size_t)22267904 * 4) return;
  float* ws = (float*)d_ws;
  float* r_ctx = ws;                      // 1,048,576 f: ctx split-f16; later kh/vT
  float* r_kv = r_ctx + 1048576;          // 4,194,304 f: kbh/kbl f16; later attnt split
  float* r_qs = r_kv + 4194304;           // 2,097,152 f: qs split-f16; later cb2h/l, ybuf
  float* r_q3 = r_qs + 2097152;           // 4,194,304 f: qbh/qbl f16
  float* qbuf = r_q3 + 4194304;           // 4,194,304 f
  float* kbuf = qbuf + 4194304;           // 2,097,152 f
  float* vbuf = kbuf + 2097152;           // 2,097,152 f
  float* cent = vbuf + 2097152;           // 65,536 f
  float* csq = cent + 65536;              // 1,024 f
  float* sums = csq + 1024;               // 65,536 f
  float* cnt = sums + 65536;              // 1,024 f
  int* asg = (int*)(cnt + 1024);          // 65,536 i
  float* dist = (float*)(asg + 65536);    // 32,768 f
  int* sel = (int*)(dist + 32768);        // 16,384 i
  float* kgreg = (float*)(sel + 16384);   // 2,097,152 f (qh bf16)

  unsigned short* ctxth = (unsigned short*)r_ctx;   // [b][2048][256] f16 hi
  unsigned short* ctxtl = ctxth + (size_t)BB * NK * CDIM;  // lo
  unsigned short* qsth = (unsigned short*)r_qs;     // [b][4096][256] f16 hi
  unsigned short* qstl = qsth + (size_t)BB * NQ * CDIM;    // lo
  unsigned short* qh = (unsigned short*)kgreg;      // 4M bf16
  unsigned short* kh = (unsigned short*)r_ctx;      // 1M bf16 (ctx split dead)
  unsigned short* vT = kh + 1048576;                // 1M bf16
  unsigned short* qbh = (unsigned short*)r_q3;      // 4M f16 (q split hi)
  unsigned short* qbl = qbh + (size_t)NPQ * 64;     // 4M f16 (lo)
  unsigned short* kbh = (unsigned short*)r_kv;      // 2M f16 (k split hi)
  unsigned short* kbl = kbh + (size_t)NPK * 64;     // 2M f16 (lo)
  unsigned short* cb2h = (unsigned short*)r_qs;     // 64K f16 (-2c hi)
  unsigned short* cb2l = cb2h + 65536;              // 64K f16 (lo)
  unsigned short* attnth = (unsigned short*)r_kv;   // [b][4096][512] f16 hi (kb split dead)
  unsigned short* attntl = attnth + (size_t)BB * NQ * 512;  // lo
  float* ybuf = r_qs;                     // [b][256][4096] f32 (cb2 dead)

  // 1. channel LayerNorms -> transposed split-f16
  chan_ln_tsplit_k<<<dim3(NK / 64, BB), 256, 0, stream>>>(ctx, cn_g, cn_b, ctxth, ctxtl, CDIM, NK);
  chan_ln_tsplit_k<<<dim3(NQ / 64, BB), 256, 0, stream>>>(qsrc, qn_g, qn_b, qsth, qstl, CDIM, NQ);
  // 2. fused MFMA projections + fold + L2-norm + format emit
  gemmfold_k<1><<<dim3(NK / 64, 16, BB), 256, 0, stream>>>(
      w_kv, ctxth, ctxtl, kbuf, kbh, kbl, nullptr, vbuf, CDIM, NK);
  gemmfold_k<0><<<dim3(NQ / 64, 8, BB), 256, 0, stream>>>(
      w_q, qsth, qstl, qbuf, qbh, qbl, qh, nullptr, CDIM, NQ);
  // 3. k-means: initial prep + one memset; centup_prep fuses update/prep/zero
  hipMemcpyAsync(cent, qbuf, 65536 * sizeof(float), hipMemcpyDeviceToDevice, stream);
  centprep_k<<<1024, 64, 0, stream>>>(cent, csq, cb2h, cb2l);
  hipMemsetAsync(sums, 0, (65536 + 1024) * sizeof(float), stream);
  for (int it = 0; it < 4; ++it) {
    assign_mfma_k<1><<<NPQ / 128, 256, 0, stream>>>(qbh, qbl, cb2h, cb2l, csq, asg);
    segsum_k<<<NPQ / 4, 256, 0, stream>>>(qbuf, asg, sums, cnt);
    centup_prep_k<<<65536 / 256, 256, 0, stream>>>(cent, sums, cnt, csq, cb2h, cb2l);
  }
  // 4. score keys: argmin (MFMA) -> exact f32 L1 dist -> per-head top-1024
  assign_mfma_k<0><<<NPK / 64, 256, 0, stream>>>(kbh, kbl, cb2h, cb2l, csq, asg);
  dist_k<<<NPK / 4, 256, 0, stream>>>(kbuf, cent, asg, dist);
  topk_k<<<BH, 1024, 0, stream>>>(dist, sel);
  // 5. gather (kh row-major bf16, vT transposed bf16)
  gatherb_k<<<dim3(TOPK / 64, BH), 256, 0, stream>>>(kbuf, vbuf, sel, kh, vT);
  // 6. MFMA attention -> split-f16 un-folded [b][n][512]
  attn_mfma_k<<<dim3(NQ / 64, BH), 256, 0, stream>>>(qh, kh, vT, attnth, attntl);
  // 7. output projection (MFMA)
  gemm_mfma_k<<<dim3(NQ / 64, 256 / 64, BB), 256, 0, stream>>>(w_out, attnth, attntl, ybuf, 256, 512, NQ);
  // 8. final LN + residual
  final_k<<<dim3(NQ / 64, BB), 256, 0, stream>>>(ybuf, on_g, on_b, gamma, qsrc, (float*)d_out);
}

// Round 13
// 537.067 us; speedup vs baseline: 1.8550x; 1.0957x over previous
//
#include <hip/hip_runtime.h>
#include <math.h>

#define BB 2
#define CDIM 256
#define NQ 4096   // 16*16*16
#define NK 2048   // 8*16*16
#define BH 16
#define TOPK 1024
#define NPQ (BH*NQ)   // 65536
#define NPK (BH*NK)   // 32768

typedef __attribute__((ext_vector_type(8))) short bfx8;
typedef __attribute__((ext_vector_type(8))) _Float16 hfx8;
typedef __attribute__((ext_vector_type(4))) float fx4;
typedef __attribute__((ext_vector_type(4))) unsigned short us4;

__device__ inline unsigned short f2bf(float x) {
  unsigned u = __float_as_uint(x);
  return (unsigned short)((u + 0x7fffu + ((u >> 16) & 1u)) >> 16);
}
__device__ inline unsigned short f2h_bits(float x) {
  _Float16 h = (_Float16)x;
  unsigned short u;
  __builtin_memcpy(&u, &h, 2);
  return u;
}
__device__ inline float h_bits2f(unsigned short u) {
  _Float16 h;
  __builtin_memcpy(&h, &u, 2);
  return (float)h;
}

// ------- channel LayerNorm -> transposed split-f16 [b][n][C] (hi, lo*2048) ---
__global__ __launch_bounds__(256) void chan_ln_tsplit_k(
    const float* __restrict__ x, const float* __restrict__ g,
    const float* __restrict__ bta, unsigned short* __restrict__ yh,
    unsigned short* __restrict__ yl, int C, int N) {
  __shared__ float tile[4][64][65];
  __shared__ float p1[4][64], p2[4][64];
  __shared__ float mArr[64], invArr[64];
  int t = threadIdx.x, lane = t & 63, wv = t >> 6;
  int n0 = blockIdx.x * 64, bi = blockIdx.y;
  const float* xb = x + (size_t)bi * C * N + n0 + lane;
  float s = 0.f, s2 = 0.f;
  for (int cl = 0; cl < 64; ++cl) {
    float v = xb[(size_t)(wv * 64 + cl) * N];
    tile[wv][cl][lane] = v;
    s += v;
    s2 += v * v;
  }
  p1[wv][lane] = s;
  p2[wv][lane] = s2;
  __syncthreads();
  if (t < 64) {
    float ts = p1[0][t] + p1[1][t] + p1[2][t] + p1[3][t];
    float ts2 = p2[0][t] + p2[1][t] + p2[2][t] + p2[3][t];
    float m = ts / C;
    float var = ts2 / C - m * m;
    mArr[t] = m;
    invArr[t] = 1.f / (sqrtf(fmaxf(var, 0.f)) + 1e-6f);
  }
  __syncthreads();
  int c = wv * 64 + lane;  // lane = channel in phase 2
  float gc = g[c], bc = bta[c];
  unsigned short* ohb = yh + ((size_t)bi * N + n0) * C + c;
  unsigned short* olb = yl + ((size_t)bi * N + n0) * C + c;
  for (int pl = 0; pl < 64; ++pl) {
    float v = tile[wv][lane][pl];
    float ln = gc * (v - mArr[pl]) * invArr[pl] + bc;
    unsigned short hb = f2h_bits(ln);
    ohb[(size_t)pl * C] = hb;
    olb[(size_t)pl * C] = f2h_bits((ln - h_bits2f(hb)) * 2048.f);
  }
}

// ------- plain MFMA GEMM (w_out): Y[b][o][n] = sum_c W[o][c]*Xt[b][n][c] -----
__global__ __launch_bounds__(256) void gemm_mfma_k(
    const float* __restrict__ W, const unsigned short* __restrict__ Xh,
    const unsigned short* __restrict__ Xl, float* __restrict__ Y,
    int O, int C, int N) {
  int t = threadIdx.x, lane = t & 63, wv = t >> 6;
  int lq = lane & 15, lg = lane >> 4;
  int n0 = blockIdx.x * 64, o0 = blockIdx.y * 64 + wv * 16;
  int b = blockIdx.z;
  const unsigned short* xbh = Xh + ((size_t)b * N + n0) * C;
  const unsigned short* xbl = Xl + ((size_t)b * N + n0) * C;
  const float* wr = W + (size_t)(o0 + lq) * C;
  fx4 ahi[4], alo[4];
  for (int nt = 0; nt < 4; ++nt) {
    ahi[nt] = (fx4){0.f, 0.f, 0.f, 0.f};
    alo[nt] = (fx4){0.f, 0.f, 0.f, 0.f};
  }
  for (int k0 = 0; k0 < C; k0 += 32) {
    float4 w0 = *(const float4*)(wr + k0 + lg * 8);
    float4 w1 = *(const float4*)(wr + k0 + lg * 8 + 4);
    float wv8[8] = {w0.x, w0.y, w0.z, w0.w, w1.x, w1.y, w1.z, w1.w};
    hfx8 ah, al;
#pragma unroll
    for (int i = 0; i < 8; ++i) {
      _Float16 h = (_Float16)wv8[i];
      ah[i] = h;
      al[i] = (_Float16)((wv8[i] - (float)h) * 2048.f);
    }
#pragma unroll
    for (int nt = 0; nt < 4; ++nt) {
      const unsigned short* bph = xbh + (size_t)(nt * 16 + lq) * C + k0 + lg * 8;
      const unsigned short* bpl = xbl + (size_t)(nt * 16 + lq) * C + k0 + lg * 8;
      hfx8 bh = *(const hfx8*)bph;
      hfx8 bl = *(const hfx8*)bpl;
      ahi[nt] = __builtin_amdgcn_mfma_f32_16x16x32_f16(ah, bh, ahi[nt], 0, 0, 0);
      alo[nt] = __builtin_amdgcn_mfma_f32_16x16x32_f16(al, bh, alo[nt], 0, 0, 0);
      alo[nt] = __builtin_amdgcn_mfma_f32_16x16x32_f16(ah, bl, alo[nt], 0, 0, 0);
    }
  }
  float* yb = Y + ((size_t)b * O + o0) * N + n0;
#pragma unroll
  for (int nt = 0; nt < 4; ++nt)
#pragma unroll
    for (int r = 0; r < 4; ++r)
      yb[(size_t)(lg * 4 + r) * N + nt * 16 + lq] = ahi[nt][r] + alo[nt][r] * (1.f / 2048.f);
}

// ------- fused GEMM + head-fold + L2-norm + multi-format emit ---------------
// LDS-staged X (hi+lo interleaved per 128B row, XOR-swizzled, double-buffered);
// W + X prefetched one k-step ahead. MFMA sequence identical to R12 (bit-exact).
// PATH 0 (q-proj): blockIdx.y = head 0..7; norm; emit fq, sh/sl, b16.
// PATH 1 (kv-proj): blockIdx.y 0..7 = K head (norm; fq,sh,sl); 8..15 = V (fv).
template <int PATH>
__global__ __launch_bounds__(256) void gemmfold_k(
    const float* __restrict__ W, const unsigned short* __restrict__ Xh,
    const unsigned short* __restrict__ Xl, float* __restrict__ fq,
    unsigned short* __restrict__ sh, unsigned short* __restrict__ sl,
    unsigned short* __restrict__ b16, float* __restrict__ fv,
    int C, int N) {
  __shared__ __align__(16) unsigned short xlds[2][64][64];  // [buf][row][hi32|lo32]
  __shared__ float ftile[64][65];
  __shared__ float part[4][64];
  __shared__ float invArr[64];
  int t = threadIdx.x, lane = t & 63, wv = t >> 6;
  int lq = lane & 15, lg = lane >> 4;
  int n0 = blockIdx.x * 64, o0 = blockIdx.y * 64 + wv * 16;
  int b = blockIdx.z;
  bool isV = (PATH == 1) && (blockIdx.y >= 8);
  int h = (PATH == 1) ? (blockIdx.y & 7) : blockIdx.y;
  const unsigned short* xbh = Xh + ((size_t)b * N + n0) * C;
  const unsigned short* xbl = Xl + ((size_t)b * N + n0) * C;
  const float* wr = W + (size_t)(o0 + lq) * C;

  // staging role: thread t stages 16B hi + 16B lo of the 64x32 subtile
  int a = t * 16;                 // byte within 4KB hi half
  int srow = a >> 6;              // 0..63
  int schunk = (a >> 4) & 3;      // 0..3 (8-ch chunk within 32)
  const unsigned short* gsh = xbh + (size_t)srow * C + schunk * 8;
  const unsigned short* gsl = xbl + (size_t)srow * C + schunk * 8;
  int swz = (srow & 7) << 4;
  int wbh = srow * 128 + ((schunk * 16) ^ swz);
  int wbl = srow * 128 + ((64 + schunk * 16) ^ swz);
  // read-side offsets (row & 7 == lq & 7)
  int rswz = (lq & 7) << 4;
  int xh0 = (lg * 16) ^ rswz;
  int xl0 = (64 + lg * 16) ^ rswz;

  fx4 ahi[4], alo[4];
  for (int nt = 0; nt < 4; ++nt) {
    ahi[nt] = (fx4){0.f, 0.f, 0.f, 0.f};
    alo[nt] = (fx4){0.f, 0.f, 0.f, 0.f};
  }

  // prologue: stage subtile 0, load W pair 0
  {
    uint4 h0 = *(const uint4*)(gsh);
    uint4 l0 = *(const uint4*)(gsl);
    *(uint4*)((char*)&xlds[0][0][0] + wbh) = h0;
    *(uint4*)((char*)&xlds[0][0][0] + wbl) = l0;
  }
  float4 w0c = *(const float4*)(wr + lg * 8);
  float4 w1c = *(const float4*)(wr + lg * 8 + 4);

  for (int s = 0; s < 8; ++s) {
    int cur = s & 1;
    __syncthreads();
    uint4 nh, nl;
    float4 nw0, nw1;
    if (s < 7) {
      nh = *(const uint4*)(gsh + (s + 1) * 32);
      nl = *(const uint4*)(gsl + (s + 1) * 32);
      nw0 = *(const float4*)(wr + (s + 1) * 32 + lg * 8);
      nw1 = *(const float4*)(wr + (s + 1) * 32 + lg * 8 + 4);
    }
    __builtin_amdgcn_sched_barrier(0);
    float wv8[8] = {w0c.x, w0c.y, w0c.z, w0c.w, w1c.x, w1c.y, w1c.z, w1c.w};
    hfx8 ah, al;
#pragma unroll
    for (int i = 0; i < 8; ++i) {
      _Float16 hh = (_Float16)wv8[i];
      ah[i] = hh;
      al[i] = (_Float16)((wv8[i] - (float)hh) * 2048.f);
    }
    const char* Xb = (const char*)&xlds[cur][0][0];
#pragma unroll
    for (int nt = 0; nt < 4; ++nt) {
      int rb = (nt * 16 + lq) * 128;
      hfx8 bh = *(const hfx8*)(Xb + rb + xh0);
      hfx8 bl = *(const hfx8*)(Xb + rb + xl0);
      ahi[nt] = __builtin_amdgcn_mfma_f32_16x16x32_f16(ah, bh, ahi[nt], 0, 0, 0);
      alo[nt] = __builtin_amdgcn_mfma_f32_16x16x32_f16(al, bh, alo[nt], 0, 0, 0);
      alo[nt] = __builtin_amdgcn_mfma_f32_16x16x32_f16(ah, bl, alo[nt], 0, 0, 0);
    }
    __builtin_amdgcn_sched_barrier(0);
    if (s < 7) {
      *(uint4*)((char*)&xlds[cur ^ 1][0][0] + wbh) = nh;
      *(uint4*)((char*)&xlds[cur ^ 1][0][0] + wbl) = nl;
      w0c = nw0;
      w1c = nw1;
    }
  }

  float val[4][4];
#pragma unroll
  for (int nt = 0; nt < 4; ++nt)
#pragma unroll
    for (int r = 0; r < 4; ++r)
      val[nt][r] = ahi[nt][r] + alo[nt][r] * (1.f / 2048.f);
  __syncthreads();  // xlds reads done; LDS phase transition
  if (!isV) {
#pragma unroll
    for (int nt = 0; nt < 4; ++nt) {
      float ss = val[nt][0] * val[nt][0] + val[nt][1] * val[nt][1] +
                 val[nt][2] * val[nt][2] + val[nt][3] * val[nt][3];
      ss += __shfl_xor(ss, 16);
      ss += __shfl_xor(ss, 32);
      if (lg == 0) part[wv][nt * 16 + lq] = ss;
    }
    __syncthreads();
    if (t < 64) {
      float tot = part[0][t] + part[1][t] + part[2][t] + part[3][t];
      invArr[t] = 1.f / fmaxf(sqrtf(tot), 1e-12f);
    }
    __syncthreads();
#pragma unroll
    for (int nt = 0; nt < 4; ++nt) {
      float iv = invArr[nt * 16 + lq];
#pragma unroll
      for (int r = 0; r < 4; ++r) val[nt][r] *= iv;
    }
    __syncthreads();
  }
  // transpose via LDS: ftile[n][d]
#pragma unroll
  for (int nt = 0; nt < 4; ++nt)
#pragma unroll
    for (int r = 0; r < 4; ++r)
      ftile[nt * 16 + lq][wv * 16 + lg * 4 + r] = val[nt][r];
  __syncthreads();
  size_t rowb = (size_t)(b * 8 + h) * N + n0;
  for (int r2 = 0; r2 < 16; ++r2) {
    int n = r2 * 4 + wv;
    float v = ftile[n][lane];
    size_t idx = (rowb + n) * 64 + lane;
    if (PATH == 1 && isV) {
      fv[idx] = v;
    } else {
      fq[idx] = v;
      unsigned short hb = f2h_bits(v);
      sh[idx] = hb;
      sl[idx] = f2h_bits((v - h_bits2f(hb)) * 2048.f);
      if (PATH == 0) b16[idx] = f2bf(v);
    }
  }
}

// ---------------- centroid prep (initial only): csq, -2c split f16 -----------
__global__ void centprep_k(const float* __restrict__ cent, float* __restrict__ csq,
                           unsigned short* __restrict__ cb2h, unsigned short* __restrict__ cb2l) {
  int j = blockIdx.x, lane = threadIdx.x;  // blockDim = 64
  float c = cent[j * 64 + lane];
  float s = c * c;
  for (int off = 32; off; off >>= 1) s += __shfl_xor(s, off);
  if (lane == 0) csq[j] = s;
  float m2 = -2.f * c;
  unsigned short h = f2h_bits(m2);
  cb2h[j * 64 + lane] = h;
  cb2l[j * 64 + lane] = f2h_bits((m2 - h_bits2f(h)) * 2048.f);
}

// ---------------- MFMA nearest-centroid assign (f16 split, LDS-staged) -------
template <int DUO>
__global__ __launch_bounds__(256) void assign_mfma_k(
    const unsigned short* __restrict__ xh, const unsigned short* __restrict__ xl,
    const unsigned short* __restrict__ cb2h, const unsigned short* __restrict__ cb2l,
    const float* __restrict__ csq, int* __restrict__ aout) {
  __shared__ __align__(16) unsigned short clds[2][2][1024];  // [buf][hi/lo][16x64]
  int t = threadIdx.x, lane = t & 63, wv = t >> 6;
  int lq = lane & 15, lg = lane >> 4;
  int p0 = blockIdx.x * (DUO ? 128 : 64) + wv * (DUO ? 32 : 16);
  const unsigned short* xbA = xh + (size_t)(p0 + lq) * 64;
  const unsigned short* xlA = xl + (size_t)(p0 + lq) * 64;
  hfx8 ba0 = *(const hfx8*)(xbA + lg * 8);
  hfx8 ba1 = *(const hfx8*)(xbA + 32 + lg * 8);
  hfx8 la0 = *(const hfx8*)(xlA + lg * 8);
  hfx8 la1 = *(const hfx8*)(xlA + 32 + lg * 8);
  hfx8 bb0, bb1, lb0, lb1;
  if (DUO) {
    const unsigned short* xbB = xh + (size_t)(p0 + 16 + lq) * 64;
    const unsigned short* xlB = xl + (size_t)(p0 + 16 + lq) * 64;
    bb0 = *(const hfx8*)(xbB + lg * 8);
    bb1 = *(const hfx8*)(xbB + 32 + lg * 8);
    lb0 = *(const hfx8*)(xlB + lg * 8);
    lb1 = *(const hfx8*)(xlB + 32 + lg * 8);
  }

  int part = t >> 7;
  int abyte = (t & 127) * 16;
  int wbyte = abyte ^ (((abyte >> 7) & 7) << 4);
  const unsigned short* gsrc = (part ? cb2l : cb2h) + (abyte >> 1);
  int rowoff = lq * 128;
  int x0 = (lg * 16) ^ ((lq & 7) << 4);
  int x1 = (64 + lg * 16) ^ ((lq & 7) << 4);

  float bestA = 3.4e38f, bestB = 3.4e38f;
  int jA = 0, jB = 0;

  uint4 r0 = *(const uint4*)(gsrc);
  *(uint4*)((char*)&clds[0][part][0] + wbyte) = r0;

  for (int s = 0; s < 64; ++s) {
    int cur = s & 1;
    __syncthreads();
    uint4 rn;
    if (s < 63) rn = *(const uint4*)(gsrc + (size_t)(s + 1) * 1024);
    __builtin_amdgcn_sched_barrier(0);
    const char* ph = (const char*)&clds[cur][0][0];
    const char* pl = (const char*)&clds[cur][1][0];
    hfx8 ah0 = *(const hfx8*)(ph + rowoff + x0);
    hfx8 ah1 = *(const hfx8*)(ph + rowoff + x1);
    hfx8 al0 = *(const hfx8*)(pl + rowoff + x0);
    hfx8 al1 = *(const hfx8*)(pl + rowoff + x1);
    fx4 cq = *(const fx4*)(csq + s * 16 + lg * 4);
    {
      fx4 chi = cq;
      chi = __builtin_amdgcn_mfma_f32_16x16x32_f16(ah0, ba0, chi, 0, 0, 0);
      chi = __builtin_amdgcn_mfma_f32_16x16x32_f16(ah1, ba1, chi, 0, 0, 0);
      fx4 clo = (fx4){0.f, 0.f, 0.f, 0.f};
      clo = __builtin_amdgcn_mfma_f32_16x16x32_f16(ah0, la0, clo, 0, 0, 0);
      clo = __builtin_amdgcn_mfma_f32_16x16x32_f16(ah1, la1, clo, 0, 0, 0);
      clo = __builtin_amdgcn_mfma_f32_16x16x32_f16(al0, ba0, clo, 0, 0, 0);
      clo = __builtin_amdgcn_mfma_f32_16x16x32_f16(al1, ba1, clo, 0, 0, 0);
#pragma unroll
      for (int r_ = 0; r_ < 4; ++r_) {
        int j_ = s * 16 + lg * 4 + r_;
        float d2_ = chi[r_] + clo[r_] * (1.f / 2048.f);
        if (d2_ < bestA) { bestA = d2_; jA = j_; }
      }
    }
    if (DUO) {
      fx4 chi = cq;
      chi = __builtin_amdgcn_mfma_f32_16x16x32_f16(ah0, bb0, chi, 0, 0, 0);
      chi = __builtin_amdgcn_mfma_f32_16x16x32_f16(ah1, bb1, chi, 0, 0, 0);
      fx4 clo = (fx4){0.f, 0.f, 0.f, 0.f};
      clo = __builtin_amdgcn_mfma_f32_16x16x32_f16(ah0, lb0, clo, 0, 0, 0);
      clo = __builtin_amdgcn_mfma_f32_16x16x32_f16(ah1, lb1, clo, 0, 0, 0);
      clo = __builtin_amdgcn_mfma_f32_16x16x32_f16(al0, bb0, clo, 0, 0, 0);
      clo = __builtin_amdgcn_mfma_f32_16x16x32_f16(al1, bb1, clo, 0, 0, 0);
#pragma unroll
      for (int r_ = 0; r_ < 4; ++r_) {
        int j_ = s * 16 + lg * 4 + r_;
        float d2_ = chi[r_] + clo[r_] * (1.f / 2048.f);
        if (d2_ < bestB) { bestB = d2_; jB = j_; }
      }
    }
    __builtin_amdgcn_sched_barrier(0);
    if (s < 63) *(uint4*)((char*)&clds[cur ^ 1][part][0] + wbyte) = rn;
  }

  {
    float o = __shfl_xor(bestA, 16);
    int oj = __shfl_xor(jA, 16);
    if (o < bestA || (o == bestA && oj < jA)) { bestA = o; jA = oj; }
    o = __shfl_xor(bestA, 32);
    oj = __shfl_xor(jA, 32);
    if (o < bestA || (o == bestA && oj < jA)) { bestA = o; jA = oj; }
  }
  if (DUO) {
    float o = __shfl_xor(bestB, 16);
    int oj = __shfl_xor(jB, 16);
    if (o < bestB || (o == bestB && oj < jB)) { bestB = o; jB = oj; }
    o = __shfl_xor(bestB, 32);
    oj = __shfl_xor(jB, 32);
    if (o < bestB || (o == bestB && oj < jB)) { bestB = o; jB = oj; }
  }
  if (lg == 0) {
    aout[p0 + lq] = jA;
    if (DUO) aout[p0 + 16 + lq] = jB;
  }
}

// ---------------- exact f32 L1 distance to assigned centroid -----------------
__global__ void dist_k(const float* __restrict__ x, const float* __restrict__ cent,
                       const int* __restrict__ asg, float* __restrict__ dout) {
  int t = threadIdx.x, lane = t & 63, wv = t >> 6;
  int p = blockIdx.x * 4 + wv;
  int a = asg[p];
  float v = fabsf(cent[(size_t)a * 64 + lane] - x[(size_t)p * 64 + lane]);
  for (int off = 32; off; off >>= 1) v += __shfl_xor(v, off);
  if (lane == 0) dout[p] = v;
}

// ---------------- segment sum via atomics (wave=point: coalesced) ------------
__global__ void segsum_k(const float* __restrict__ x, const int* __restrict__ asg,
                         float* __restrict__ sums, float* __restrict__ cnt) {
  int t = threadIdx.x, lane = t & 63, wv = t >> 6;
  int p = blockIdx.x * 4 + wv;
  int a = asg[p];
  float v = x[(size_t)p * 64 + lane];
  atomicAdd(&sums[a * 64 + lane], v);
  if (lane == 0) atomicAdd(&cnt[a], 1.0f);
}

// ---------------- centroid update + prep + zero (fused) ----------------------
__global__ __launch_bounds__(256) void centup_prep_k(
    float* __restrict__ cent, float* __restrict__ sums, float* __restrict__ cnt,
    float* __restrict__ csq, unsigned short* __restrict__ cb2h,
    unsigned short* __restrict__ cb2l) {
  int i = blockIdx.x * 256 + threadIdx.x;  // 65536 total; rows never span blocks
  int j = i >> 6, lane = threadIdx.x & 63;
  float c = cnt[j];
  float oldc = cent[i];
  float newc = (c > 0.f) ? sums[i] / fmaxf(c, 1.f) : oldc;
  cent[i] = newc;
  float s = newc * newc;
  for (int off = 32; off; off >>= 1) s += __shfl_xor(s, off);
  if (lane == 0) csq[j] = s;
  float m2 = -2.f * newc;
  unsigned short h = f2h_bits(m2);
  cb2h[i] = h;
  cb2l[i] = f2h_bits((m2 - h_bits2f(h)) * 2048.f);
  sums[i] = 0.f;
  if (lane == 0) cnt[j] = 0.f;
}

// ---------------- per-bh top-1024 by descending dist (stable ties) -----------
__global__ __launch_bounds__(1024) void topk_k(const float* __restrict__ dist,
                                               int* __restrict__ sel) {
  __shared__ unsigned long long keys[2048];
  int bh = blockIdx.x, t = threadIdx.x;
  for (int i = t; i < 2048; i += 1024) {
    float d = dist[bh * 2048 + i];
    unsigned int db = __float_as_uint(d);  // d >= 0 -> monotonic
    keys[i] = ((unsigned long long)db << 32) | (unsigned int)(2047 - i);
  }
  __syncthreads();
  for (int k = 2; k <= 2048; k <<= 1) {
    for (int j = k >> 1; j > 0; j >>= 1) {
      for (int i = t; i < 2048; i += 1024) {
        int ixj = i ^ j;
        if (ixj > i) {
          unsigned long long a = keys[i], b = keys[ixj];
          bool up = ((i & k) == 0);
          bool sw = up ? (a < b) : (a > b);  // descending overall
          if (sw) { keys[i] = b; keys[ixj] = a; }
        }
      }
      __syncthreads();
    }
  }
  if (t < 1024) sel[bh * 1024 + t] = 2047 - (int)(keys[t] & 0xffffffffu);
}

// ---------------- gather selected rows -> kh (bf16 row-major), vT (bf16 d-major)
__global__ void gatherb_k(const float* __restrict__ kbuf, const float* __restrict__ vbuf,
                          const int* __restrict__ sel, unsigned short* __restrict__ kh,
                          unsigned short* __restrict__ vT) {
  __shared__ unsigned short tile[64][66];
  int t = threadIdx.x, lane = t & 63, wv = t >> 6;
  int bh = blockIdx.y, i0 = blockIdx.x * 64;
  for (int r = 0; r < 16; ++r) {
    int i = r * 4 + wv;
    int src = sel[bh * 1024 + i0 + i];
    float kvv = kbuf[((size_t)bh * 2048 + src) * 64 + lane];
    kh[((size_t)bh * 1024 + i0 + i) * 64 + lane] = f2bf(kvv);
    float vv = vbuf[((size_t)bh * 2048 + src) * 64 + lane];
    tile[i][lane] = f2bf(vv);
  }
  __syncthreads();
  for (int r = 0; r < 16; ++r) {
    int d = r * 4 + wv;
    vT[((size_t)bh * 64 + d) * 1024 + i0 + lane] = tile[lane][d];
  }
}

// ---------------- MFMA flash attention (K/V LDS-staged, barrier-light) -------
__global__ __launch_bounds__(256) void attn_mfma_k(
    const unsigned short* __restrict__ qh, const unsigned short* __restrict__ kh,
    const unsigned short* __restrict__ vT,
    unsigned short* __restrict__ oh, unsigned short* __restrict__ ol) {
  __shared__ __align__(16) unsigned short kvlds[2][2][4096];  // [buf][K/V][64x64]
  __shared__ unsigned short plds[4][16][72];
  int t = threadIdx.x, lane = t & 63, wv = t >> 6;
  int lq = lane & 15, lg = lane >> 4;
  int bh = blockIdx.y;
  int q0 = blockIdx.x * 64 + wv * 16;
  const unsigned short* qbase = qh + ((size_t)bh * 4096 + q0 + lq) * 64;
  bfx8 qf0 = *(const bfx8*)(qbase + lg * 8);
  bfx8 qf1 = *(const bfx8*)(qbase + 32 + lg * 8);
  fx4 acc[4];
  for (int nt = 0; nt < 4; ++nt) acc[nt] = (fx4){0.f, 0.f, 0.f, 0.f};
  float lsum = 0.f;
  const unsigned short* kbase = kh + (size_t)bh * 1024 * 64;
  const unsigned short* vbase = vT + (size_t)bh * 64 * 1024;

  int srow = t >> 2;
  int scolb = (t & 3) * 32;
  const char* gK = (const char*)kbase + (size_t)srow * 128 + scolb;   // + s*8192
  const char* gV = (const char*)vbase + (size_t)srow * 2048 + scolb;  // + s*128
  int sw_w = (srow & 7) << 4;
  int wb0 = srow * 128 + (scolb ^ sw_w);
  int wb1 = srow * 128 + ((scolb + 16) ^ sw_w);

  {
    uint4 k0 = *(const uint4*)(gK);
    uint4 k1 = *(const uint4*)(gK + 16);
    uint4 v0 = *(const uint4*)(gV);
    uint4 v1 = *(const uint4*)(gV + 16);
    *(uint4*)((char*)&kvlds[0][0][0] + wb0) = k0;
    *(uint4*)((char*)&kvlds[0][0][0] + wb1) = k1;
    *(uint4*)((char*)&kvlds[0][1][0] + wb0) = v0;
    *(uint4*)((char*)&kvlds[0][1][0] + wb1) = v1;
  }

  int swr = (lq & 7) << 4;
  int rc0 = (lg * 16) ^ swr;
  int rc1 = (64 + lg * 16) ^ swr;

  for (int s = 0; s < 16; ++s) {
    int cur = s & 1;
    __syncthreads();
    uint4 nk0, nk1, nv0, nv1;
    if (s < 15) {
      const char* gKn = gK + (size_t)(s + 1) * 8192;
      const char* gVn = gV + (size_t)(s + 1) * 128;
      nk0 = *(const uint4*)(gKn);
      nk1 = *(const uint4*)(gKn + 16);
      nv0 = *(const uint4*)(gVn);
      nv1 = *(const uint4*)(gVn + 16);
    }
    __builtin_amdgcn_sched_barrier(0);
    const char* Kb = (const char*)&kvlds[cur][0][0];
    const char* Vb = (const char*)&kvlds[cur][1][0];
    fx4 sS[4];
#pragma unroll
    for (int mt = 0; mt < 4; ++mt) {
      int rowb = (mt * 16 + lq) * 128;
      bfx8 a0 = *(const bfx8*)(Kb + rowb + rc0);
      bfx8 a1 = *(const bfx8*)(Kb + rowb + rc1);
      fx4 c = (fx4){0.f, 0.f, 0.f, 0.f};
      c = __builtin_amdgcn_mfma_f32_16x16x32_bf16(a0, qf0, c, 0, 0, 0);
      c = __builtin_amdgcn_mfma_f32_16x16x32_bf16(a1, qf1, c, 0, 0, 0);
      sS[mt] = c;
    }
#pragma unroll
    for (int mt = 0; mt < 4; ++mt) {
      float p0 = __expf(sS[mt].x), p1 = __expf(sS[mt].y);
      float p2 = __expf(sS[mt].z), p3 = __expf(sS[mt].w);
      lsum += (p0 + p1) + (p2 + p3);
      us4 pk = {f2bf(p0), f2bf(p1), f2bf(p2), f2bf(p3)};
      *(us4*)&plds[wv][lq][mt * 16 + lg * 4] = pk;
    }
    bfx8 pa0 = *(const bfx8*)&plds[wv][lq][lg * 8];
    bfx8 pa1 = *(const bfx8*)&plds[wv][lq][32 + lg * 8];
#pragma unroll
    for (int nt = 0; nt < 4; ++nt) {
      int rowb = (nt * 16 + lq) * 128;
      bfx8 b0 = *(const bfx8*)(Vb + rowb + rc0);
      bfx8 b1 = *(const bfx8*)(Vb + rowb + rc1);
      acc[nt] = __builtin_amdgcn_mfma_f32_16x16x32_bf16(pa0, b0, acc[nt], 0, 0, 0);
      acc[nt] = __builtin_amdgcn_mfma_f32_16x16x32_bf16(pa1, b1, acc[nt], 0, 0, 0);
    }
    __builtin_amdgcn_sched_barrier(0);
    if (s < 15) {
      char* dK = (char*)&kvlds[cur ^ 1][0][0];
      char* dV = (char*)&kvlds[cur ^ 1][1][0];
      *(uint4*)(dK + wb0) = nk0;
      *(uint4*)(dK + wb1) = nk1;
      *(uint4*)(dV + wb0) = nv0;
      *(uint4*)(dV + wb1) = nv1;
    }
  }
  lsum += __shfl_xor(lsum, 16);
  lsum += __shfl_xor(lsum, 32);
  int bi = bh >> 3, hd = bh & 7;
  for (int r = 0; r < 4; ++r) {
    float inv = 1.f / __shfl(lsum, lg * 4 + r);
    size_t rowb = ((size_t)bi * 4096 + q0 + lg * 4 + r) * 512 + hd * 64;
    for (int nt = 0; nt < 4; ++nt) {
      float val = acc[nt][r] * inv;
      unsigned short hb = f2h_bits(val);
      oh[rowb + nt * 16 + lq] = hb;
      ol[rowb + nt * 16 + lq] = f2h_bits((val - h_bits2f(hb)) * 2048.f);
    }
  }
}

// ---------------- final LN + gamma*ln + residual (wave-split channels) -------
__global__ __launch_bounds__(256) void final_k(
    const float* __restrict__ y, const float* __restrict__ g,
    const float* __restrict__ bta, const float* __restrict__ gamma,
    const float* __restrict__ qs, float* __restrict__ out) {
  __shared__ float p1[4][64], p2[4][64];
  __shared__ float mArr[64], invArr[64];
  int t = threadIdx.x, lane = t & 63, wv = t >> 6;
  int n0 = blockIdx.x * 64, bi = blockIdx.y;
  const float* yb = y + (size_t)bi * CDIM * NQ + n0 + lane;
  float s = 0.f, s2 = 0.f;
  for (int cl = 0; cl < 64; ++cl) {
    float v = yb[(size_t)(wv * 64 + cl) * NQ];
    s += v;
    s2 += v * v;
  }
  p1[wv][lane] = s;
  p2[wv][lane] = s2;
  __syncthreads();
  if (t < 64) {
    float ts = p1[0][t] + p1[1][t] + p1[2][t] + p1[3][t];
    float ts2 = p2[0][t] + p2[1][t] + p2[2][t] + p2[3][t];
    float m = ts / CDIM;
    float var = ts2 / CDIM - m * m;
    mArr[t] = m;
    invArr[t] = 1.f / (sqrtf(fmaxf(var, 0.f)) + 1e-6f);
  }
  __syncthreads();
  float gm = gamma[0];
  float m = mArr[lane], inv = invArr[lane];
  const float* qb = qs + (size_t)bi * CDIM * NQ + n0 + lane;
  float* ob = out + (size_t)bi * CDIM * NQ + n0 + lane;
  for (int cl = 0; cl < 64; ++cl) {
    int c = wv * 64 + cl;
    float v = yb[(size_t)c * NQ];
    float ln = g[c] * (v - m) * inv + bta[c];
    ob[(size_t)c * NQ] = gm * ln + qb[(size_t)c * NQ];
  }
}

extern "C" void kernel_launch(void* const* d_in, const int* in_sizes, int n_in,
                              void* d_out, int out_size, void* d_ws, size_t ws_size,
                              hipStream_t stream) {
  const float* qsrc = (const float*)d_in[0];
  const float* ctx = (const float*)d_in[1];
  const float* w_q = (const float*)d_in[2];
  const float* w_kv = (const float*)d_in[3];
  const float* w_out = (const float*)d_in[4];
  const float* cn_g = (const float*)d_in[5];
  const float* cn_b = (const float*)d_in[6];
  const float* qn_g = (const float*)d_in[7];
  const float* qn_b = (const float*)d_in[8];
  const float* on_g = (const float*)d_in[9];
  const float* on_b = (const float*)d_in[10];
  const float* gamma = (const float*)d_in[11];

  // scratch layout (floats); total 22,267,904 floats = 89.1 MB
  if (ws_size < (size_t)22267904 * 4) return;
  float* ws = (float*)d_ws;
  float* r_ctx = ws;                      // 1,048,576 f: ctx split-f16; later kh/vT
  float* r_kv = r_ctx + 1048576;          // 4,194,304 f: kbh/kbl f16; later attnt split
  float* r_qs = r_kv + 4194304;           // 2,097,152 f: qs split-f16; later cb2h/l, ybuf
  float* r_q3 = r_qs + 2097152;           // 4,194,304 f: qbh/qbl f16
  float* qbuf = r_q3 + 4194304;           // 4,194,304 f
  float* kbuf = qbuf + 4194304;           // 2,097,152 f
  float* vbuf = kbuf + 2097152;           // 2,097,152 f
  float* cent = vbuf + 2097152;           // 65,536 f
  float* csq = cent + 65536;              // 1,024 f
  float* sums = csq + 1024;               // 65,536 f
  float* cnt = sums + 65536;              // 1,024 f
  int* asg = (int*)(cnt + 1024);          // 65,536 i
  float* dist = (float*)(asg + 65536);    // 32,768 f
  int* sel = (int*)(dist + 32768);        // 16,384 i
  float* kgreg = (float*)(sel + 16384);   // 2,097,152 f (qh bf16)

  unsigned short* ctxth = (unsigned short*)r_ctx;   // [b][2048][256] f16 hi
  unsigned short* ctxtl = ctxth + (size_t)BB * NK * CDIM;  // lo
  unsigned short* qsth = (unsigned short*)r_qs;     // [b][4096][256] f16 hi
  unsigned short* qstl = qsth + (size_t)BB * NQ * CDIM;    // lo
  unsigned short* qh = (unsigned short*)kgreg;      // 4M bf16
  unsigned short* kh = (unsigned short*)r_ctx;      // 1M bf16 (ctx split dead)
  unsigned short* vT = kh + 1048576;                // 1M bf16
  unsigned short* qbh = (unsigned short*)r_q3;      // 4M f16 (q split hi)
  unsigned short* qbl = qbh + (size_t)NPQ * 64;     // 4M f16 (lo)
  unsigned short* kbh = (unsigned short*)r_kv;      // 2M f16 (k split hi)
  unsigned short* kbl = kbh + (size_t)NPK * 64;     // 2M f16 (lo)
  unsigned short* cb2h = (unsigned short*)r_qs;     // 64K f16 (-2c hi)
  unsigned short* cb2l = cb2h + 65536;              // 64K f16 (lo)
  unsigned short* attnth = (unsigned short*)r_kv;   // [b][4096][512] f16 hi (kb split dead)
  unsigned short* attntl = attnth + (size_t)BB * NQ * 512;  // lo
  float* ybuf = r_qs;                     // [b][256][4096] f32 (cb2 dead)

  // 1. channel LayerNorms -> transposed split-f16
  chan_ln_tsplit_k<<<dim3(NK / 64, BB), 256, 0, stream>>>(ctx, cn_g, cn_b, ctxth, ctxtl, CDIM, NK);
  chan_ln_tsplit_k<<<dim3(NQ / 64, BB), 256, 0, stream>>>(qsrc, qn_g, qn_b, qsth, qstl, CDIM, NQ);
  // 2. fused MFMA projections + fold + L2-norm + format emit (LDS-pipelined)
  gemmfold_k<1><<<dim3(NK / 64, 16, BB), 256, 0, stream>>>(
      w_kv, ctxth, ctxtl, kbuf, kbh, kbl, nullptr, vbuf, CDIM, NK);
  gemmfold_k<0><<<dim3(NQ / 64, 8, BB), 256, 0, stream>>>(
      w_q, qsth, qstl, qbuf, qbh, qbl, qh, nullptr, CDIM, NQ);
  // 3. k-means: initial prep + one memset; centup_prep fuses update/prep/zero
  hipMemcpyAsync(cent, qbuf, 65536 * sizeof(float), hipMemcpyDeviceToDevice, stream);
  centprep_k<<<1024, 64, 0, stream>>>(cent, csq, cb2h, cb2l);
  hipMemsetAsync(sums, 0, (65536 + 1024) * sizeof(float), stream);
  for (int it = 0; it < 4; ++it) {
    assign_mfma_k<1><<<NPQ / 128, 256, 0, stream>>>(qbh, qbl, cb2h, cb2l, csq, asg);
    segsum_k<<<NPQ / 4, 256, 0, stream>>>(qbuf, asg, sums, cnt);
    centup_prep_k<<<65536 / 256, 256, 0, stream>>>(cent, sums, cnt, csq, cb2h, cb2l);
  }
  // 4. score keys: argmin (MFMA) -> exact f32 L1 dist -> per-head top-1024
  assign_mfma_k<0><<<NPK / 64, 256, 0, stream>>>(kbh, kbl, cb2h, cb2l, csq, asg);
  dist_k<<<NPK / 4, 256, 0, stream>>>(kbuf, cent, asg, dist);
  topk_k<<<BH, 1024, 0, stream>>>(dist, sel);
  // 5. gather (kh row-major bf16, vT transposed bf16)
  gatherb_k<<<dim3(TOPK / 64, BH), 256, 0, stream>>>(kbuf, vbuf, sel, kh, vT);
  // 6. MFMA attention -> split-f16 un-folded [b][n][512]
  attn_mfma_k<<<dim3(NQ / 64, BH), 256, 0, stream>>>(qh, kh, vT, attnth, attntl);
  // 7. output projection (MFMA)
  gemm_mfma_k<<<dim3(NQ / 64, 256 / 64, BB), 256, 0, stream>>>(w_out, attnth, attntl, ybuf, 256, 512, NQ);
  // 8. final LN + residual
  final_k<<<dim3(NQ / 64, BB), 256, 0, stream>>>(ybuf, on_g, on_b, gamma, qsrc, (float*)d_out);
}

// Round 15
// 535.480 us; speedup vs baseline: 1.8605x; 1.0030x over previous
//
#include <hip/hip_runtime.h>
#include <math.h>

#define BB 2
#define CDIM 256
#define NQ 4096   // 16*16*16
#define NK 2048   // 8*16*16
#define BH 16
#define TOPK 1024
#define NPQ (BH*NQ)   // 65536
#define NPK (BH*NK)   // 32768

typedef __attribute__((ext_vector_type(8))) short bfx8;
typedef __attribute__((ext_vector_type(8))) _Float16 hfx8;
typedef __attribute__((ext_vector_type(2))) __fp16 fpx2;
typedef __attribute__((ext_vector_type(4))) float fx4;
typedef __attribute__((ext_vector_type(4))) unsigned short us4;

__device__ inline unsigned short f2bf(float x) {
  unsigned u = __float_as_uint(x);
  return (unsigned short)((u + 0x7fffu + ((u >> 16) & 1u)) >> 16);
}
__device__ inline unsigned short f2h_bits(float x) {
  _Float16 h = (_Float16)x;
  unsigned short u;
  __builtin_memcpy(&u, &h, 2);
  return u;
}
__device__ inline float h_bits2f(unsigned short u) {
  _Float16 h;
  __builtin_memcpy(&h, &u, 2);
  return (float)h;
}

// ------- channel LayerNorm -> transposed split-f16 [b][n][C] (hi, lo*2048) ---
__global__ __launch_bounds__(256) void chan_ln_tsplit_k(
    const float* __restrict__ x, const float* __restrict__ g,
    const float* __restrict__ bta, unsigned short* __restrict__ yh,
    unsigned short* __restrict__ yl, int C, int N) {
  __shared__ float tile[4][64][65];
  __shared__ float p1[4][64], p2[4][64];
  __shared__ float mArr[64], invArr[64];
  int t = threadIdx.x, lane = t & 63, wv = t >> 6;
  int n0 = blockIdx.x * 64, bi = blockIdx.y;
  const float* xb = x + (size_t)bi * C * N + n0 + lane;
  float s = 0.f, s2 = 0.f;
  for (int cl = 0; cl < 64; ++cl) {
    float v = xb[(size_t)(wv * 64 + cl) * N];
    tile[wv][cl][lane] = v;
    s += v;
    s2 += v * v;
  }
  p1[wv][lane] = s;
  p2[wv][lane] = s2;
  __syncthreads();
  if (t < 64) {
    float ts = p1[0][t] + p1[1][t] + p1[2][t] + p1[3][t];
    float ts2 = p2[0][t] + p2[1][t] + p2[2][t] + p2[3][t];
    float m = ts / C;
    float var = ts2 / C - m * m;
    mArr[t] = m;
    invArr[t] = 1.f / (sqrtf(fmaxf(var, 0.f)) + 1e-6f);
  }
  __syncthreads();
  int c = wv * 64 + lane;  // lane = channel in phase 2
  float gc = g[c], bc = bta[c];
  unsigned short* ohb = yh + ((size_t)bi * N + n0) * C + c;
  unsigned short* olb = yl + ((size_t)bi * N + n0) * C + c;
  for (int pl = 0; pl < 64; ++pl) {
    float v = tile[wv][lane][pl];
    float ln = gc * (v - mArr[pl]) * invArr[pl] + bc;
    unsigned short hb = f2h_bits(ln);
    ohb[(size_t)pl * C] = hb;
    olb[(size_t)pl * C] = f2h_bits((ln - h_bits2f(hb)) * 2048.f);
  }
}

// ------- plain MFMA GEMM (w_out): Y[b][o][n] = sum_c W[o][c]*Xt[b][n][c] -----
__global__ __launch_bounds__(256) void gemm_mfma_k(
    const float* __restrict__ W, const unsigned short* __restrict__ Xh,
    const unsigned short* __restrict__ Xl, float* __restrict__ Y,
    int O, int C, int N) {
  int t = threadIdx.x, lane = t & 63, wv = t >> 6;
  int lq = lane & 15, lg = lane >> 4;
  int n0 = blockIdx.x * 64, o0 = blockIdx.y * 64 + wv * 16;
  int b = blockIdx.z;
  const unsigned short* xbh = Xh + ((size_t)b * N + n0) * C;
  const unsigned short* xbl = Xl + ((size_t)b * N + n0) * C;
  const float* wr = W + (size_t)(o0 + lq) * C;
  fx4 ahi[4], alo[4];
  for (int nt = 0; nt < 4; ++nt) {
    ahi[nt] = (fx4){0.f, 0.f, 0.f, 0.f};
    alo[nt] = (fx4){0.f, 0.f, 0.f, 0.f};
  }
  for (int k0 = 0; k0 < C; k0 += 32) {
    float4 w0 = *(const float4*)(wr + k0 + lg * 8);
    float4 w1 = *(const float4*)(wr + k0 + lg * 8 + 4);
    float wv8[8] = {w0.x, w0.y, w0.z, w0.w, w1.x, w1.y, w1.z, w1.w};
    hfx8 ah, al;
#pragma unroll
    for (int i = 0; i < 8; ++i) {
      _Float16 h = (_Float16)wv8[i];
      ah[i] = h;
      al[i] = (_Float16)((wv8[i] - (float)h) * 2048.f);
    }
#pragma unroll
    for (int nt = 0; nt < 4; ++nt) {
      const unsigned short* bph = xbh + (size_t)(nt * 16 + lq) * C + k0 + lg * 8;
      const unsigned short* bpl = xbl + (size_t)(nt * 16 + lq) * C + k0 + lg * 8;
      hfx8 bh = *(const hfx8*)bph;
      hfx8 bl = *(const hfx8*)bpl;
      ahi[nt] = __builtin_amdgcn_mfma_f32_16x16x32_f16(ah, bh, ahi[nt], 0, 0, 0);
      alo[nt] = __builtin_amdgcn_mfma_f32_16x16x32_f16(al, bh, alo[nt], 0, 0, 0);
      alo[nt] = __builtin_amdgcn_mfma_f32_16x16x32_f16(ah, bl, alo[nt], 0, 0, 0);
    }
  }
  float* yb = Y + ((size_t)b * O + o0) * N + n0;
#pragma unroll
  for (int nt = 0; nt < 4; ++nt)
#pragma unroll
    for (int r = 0; r < 4; ++r)
      yb[(size_t)(lg * 4 + r) * N + nt * 16 + lq] = ahi[nt][r] + alo[nt][r] * (1.f / 2048.f);
}

// ------- fused GEMM + head-fold + L2-norm + multi-format emit ---------------
template <int PATH>
__global__ __launch_bounds__(256) void gemmfold_k(
    const float* __restrict__ W, const unsigned short* __restrict__ Xh,
    const unsigned short* __restrict__ Xl, float* __restrict__ fq,
    unsigned short* __restrict__ sh, unsigned short* __restrict__ sl,
    unsigned short* __restrict__ b16, float* __restrict__ fv,
    int C, int N) {
  __shared__ __align__(16) unsigned short xlds[2][64][64];  // [buf][row][hi32|lo32]
  __shared__ float ftile[64][65];
  __shared__ float part[4][64];
  __shared__ float invArr[64];
  int t = threadIdx.x, lane = t & 63, wv = t >> 6;
  int lq = lane & 15, lg = lane >> 4;
  int n0 = blockIdx.x * 64, o0 = blockIdx.y * 64 + wv * 16;
  int b = blockIdx.z;
  bool isV = (PATH == 1) && (blockIdx.y >= 8);
  int h = (PATH == 1) ? (blockIdx.y & 7) : blockIdx.y;
  const unsigned short* xbh = Xh + ((size_t)b * N + n0) * C;
  const unsigned short* xbl = Xl + ((size_t)b * N + n0) * C;
  const float* wr = W + (size_t)(o0 + lq) * C;

  int a = t * 16;
  int srow = a >> 6;
  int schunk = (a >> 4) & 3;
  const unsigned short* gsh = xbh + (size_t)srow * C + schunk * 8;
  const unsigned short* gsl = xbl + (size_t)srow * C + schunk * 8;
  int swz = (srow & 7) << 4;
  int wbh = srow * 128 + ((schunk * 16) ^ swz);
  int wbl = srow * 128 + ((64 + schunk * 16) ^ swz);
  int rswz = (lq & 7) << 4;
  int xh0 = (lg * 16) ^ rswz;
  int xl0 = (64 + lg * 16) ^ rswz;

  fx4 ahi[4], alo[4];
  for (int nt = 0; nt < 4; ++nt) {
    ahi[nt] = (fx4){0.f, 0.f, 0.f, 0.f};
    alo[nt] = (fx4){0.f, 0.f, 0.f, 0.f};
  }

  {
    uint4 h0 = *(const uint4*)(gsh);
    uint4 l0 = *(const uint4*)(gsl);
    *(uint4*)((char*)&xlds[0][0][0] + wbh) = h0;
    *(uint4*)((char*)&xlds[0][0][0] + wbl) = l0;
  }
  float4 w0c = *(const float4*)(wr + lg * 8);
  float4 w1c = *(const float4*)(wr + lg * 8 + 4);

  for (int s = 0; s < 8; ++s) {
    int cur = s & 1;
    __syncthreads();
    uint4 nh, nl;
    float4 nw0, nw1;
    if (s < 7) {
      nh = *(const uint4*)(gsh + (s + 1) * 32);
      nl = *(const uint4*)(gsl + (s + 1) * 32);
      nw0 = *(const float4*)(wr + (s + 1) * 32 + lg * 8);
      nw1 = *(const float4*)(wr + (s + 1) * 32 + lg * 8 + 4);
    }
    __builtin_amdgcn_sched_barrier(0);
    float wv8[8] = {w0c.x, w0c.y, w0c.z, w0c.w, w1c.x, w1c.y, w1c.z, w1c.w};
    hfx8 ah, al;
#pragma unroll
    for (int i = 0; i < 8; ++i) {
      _Float16 hh = (_Float16)wv8[i];
      ah[i] = hh;
      al[i] = (_Float16)((wv8[i] - (float)hh) * 2048.f);
    }
    const char* Xb = (const char*)&xlds[cur][0][0];
#pragma unroll
    for (int nt = 0; nt < 4; ++nt) {
      int rb = (nt * 16 + lq) * 128;
      hfx8 bh = *(const hfx8*)(Xb + rb + xh0);
      hfx8 bl = *(const hfx8*)(Xb + rb + xl0);
      ahi[nt] = __builtin_amdgcn_mfma_f32_16x16x32_f16(ah, bh, ahi[nt], 0, 0, 0);
      alo[nt] = __builtin_amdgcn_mfma_f32_16x16x32_f16(al, bh, alo[nt], 0, 0, 0);
      alo[nt] = __builtin_amdgcn_mfma_f32_16x16x32_f16(ah, bl, alo[nt], 0, 0, 0);
    }
    __builtin_amdgcn_sched_barrier(0);
    if (s < 7) {
      *(uint4*)((char*)&xlds[cur ^ 1][0][0] + wbh) = nh;
      *(uint4*)((char*)&xlds[cur ^ 1][0][0] + wbl) = nl;
      w0c = nw0;
      w1c = nw1;
    }
  }

  float val[4][4];
#pragma unroll
  for (int nt = 0; nt < 4; ++nt)
#pragma unroll
    for (int r = 0; r < 4; ++r)
      val[nt][r] = ahi[nt][r] + alo[nt][r] * (1.f / 2048.f);
  __syncthreads();
  if (!isV) {
#pragma unroll
    for (int nt = 0; nt < 4; ++nt) {
      float ss = val[nt][0] * val[nt][0] + val[nt][1] * val[nt][1] +
                 val[nt][2] * val[nt][2] + val[nt][3] * val[nt][3];
      ss += __shfl_xor(ss, 16);
      ss += __shfl_xor(ss, 32);
      if (lg == 0) part[wv][nt * 16 + lq] = ss;
    }
    __syncthreads();
    if (t < 64) {
      float tot = part[0][t] + part[1][t] + part[2][t] + part[3][t];
      invArr[t] = 1.f / fmaxf(sqrtf(tot), 1e-12f);
    }
    __syncthreads();
#pragma unroll
    for (int nt = 0; nt < 4; ++nt) {
      float iv = invArr[nt * 16 + lq];
#pragma unroll
      for (int r = 0; r < 4; ++r) val[nt][r] *= iv;
    }
    __syncthreads();
  }
#pragma unroll
  for (int nt = 0; nt < 4; ++nt)
#pragma unroll
    for (int r = 0; r < 4; ++r)
      ftile[nt * 16 + lq][wv * 16 + lg * 4 + r] = val[nt][r];
  __syncthreads();
  size_t rowb = (size_t)(b * 8 + h) * N + n0;
  for (int r2 = 0; r2 < 16; ++r2) {
    int n = r2 * 4 + wv;
    float v = ftile[n][lane];
    size_t idx = (rowb + n) * 64 + lane;
    if (PATH == 1 && isV) {
      fv[idx] = v;
    } else {
      fq[idx] = v;
      unsigned short hb = f2h_bits(v);
      sh[idx] = hb;
      sl[idx] = f2h_bits((v - h_bits2f(hb)) * 2048.f);
      if (PATH == 0) b16[idx] = hb;  // f16 copy for attention
    }
  }
}

// ---------------- centroid prep (initial only): csq, -2c split f16 -----------
__global__ void centprep_k(const float* __restrict__ cent, float* __restrict__ csq,
                           unsigned short* __restrict__ cb2h, unsigned short* __restrict__ cb2l) {
  int j = blockIdx.x, lane = threadIdx.x;  // blockDim = 64
  float c = cent[j * 64 + lane];
  float s = c * c;
  for (int off = 32; off; off >>= 1) s += __shfl_xor(s, off);
  if (lane == 0) csq[j] = s;
  float m2 = -2.f * c;
  unsigned short h = f2h_bits(m2);
  cb2h[j * 64 + lane] = h;
  cb2l[j * 64 + lane] = f2h_bits((m2 - h_bits2f(h)) * 2048.f);
}

// ---------------- MFMA nearest-centroid assign (f16 split, LDS-staged) -------
template <int DUO>
__global__ __launch_bounds__(256) void assign_mfma_k(
    const unsigned short* __restrict__ xh, const unsigned short* __restrict__ xl,
    const unsigned short* __restrict__ cb2h, const unsigned short* __restrict__ cb2l,
    const float* __restrict__ csq, int* __restrict__ aout) {
  __shared__ __align__(16) unsigned short clds[2][2][1024];  // [buf][hi/lo][16x64]
  int t = threadIdx.x, lane = t & 63, wv = t >> 6;
  int lq = lane & 15, lg = lane >> 4;
  int p0 = blockIdx.x * (DUO ? 128 : 64) + wv * (DUO ? 32 : 16);
  const unsigned short* xbA = xh + (size_t)(p0 + lq) * 64;
  const unsigned short* xlA = xl + (size_t)(p0 + lq) * 64;
  hfx8 ba0 = *(const hfx8*)(xbA + lg * 8);
  hfx8 ba1 = *(const hfx8*)(xbA + 32 + lg * 8);
  hfx8 la0 = *(const hfx8*)(xlA + lg * 8);
  hfx8 la1 = *(const hfx8*)(xlA + 32 + lg * 8);
  hfx8 bb0, bb1, lb0, lb1;
  if (DUO) {
    const unsigned short* xbB = xh + (size_t)(p0 + 16 + lq) * 64;
    const unsigned short* xlB = xl + (size_t)(p0 + 16 + lq) * 64;
    bb0 = *(const hfx8*)(xbB + lg * 8);
    bb1 = *(const hfx8*)(xbB + 32 + lg * 8);
    lb0 = *(const hfx8*)(xlB + lg * 8);
    lb1 = *(const hfx8*)(xlB + 32 + lg * 8);
  }

  int part = t >> 7;
  int abyte = (t & 127) * 16;
  int wbyte = abyte ^ (((abyte >> 7) & 7) << 4);
  const unsigned short* gsrc = (part ? cb2l : cb2h) + (abyte >> 1);
  int rowoff = lq * 128;
  int x0 = (lg * 16) ^ ((lq & 7) << 4);
  int x1 = (64 + lg * 16) ^ ((lq & 7) << 4);

  float bestA = 3.4e38f, bestB = 3.4e38f;
  int jA = 0, jB = 0;

  uint4 r0 = *(const uint4*)(gsrc);
  *(uint4*)((char*)&clds[0][part][0] + wbyte) = r0;

  for (int s = 0; s < 64; ++s) {
    int cur = s & 1;
    __syncthreads();
    uint4 rn;
    if (s < 63) rn = *(const uint4*)(gsrc + (size_t)(s + 1) * 1024);
    __builtin_amdgcn_sched_barrier(0);
    const char* ph = (const char*)&clds[cur][0][0];
    const char* pl = (const char*)&clds[cur][1][0];
    hfx8 ah0 = *(const hfx8*)(ph + rowoff + x0);
    hfx8 ah1 = *(const hfx8*)(ph + rowoff + x1);
    hfx8 al0 = *(const hfx8*)(pl + rowoff + x0);
    hfx8 al1 = *(const hfx8*)(pl + rowoff + x1);
    fx4 cq = *(const fx4*)(csq + s * 16 + lg * 4);
    {
      fx4 chi = cq;
      chi = __builtin_amdgcn_mfma_f32_16x16x32_f16(ah0, ba0, chi, 0, 0, 0);
      chi = __builtin_amdgcn_mfma_f32_16x16x32_f16(ah1, ba1, chi, 0, 0, 0);
      fx4 clo = (fx4){0.f, 0.f, 0.f, 0.f};
      clo = __builtin_amdgcn_mfma_f32_16x16x32_f16(ah0, la0, clo, 0, 0, 0);
      clo = __builtin_amdgcn_mfma_f32_16x16x32_f16(ah1, la1, clo, 0, 0, 0);
      clo = __builtin_amdgcn_mfma_f32_16x16x32_f16(al0, ba0, clo, 0, 0, 0);
      clo = __builtin_amdgcn_mfma_f32_16x16x32_f16(al1, ba1, clo, 0, 0, 0);
#pragma unroll
      for (int r_ = 0; r_ < 4; ++r_) {
        int j_ = s * 16 + lg * 4 + r_;
        float d2_ = chi[r_] + clo[r_] * (1.f / 2048.f);
        if (d2_ < bestA) { bestA = d2_; jA = j_; }
      }
    }
    if (DUO) {
      fx4 chi = cq;
      chi = __builtin_amdgcn_mfma_f32_16x16x32_f16(ah0, bb0, chi, 0, 0, 0);
      chi = __builtin_amdgcn_mfma_f32_16x16x32_f16(ah1, bb1, chi, 0, 0, 0);
      fx4 clo = (fx4){0.f, 0.f, 0.f, 0.f};
      clo = __builtin_amdgcn_mfma_f32_16x16x32_f16(ah0, lb0, clo, 0, 0, 0);
      clo = __builtin_amdgcn_mfma_f32_16x16x32_f16(ah1, lb1, clo, 0, 0, 0);
      clo = __builtin_amdgcn_mfma_f32_16x16x32_f16(al0, bb0, clo, 0, 0, 0);
      clo = __builtin_amdgcn_mfma_f32_16x16x32_f16(al1, bb1, clo, 0, 0, 0);
#pragma unroll
      for (int r_ = 0; r_ < 4; ++r_) {
        int j_ = s * 16 + lg * 4 + r_;
        float d2_ = chi[r_] + clo[r_] * (1.f / 2048.f);
        if (d2_ < bestB) { bestB = d2_; jB = j_; }
      }
    }
    __builtin_amdgcn_sched_barrier(0);
    if (s < 63) *(uint4*)((char*)&clds[cur ^ 1][part][0] + wbyte) = rn;
  }

  {
    float o = __shfl_xor(bestA, 16);
    int oj = __shfl_xor(jA, 16);
    if (o < bestA || (o == bestA && oj < jA)) { bestA = o; jA = oj; }
    o = __shfl_xor(bestA, 32);
    oj = __shfl_xor(jA, 32);
    if (o < bestA || (o == bestA && oj < jA)) { bestA = o; jA = oj; }
  }
  if (DUO) {
    float o = __shfl_xor(bestB, 16);
    int oj = __shfl_xor(jB, 16);
    if (o < bestB || (o == bestB && oj < jB)) { bestB = o; jB = oj; }
    o = __shfl_xor(bestB, 32);
    oj = __shfl_xor(jB, 32);
    if (o < bestB || (o == bestB && oj < jB)) { bestB = o; jB = oj; }
  }
  if (lg == 0) {
    aout[p0 + lq] = jA;
    if (DUO) aout[p0 + 16 + lq] = jB;
  }
}

// ---------------- exact f32 L1 distance to assigned centroid -----------------
__global__ void dist_k(const float* __restrict__ x, const float* __restrict__ cent,
                       const int* __restrict__ asg, float* __restrict__ dout) {
  int t = threadIdx.x, lane = t & 63, wv = t >> 6;
  int p = blockIdx.x * 4 + wv;
  int a = asg[p];
  float v = fabsf(cent[(size_t)a * 64 + lane] - x[(size_t)p * 64 + lane]);
  for (int off = 32; off; off >>= 1) v += __shfl_xor(v, off);
  if (lane == 0) dout[p] = v;
}

// ---------------- segment sum via atomics (wave=point: coalesced) ------------
__global__ void segsum_k(const float* __restrict__ x, const int* __restrict__ asg,
                         float* __restrict__ sums, float* __restrict__ cnt) {
  int t = threadIdx.x, lane = t & 63, wv = t >> 6;
  int p = blockIdx.x * 4 + wv;
  int a = asg[p];
  float v = x[(size_t)p * 64 + lane];
  atomicAdd(&sums[a * 64 + lane], v);
  if (lane == 0) atomicAdd(&cnt[a], 1.0f);
}

// ---------------- centroid update + prep + zero (fused) ----------------------
__global__ __launch_bounds__(256) void centup_prep_k(
    float* __restrict__ cent, float* __restrict__ sums, float* __restrict__ cnt,
    float* __restrict__ csq, unsigned short* __restrict__ cb2h,
    unsigned short* __restrict__ cb2l) {
  int i = blockIdx.x * 256 + threadIdx.x;  // 65536 total; rows never span blocks
  int j = i >> 6, lane = threadIdx.x & 63;
  float c = cnt[j];
  float oldc = cent[i];
  float newc = (c > 0.f) ? sums[i] / fmaxf(c, 1.f) : oldc;
  cent[i] = newc;
  float s = newc * newc;
  for (int off = 32; off; off >>= 1) s += __shfl_xor(s, off);
  if (lane == 0) csq[j] = s;
  float m2 = -2.f * newc;
  unsigned short h = f2h_bits(m2);
  cb2h[i] = h;
  cb2l[i] = f2h_bits((m2 - h_bits2f(h)) * 2048.f);
  sums[i] = 0.f;
  if (lane == 0) cnt[j] = 0.f;
}

// ---------------- per-bh top-1024 by descending dist (stable ties) -----------
__global__ __launch_bounds__(1024) void topk_k(const float* __restrict__ dist,
                                               int* __restrict__ sel) {
  __shared__ unsigned long long keys[2048];
  int bh = blockIdx.x, t = threadIdx.x;
  for (int i = t; i < 2048; i += 1024) {
    float d = dist[bh * 2048 + i];
    unsigned int db = __float_as_uint(d);  // d >= 0 -> monotonic
    keys[i] = ((unsigned long long)db << 32) | (unsigned int)(2047 - i);
  }
  __syncthreads();
  for (int k = 2; k <= 2048; k <<= 1) {
    for (int j = k >> 1; j > 0; j >>= 1) {
      for (int i = t; i < 2048; i += 1024) {
        int ixj = i ^ j;
        if (ixj > i) {
          unsigned long long a = keys[i], b = keys[ixj];
          bool up = ((i & k) == 0);
          bool sw = up ? (a < b) : (a > b);  // descending overall
          if (sw) { keys[i] = b; keys[ixj] = a; }
        }
      }
      __syncthreads();
    }
  }
  if (t < 1024) sel[bh * 1024 + t] = 2047 - (int)(keys[t] & 0xffffffffu);
}

// ---------------- gather selected rows -> kh (f16 row-major), vT (f16 d-major)
__global__ void gatherb_k(const float* __restrict__ kbuf, const float* __restrict__ vbuf,
                          const int* __restrict__ sel, unsigned short* __restrict__ kh,
                          unsigned short* __restrict__ vT) {
  __shared__ unsigned short tile[64][66];
  int t = threadIdx.x, lane = t & 63, wv = t >> 6;
  int bh = blockIdx.y, i0 = blockIdx.x * 64;
  for (int r = 0; r < 16; ++r) {
    int i = r * 4 + wv;
    int src = sel[bh * 1024 + i0 + i];
    float kvv = kbuf[((size_t)bh * 2048 + src) * 64 + lane];
    kh[((size_t)bh * 1024 + i0 + i) * 64 + lane] = f2h_bits(kvv);
    float vv = vbuf[((size_t)bh * 2048 + src) * 64 + lane];
    tile[i][lane] = f2h_bits(vv);
  }
  __syncthreads();
  for (int r = 0; r < 16; ++r) {
    int d = r * 4 + wv;
    vT[((size_t)bh * 64 + d) * 1024 + i0 + lane] = tile[lane][d];
  }
}

// ---------------- MFMA flash attention (f16, K/V LDS-staged, XCD-mapped) -----
__global__ __launch_bounds__(256) void attn_mfma_k(
    const unsigned short* __restrict__ qh, const unsigned short* __restrict__ kh,
    const unsigned short* __restrict__ vT,
    unsigned short* __restrict__ oh, unsigned short* __restrict__ ol) {
  __shared__ __align__(16) unsigned short kvlds[2][2][4096];  // [buf][K/V][64x64]
  __shared__ __align__(16) unsigned short plds[4][16][72];
  int t = threadIdx.x, lane = t & 63, wv = t >> 6;
  int lq = lane & 15, lg = lane >> 4;
  int id = blockIdx.x;
  int bh = (id & 7) * 2 + ((id >> 3) & 1);
  int q0 = (id >> 4) * 64 + wv * 16;
  const unsigned short* qbase = qh + ((size_t)bh * 4096 + q0 + lq) * 64;
  hfx8 qf0 = *(const hfx8*)(qbase + lg * 8);
  hfx8 qf1 = *(const hfx8*)(qbase + 32 + lg * 8);
  fx4 acc[4];
  for (int nt = 0; nt < 4; ++nt) acc[nt] = (fx4){0.f, 0.f, 0.f, 0.f};
  float lsum = 0.f;
  const unsigned short* kbase = kh + (size_t)bh * 1024 * 64;
  const unsigned short* vbase = vT + (size_t)bh * 64 * 1024;

  int srow = t >> 2;
  int scolb = (t & 3) * 32;
  const char* gK = (const char*)kbase + (size_t)srow * 128 + scolb;   // + s*8192
  const char* gV = (const char*)vbase + (size_t)srow * 2048 + scolb;  // + s*128
  int sw_w = (srow & 7) << 4;
  int wb0 = srow * 128 + (scolb ^ sw_w);
  int wb1 = srow * 128 + ((scolb + 16) ^ sw_w);

  {
    uint4 k0 = *(const uint4*)(gK);
    uint4 k1 = *(const uint4*)(gK + 16);
    uint4 v0 = *(const uint4*)(gV);
    uint4 v1 = *(const uint4*)(gV + 16);
    *(uint4*)((char*)&kvlds[0][0][0] + wb0) = k0;
    *(uint4*)((char*)&kvlds[0][0][0] + wb1) = k1;
    *(uint4*)((char*)&kvlds[0][1][0] + wb0) = v0;
    *(uint4*)((char*)&kvlds[0][1][0] + wb1) = v1;
  }

  int swr = (lq & 7) << 4;
  int rc0 = (lg * 16) ^ swr;
  int rc1 = (64 + lg * 16) ^ swr;

  for (int s = 0; s < 16; ++s) {
    int cur = s & 1;
    __syncthreads();
    uint4 nk0, nk1, nv0, nv1;
    if (s < 15) {
      const char* gKn = gK + (size_t)(s + 1) * 8192;
      const char* gVn = gV + (size_t)(s + 1) * 128;
      nk0 = *(const uint4*)(gKn);
      nk1 = *(const uint4*)(gKn + 16);
      nv0 = *(const uint4*)(gVn);
      nv1 = *(const uint4*)(gVn + 16);
    }
    __builtin_amdgcn_sched_barrier(0);
    const char* Kb = (const char*)&kvlds[cur][0][0];
    const char* Vb = (const char*)&kvlds[cur][1][0];
    fx4 sS[4];
#pragma unroll
    for (int mt = 0; mt < 4; ++mt) {
      int rowb = (mt * 16 + lq) * 128;
      hfx8 a0 = *(const hfx8*)(Kb + rowb + rc0);
      hfx8 a1 = *(const hfx8*)(Kb + rowb + rc1);
      fx4 c = (fx4){0.f, 0.f, 0.f, 0.f};
      c = __builtin_amdgcn_mfma_f32_16x16x32_f16(a0, qf0, c, 0, 0, 0);
      c = __builtin_amdgcn_mfma_f32_16x16x32_f16(a1, qf1, c, 0, 0, 0);
      sS[mt] = c;
    }
#pragma unroll
    for (int mt = 0; mt < 4; ++mt) {
      float p0 = __expf(sS[mt].x), p1 = __expf(sS[mt].y);
      float p2 = __expf(sS[mt].z), p3 = __expf(sS[mt].w);
      lsum += (p0 + p1) + (p2 + p3);
      fpx2 c01 = __builtin_amdgcn_cvt_pkrtz(p0, p1);
      fpx2 c23 = __builtin_amdgcn_cvt_pkrtz(p2, p3);
      unsigned u01, u23;
      __builtin_memcpy(&u01, &c01, 4);
      __builtin_memcpy(&u23, &c23, 4);
      uint2 pk = {u01, u23};
      *(uint2*)&plds[wv][lq][mt * 16 + lg * 4] = pk;
    }
    hfx8 pa0 = *(const hfx8*)&plds[wv][lq][lg * 8];
    hfx8 pa1 = *(const hfx8*)&plds[wv][lq][32 + lg * 8];
#pragma unroll
    for (int nt = 0; nt < 4; ++nt) {
      int rowb = (nt * 16 + lq) * 128;
      hfx8 b0 = *(const hfx8*)(Vb + rowb + rc0);
      hfx8 b1 = *(const hfx8*)(Vb + rowb + rc1);
      acc[nt] = __builtin_amdgcn_mfma_f32_16x16x32_f16(pa0, b0, acc[nt], 0, 0, 0);
      acc[nt] = __builtin_amdgcn_mfma_f32_16x16x32_f16(pa1, b1, acc[nt], 0, 0, 0);
    }
    __builtin_amdgcn_sched_barrier(0);
    if (s < 15) {
      char* dK = (char*)&kvlds[cur ^ 1][0][0];
      char* dV = (char*)&kvlds[cur ^ 1][1][0];
      *(uint4*)(dK + wb0) = nk0;
      *(uint4*)(dK + wb1) = nk1;
      *(uint4*)(dV + wb0) = nv0;
      *(uint4*)(dV + wb1) = nv1;
    }
  }
  lsum += __shfl_xor(lsum, 16);
  lsum += __shfl_xor(lsum, 32);
  int bi = bh >> 3, hd = bh & 7;
  for (int r = 0; r < 4; ++r) {
    float inv = 1.f / __shfl(lsum, lg * 4 + r);
    size_t rowb = ((size_t)bi * 4096 + q0 + lg * 4 + r) * 512 + hd * 64;
    for (int nt = 0; nt < 4; ++nt) {
      float val = acc[nt][r] * inv;
      unsigned short hb = f2h_bits(val);
      oh[rowb + nt * 16 + lq] = hb;
      ol[rowb + nt * 16 + lq] = f2h_bits((val - h_bits2f(hb)) * 2048.f);
    }
  }
}

// ---------------- final LN + gamma*ln + residual (wave-split channels) -------
__global__ __launch_bounds__(256) void final_k(
    const float* __restrict__ y, const float* __restrict__ g,
    const float* __restrict__ bta, const float* __restrict__ gamma,
    const float* __restrict__ qs, float* __restrict__ out) {
  __shared__ float p1[4][64], p2[4][64];
  __shared__ float mArr[64], invArr[64];
  int t = threadIdx.x, lane = t & 63, wv = t >> 6;
  int n0 = blockIdx.x * 64, bi = blockIdx.y;
  const float* yb = y + (size_t)bi * CDIM * NQ + n0 + lane;
  float s = 0.f, s2 = 0.f;
  for (int cl = 0; cl < 64; ++cl) {
    float v = yb[(size_t)(wv * 64 + cl) * NQ];
    s += v;
    s2 += v * v;
  }
  p1[wv][lane] = s;
  p2[wv][lane] = s2;
  __syncthreads();
  if (t < 64) {
    float ts = p1[0][t] + p1[1][t] + p1[2][t] + p1[3][t];
    float ts2 = p2[0][t] + p2[1][t] + p2[2][t] + p2[3][t];
    float m = ts / CDIM;
    float var = ts2 / CDIM - m * m;
    mArr[t] = m;
    invArr[t] = 1.f / (sqrtf(fmaxf(var, 0.f)) + 1e-6f);
  }
  __syncthreads();
  float gm = gamma[0];
  float m = mArr[lane], inv = invArr[lane];
  const float* qb = qs + (size_t)bi * CDIM * NQ + n0 + lane;
  float* ob = out + (size_t)bi * CDIM * NQ + n0 + lane;
  for (int cl = 0; cl < 64; ++cl) {
    int c = wv * 64 + cl;
    float v = yb[(size_t)c * NQ];
    float ln = g[c] * (v - m) * inv + bta[c];
    ob[(size_t)c * NQ] = gm * ln + qb[(size_t)c * NQ];
  }
}

extern "C" void kernel_launch(void* const* d_in, const int* in_sizes, int n_in,
                              void* d_out, int out_size, void* d_ws, size_t ws_size,
                              hipStream_t stream) {
  const float* qsrc = (const float*)d_in[0];
  const float* ctx = (const float*)d_in[1];
  const float* w_q = (const float*)d_in[2];
  const float* w_kv = (const float*)d_in[3];
  const float* w_out = (const float*)d_in[4];
  const float* cn_g = (const float*)d_in[5];
  const float* cn_b = (const float*)d_in[6];
  const float* qn_g = (const float*)d_in[7];
  const float* qn_b = (const float*)d_in[8];
  const float* on_g = (const float*)d_in[9];
  const float* on_b = (const float*)d_in[10];
  const float* gamma = (const float*)d_in[11];

  // scratch layout (floats); total 22,267,904 floats = 89.1 MB
  if (ws_size < (size_t)22267904 * 4) return;
  float* ws = (float*)d_ws;
  float* r_ctx = ws;                      // 1,048,576 f: ctx split-f16; later kh/vT
  float* r_kv = r_ctx + 1048576;          // 4,194,304 f: kbh/kbl f16; later attnt split
  float* r_qs = r_kv + 4194304;           // 2,097,152 f: qs split-f16; later cb2h/l, ybuf
  float* r_q3 = r_qs + 2097152;           // 4,194,304 f: qbh/qbl f16
  float* qbuf = r_q3 + 4194304;           // 4,194,304 f
  float* kbuf = qbuf + 4194304;           // 2,097,152 f
  float* vbuf = kbuf + 2097152;           // 2,097,152 f
  float* cent = vbuf + 2097152;           // 65,536 f
  float* csq = cent + 65536;              // 1,024 f
  float* sums = csq + 1024;               // 65,536 f
  float* cnt = sums + 65536;              // 1,024 f
  int* asg = (int*)(cnt + 1024);          // 65,536 i
  float* dist = (float*)(asg + 65536);    // 32,768 f
  int* sel = (int*)(dist + 32768);        // 16,384 i
  float* kgreg = (float*)(sel + 16384);   // 2,097,152 f (qh f16)

  unsigned short* ctxth = (unsigned short*)r_ctx;   // [b][2048][256] f16 hi
  unsigned short* ctxtl = ctxth + (size_t)BB * NK * CDIM;  // lo
  unsigned short* qsth = (unsigned short*)r_qs;     // [b][4096][256] f16 hi
  unsigned short* qstl = qsth + (size_t)BB * NQ * CDIM;    // lo
  unsigned short* qh = (unsigned short*)kgreg;      // 4M f16
  unsigned short* kh = (unsigned short*)r_ctx;      // 1M f16 (ctx split dead)
  unsigned short* vT = kh + 1048576;                // 1M f16
  unsigned short* qbh = (unsigned short*)r_q3;      // 4M f16 (q split hi)
  unsigned short* qbl = qbh + (size_t)NPQ * 64;     // 4M f16 (lo)
  unsigned short* kbh = (unsigned short*)r_kv;      // 2M f16 (k split hi)
  unsigned short* kbl = kbh + (size_t)NPK * 64;     // 2M f16 (lo)
  unsigned short* cb2h = (unsigned short*)r_qs;     // 64K f16 (-2c hi)
  unsigned short* cb2l = cb2h + 65536;              // 64K f16 (lo)
  unsigned short* attnth = (unsigned short*)r_kv;   // [b][4096][512] f16 hi (kb split dead)
  unsigned short* attntl = attnth + (size_t)BB * NQ * 512;  // lo
  float* ybuf = r_qs;                     // [b][256][4096] f32 (cb2 dead)

  // 1. channel LayerNorms -> transposed split-f16
  chan_ln_tsplit_k<<<dim3(NK / 64, BB), 256, 0, stream>>>(ctx, cn_g, cn_b, ctxth, ctxtl, CDIM, NK);
  chan_ln_tsplit_k<<<dim3(NQ / 64, BB), 256, 0, stream>>>(qsrc, qn_g, qn_b, qsth, qstl, CDIM, NQ);
  // 2. fused MFMA projections + fold + L2-norm + format emit (LDS-pipelined)
  gemmfold_k<1><<<dim3(NK / 64, 16, BB), 256, 0, stream>>>(
      w_kv, ctxth, ctxtl, kbuf, kbh, kbl, nullptr, vbuf, CDIM, NK);
  gemmfold_k<0><<<dim3(NQ / 64, 8, BB), 256, 0, stream>>>(
      w_q, qsth, qstl, qbuf, qbh, qbl, qh, nullptr, CDIM, NQ);
  // 3. k-means: initial prep + one memset; centup_prep fuses update/prep/zero
  hipMemcpyAsync(cent, qbuf, 65536 * sizeof(float), hipMemcpyDeviceToDevice, stream);
  centprep_k<<<1024, 64, 0, stream>>>(cent, csq, cb2h, cb2l);
  hipMemsetAsync(sums, 0, (65536 + 1024) * sizeof(float), stream);
  for (int it = 0; it < 4; ++it) {
    assign_mfma_k<1><<<NPQ / 128, 256, 0, stream>>>(qbh, qbl, cb2h, cb2l, csq, asg);
    segsum_k<<<NPQ / 4, 256, 0, stream>>>(qbuf, asg, sums, cnt);
    centup_prep_k<<<65536 / 256, 256, 0, stream>>>(cent, sums, cnt, csq, cb2h, cb2l);
  }
  // 4. score keys: argmin (MFMA) -> exact f32 L1 dist -> per-head top-1024
  assign_mfma_k<0><<<NPK / 64, 256, 0, stream>>>(kbh, kbl, cb2h, cb2l, csq, asg);
  dist_k<<<NPK / 4, 256, 0, stream>>>(kbuf, cent, asg, dist);
  topk_k<<<BH, 1024, 0, stream>>>(dist, sel);
  // 5. gather (kh row-major f16, vT transposed f16)
  gatherb_k<<<dim3(TOPK / 64, BH), 256, 0, stream>>>(kbuf, vbuf, sel, kh, vT);
  // 6. MFMA attention (f16, XCD-mapped) -> split-f16 un-folded [b][n][512]
  attn_mfma_k<<<1024, 256, 0, stream>>>(qh, kh, vT, attnth, attntl);
  // 7. output projection (MFMA)
  gemm_mfma_k<<<dim3(NQ / 64, 256 / 64, BB), 256, 0, stream>>>(w_out, attnth, attntl, ybuf, 256, 512, NQ);
  // 8. final LN + residual
  final_k<<<dim3(NQ / 64, BB), 256, 0, stream>>>(ybuf, on_g, on_b, gamma, qsrc, (float*)d_out);
}

// Round 16
// 514.984 us; speedup vs baseline: 1.9346x; 1.0398x over previous
//
#include <hip/hip_runtime.h>
#include <math.h>

#define BB 2
#define CDIM 256
#define NQ 4096   // 16*16*16
#define NK 2048   // 8*16*16
#define BH 16
#define TOPK 1024
#define NPQ (BH*NQ)   // 65536
#define NPK (BH*NK)   // 32768

typedef __attribute__((ext_vector_type(8))) short bfx8;
typedef __attribute__((ext_vector_type(8))) _Float16 hfx8;
typedef __attribute__((ext_vector_type(2))) __fp16 fpx2;
typedef __attribute__((ext_vector_type(4))) float fx4;
typedef __attribute__((ext_vector_type(4))) unsigned short us4;

__device__ inline unsigned short f2bf(float x) {
  unsigned u = __float_as_uint(x);
  return (unsigned short)((u + 0x7fffu + ((u >> 16) & 1u)) >> 16);
}
__device__ inline unsigned short f2h_bits(float x) {
  _Float16 h = (_Float16)x;
  unsigned short u;
  __builtin_memcpy(&u, &h, 2);
  return u;
}
__device__ inline float h_bits2f(unsigned short u) {
  _Float16 h;
  __builtin_memcpy(&h, &u, 2);
  return (float)h;
}

// ------- channel LayerNorm -> transposed split-f16 [b][n][C] (hi, lo*2048) ---
__global__ __launch_bounds__(256) void chan_ln_tsplit_k(
    const float* __restrict__ x, const float* __restrict__ g,
    const float* __restrict__ bta, unsigned short* __restrict__ yh,
    unsigned short* __restrict__ yl, int C, int N) {
  __shared__ float tile[4][64][65];
  __shared__ float p1[4][64], p2[4][64];
  __shared__ float mArr[64], invArr[64];
  int t = threadIdx.x, lane = t & 63, wv = t >> 6;
  int n0 = blockIdx.x * 64, bi = blockIdx.y;
  const float* xb = x + (size_t)bi * C * N + n0 + lane;
  float s = 0.f, s2 = 0.f;
  for (int cl = 0; cl < 64; ++cl) {
    float v = xb[(size_t)(wv * 64 + cl) * N];
    tile[wv][cl][lane] = v;
    s += v;
    s2 += v * v;
  }
  p1[wv][lane] = s;
  p2[wv][lane] = s2;
  __syncthreads();
  if (t < 64) {
    float ts = p1[0][t] + p1[1][t] + p1[2][t] + p1[3][t];
    float ts2 = p2[0][t] + p2[1][t] + p2[2][t] + p2[3][t];
    float m = ts / C;
    float var = ts2 / C - m * m;
    mArr[t] = m;
    invArr[t] = 1.f / (sqrtf(fmaxf(var, 0.f)) + 1e-6f);
  }
  __syncthreads();
  int c = wv * 64 + lane;  // lane = channel in phase 2
  float gc = g[c], bc = bta[c];
  unsigned short* ohb = yh + ((size_t)bi * N + n0) * C + c;
  unsigned short* olb = yl + ((size_t)bi * N + n0) * C + c;
  for (int pl = 0; pl < 64; ++pl) {
    float v = tile[wv][lane][pl];
    float ln = gc * (v - mArr[pl]) * invArr[pl] + bc;
    unsigned short hb = f2h_bits(ln);
    ohb[(size_t)pl * C] = hb;
    olb[(size_t)pl * C] = f2h_bits((ln - h_bits2f(hb)) * 2048.f);
  }
}

// ------- MFMA GEMM (w_out), LDS-staged X pipeline: Y[b][o][n] ----------------
// Same staging/prefetch structure as gemmfold_k; MFMA sequence bit-exact vs R15.
__global__ __launch_bounds__(256) void gemm_mfma_k(
    const float* __restrict__ W, const unsigned short* __restrict__ Xh,
    const unsigned short* __restrict__ Xl, float* __restrict__ Y,
    int O, int C, int N) {
  __shared__ __align__(16) unsigned short xlds[2][64][64];  // [buf][row][hi32|lo32]
  int t = threadIdx.x, lane = t & 63, wv = t >> 6;
  int lq = lane & 15, lg = lane >> 4;
  int n0 = blockIdx.x * 64, o0 = blockIdx.y * 64 + wv * 16;
  int b = blockIdx.z;
  const unsigned short* xbh = Xh + ((size_t)b * N + n0) * C;
  const unsigned short* xbl = Xl + ((size_t)b * N + n0) * C;
  const float* wr = W + (size_t)(o0 + lq) * C;

  int a = t * 16;
  int srow = a >> 6;
  int schunk = (a >> 4) & 3;
  const unsigned short* gsh = xbh + (size_t)srow * C + schunk * 8;
  const unsigned short* gsl = xbl + (size_t)srow * C + schunk * 8;
  int swz = (srow & 7) << 4;
  int wbh = srow * 128 + ((schunk * 16) ^ swz);
  int wbl = srow * 128 + ((64 + schunk * 16) ^ swz);
  int rswz = (lq & 7) << 4;
  int xh0 = (lg * 16) ^ rswz;
  int xl0 = (64 + lg * 16) ^ rswz;

  fx4 ahi[4], alo[4];
  for (int nt = 0; nt < 4; ++nt) {
    ahi[nt] = (fx4){0.f, 0.f, 0.f, 0.f};
    alo[nt] = (fx4){0.f, 0.f, 0.f, 0.f};
  }

  {
    uint4 h0 = *(const uint4*)(gsh);
    uint4 l0 = *(const uint4*)(gsl);
    *(uint4*)((char*)&xlds[0][0][0] + wbh) = h0;
    *(uint4*)((char*)&xlds[0][0][0] + wbl) = l0;
  }
  float4 w0c = *(const float4*)(wr + lg * 8);
  float4 w1c = *(const float4*)(wr + lg * 8 + 4);

  int nsteps = C / 32;
  for (int s = 0; s < nsteps; ++s) {
    int cur = s & 1;
    __syncthreads();
    uint4 nh, nl;
    float4 nw0, nw1;
    if (s < nsteps - 1) {
      nh = *(const uint4*)(gsh + (s + 1) * 32);
      nl = *(const uint4*)(gsl + (s + 1) * 32);
      nw0 = *(const float4*)(wr + (s + 1) * 32 + lg * 8);
      nw1 = *(const float4*)(wr + (s + 1) * 32 + lg * 8 + 4);
    }
    __builtin_amdgcn_sched_barrier(0);
    float wv8[8] = {w0c.x, w0c.y, w0c.z, w0c.w, w1c.x, w1c.y, w1c.z, w1c.w};
    hfx8 ah, al;
#pragma unroll
    for (int i = 0; i < 8; ++i) {
      _Float16 hh = (_Float16)wv8[i];
      ah[i] = hh;
      al[i] = (_Float16)((wv8[i] - (float)hh) * 2048.f);
    }
    const char* Xb = (const char*)&xlds[cur][0][0];
#pragma unroll
    for (int nt = 0; nt < 4; ++nt) {
      int rb = (nt * 16 + lq) * 128;
      hfx8 bh = *(const hfx8*)(Xb + rb + xh0);
      hfx8 bl = *(const hfx8*)(Xb + rb + xl0);
      ahi[nt] = __builtin_amdgcn_mfma_f32_16x16x32_f16(ah, bh, ahi[nt], 0, 0, 0);
      alo[nt] = __builtin_amdgcn_mfma_f32_16x16x32_f16(al, bh, alo[nt], 0, 0, 0);
      alo[nt] = __builtin_amdgcn_mfma_f32_16x16x32_f16(ah, bl, alo[nt], 0, 0, 0);
    }
    __builtin_amdgcn_sched_barrier(0);
    if (s < nsteps - 1) {
      *(uint4*)((char*)&xlds[cur ^ 1][0][0] + wbh) = nh;
      *(uint4*)((char*)&xlds[cur ^ 1][0][0] + wbl) = nl;
      w0c = nw0;
      w1c = nw1;
    }
  }
  float* yb = Y + ((size_t)b * O + o0) * N + n0;
#pragma unroll
  for (int nt = 0; nt < 4; ++nt)
#pragma unroll
    for (int r = 0; r < 4; ++r)
      yb[(size_t)(lg * 4 + r) * N + nt * 16 + lq] = ahi[nt][r] + alo[nt][r] * (1.f / 2048.f);
}

// ------- fused GEMM + head-fold + L2-norm + multi-format emit ---------------
template <int PATH>
__global__ __launch_bounds__(256) void gemmfold_k(
    const float* __restrict__ W, const unsigned short* __restrict__ Xh,
    const unsigned short* __restrict__ Xl, float* __restrict__ fq,
    unsigned short* __restrict__ sh, unsigned short* __restrict__ sl,
    unsigned short* __restrict__ b16, float* __restrict__ fv,
    int C, int N) {
  __shared__ __align__(16) unsigned short xlds[2][64][64];  // [buf][row][hi32|lo32]
  __shared__ float ftile[64][65];
  __shared__ float part[4][64];
  __shared__ float invArr[64];
  int t = threadIdx.x, lane = t & 63, wv = t >> 6;
  int lq = lane & 15, lg = lane >> 4;
  int n0 = blockIdx.x * 64, o0 = blockIdx.y * 64 + wv * 16;
  int b = blockIdx.z;
  bool isV = (PATH == 1) && (blockIdx.y >= 8);
  int h = (PATH == 1) ? (blockIdx.y & 7) : blockIdx.y;
  const unsigned short* xbh = Xh + ((size_t)b * N + n0) * C;
  const unsigned short* xbl = Xl + ((size_t)b * N + n0) * C;
  const float* wr = W + (size_t)(o0 + lq) * C;

  int a = t * 16;
  int srow = a >> 6;
  int schunk = (a >> 4) & 3;
  const unsigned short* gsh = xbh + (size_t)srow * C + schunk * 8;
  const unsigned short* gsl = xbl + (size_t)srow * C + schunk * 8;
  int swz = (srow & 7) << 4;
  int wbh = srow * 128 + ((schunk * 16) ^ swz);
  int wbl = srow * 128 + ((64 + schunk * 16) ^ swz);
  int rswz = (lq & 7) << 4;
  int xh0 = (lg * 16) ^ rswz;
  int xl0 = (64 + lg * 16) ^ rswz;

  fx4 ahi[4], alo[4];
  for (int nt = 0; nt < 4; ++nt) {
    ahi[nt] = (fx4){0.f, 0.f, 0.f, 0.f};
    alo[nt] = (fx4){0.f, 0.f, 0.f, 0.f};
  }

  {
    uint4 h0 = *(const uint4*)(gsh);
    uint4 l0 = *(const uint4*)(gsl);
    *(uint4*)((char*)&xlds[0][0][0] + wbh) = h0;
    *(uint4*)((char*)&xlds[0][0][0] + wbl) = l0;
  }
  float4 w0c = *(const float4*)(wr + lg * 8);
  float4 w1c = *(const float4*)(wr + lg * 8 + 4);

  for (int s = 0; s < 8; ++s) {
    int cur = s & 1;
    __syncthreads();
    uint4 nh, nl;
    float4 nw0, nw1;
    if (s < 7) {
      nh = *(const uint4*)(gsh + (s + 1) * 32);
      nl = *(const uint4*)(gsl + (s + 1) * 32);
      nw0 = *(const float4*)(wr + (s + 1) * 32 + lg * 8);
      nw1 = *(const float4*)(wr + (s + 1) * 32 + lg * 8 + 4);
    }
    __builtin_amdgcn_sched_barrier(0);
    float wv8[8] = {w0c.x, w0c.y, w0c.z, w0c.w, w1c.x, w1c.y, w1c.z, w1c.w};
    hfx8 ah, al;
#pragma unroll
    for (int i = 0; i < 8; ++i) {
      _Float16 hh = (_Float16)wv8[i];
      ah[i] = hh;
      al[i] = (_Float16)((wv8[i] - (float)hh) * 2048.f);
    }
    const char* Xb = (const char*)&xlds[cur][0][0];
#pragma unroll
    for (int nt = 0; nt < 4; ++nt) {
      int rb = (nt * 16 + lq) * 128;
      hfx8 bh = *(const hfx8*)(Xb + rb + xh0);
      hfx8 bl = *(const hfx8*)(Xb + rb + xl0);
      ahi[nt] = __builtin_amdgcn_mfma_f32_16x16x32_f16(ah, bh, ahi[nt], 0, 0, 0);
      alo[nt] = __builtin_amdgcn_mfma_f32_16x16x32_f16(al, bh, alo[nt], 0, 0, 0);
      alo[nt] = __builtin_amdgcn_mfma_f32_16x16x32_f16(ah, bl, alo[nt], 0, 0, 0);
    }
    __builtin_amdgcn_sched_barrier(0);
    if (s < 7) {
      *(uint4*)((char*)&xlds[cur ^ 1][0][0] + wbh) = nh;
      *(uint4*)((char*)&xlds[cur ^ 1][0][0] + wbl) = nl;
      w0c = nw0;
      w1c = nw1;
    }
  }

  float val[4][4];
#pragma unroll
  for (int nt = 0; nt < 4; ++nt)
#pragma unroll
    for (int r = 0; r < 4; ++r)
      val[nt][r] = ahi[nt][r] + alo[nt][r] * (1.f / 2048.f);
  __syncthreads();
  if (!isV) {
#pragma unroll
    for (int nt = 0; nt < 4; ++nt) {
      float ss = val[nt][0] * val[nt][0] + val[nt][1] * val[nt][1] +
                 val[nt][2] * val[nt][2] + val[nt][3] * val[nt][3];
      ss += __shfl_xor(ss, 16);
      ss += __shfl_xor(ss, 32);
      if (lg == 0) part[wv][nt * 16 + lq] = ss;
    }
    __syncthreads();
    if (t < 64) {
      float tot = part[0][t] + part[1][t] + part[2][t] + part[3][t];
      invArr[t] = 1.f / fmaxf(sqrtf(tot), 1e-12f);
    }
    __syncthreads();
#pragma unroll
    for (int nt = 0; nt < 4; ++nt) {
      float iv = invArr[nt * 16 + lq];
#pragma unroll
      for (int r = 0; r < 4; ++r) val[nt][r] *= iv;
    }
    __syncthreads();
  }
#pragma unroll
  for (int nt = 0; nt < 4; ++nt)
#pragma unroll
    for (int r = 0; r < 4; ++r)
      ftile[nt * 16 + lq][wv * 16 + lg * 4 + r] = val[nt][r];
  __syncthreads();
  size_t rowb = (size_t)(b * 8 + h) * N + n0;
  for (int r2 = 0; r2 < 16; ++r2) {
    int n = r2 * 4 + wv;
    float v = ftile[n][lane];
    size_t idx = (rowb + n) * 64 + lane;
    if (PATH == 1 && isV) {
      fv[idx] = v;
    } else {
      fq[idx] = v;
      unsigned short hb = f2h_bits(v);
      sh[idx] = hb;
      sl[idx] = f2h_bits((v - h_bits2f(hb)) * 2048.f);
      if (PATH == 0) b16[idx] = hb;  // f16 copy for attention
    }
  }
}

// ---------------- centroid prep (initial only): csq, -2c split f16 -----------
__global__ void centprep_k(const float* __restrict__ cent, float* __restrict__ csq,
                           unsigned short* __restrict__ cb2h, unsigned short* __restrict__ cb2l) {
  int j = blockIdx.x, lane = threadIdx.x;  // blockDim = 64
  float c = cent[j * 64 + lane];
  float s = c * c;
  for (int off = 32; off; off >>= 1) s += __shfl_xor(s, off);
  if (lane == 0) csq[j] = s;
  float m2 = -2.f * c;
  unsigned short h = f2h_bits(m2);
  cb2h[j * 64 + lane] = h;
  cb2l[j * 64 + lane] = f2h_bits((m2 - h_bits2f(h)) * 2048.f);
}

// ---------------- MFMA nearest-centroid assign (f16 split, LDS-staged) -------
template <int DUO>
__global__ __launch_bounds__(256) void assign_mfma_k(
    const unsigned short* __restrict__ xh, const unsigned short* __restrict__ xl,
    const unsigned short* __restrict__ cb2h, const unsigned short* __restrict__ cb2l,
    const float* __restrict__ csq, int* __restrict__ aout) {
  __shared__ __align__(16) unsigned short clds[2][2][1024];  // [buf][hi/lo][16x64]
  int t = threadIdx.x, lane = t & 63, wv = t >> 6;
  int lq = lane & 15, lg = lane >> 4;
  int p0 = blockIdx.x * (DUO ? 128 : 64) + wv * (DUO ? 32 : 16);
  const unsigned short* xbA = xh + (size_t)(p0 + lq) * 64;
  const unsigned short* xlA = xl + (size_t)(p0 + lq) * 64;
  hfx8 ba0 = *(const hfx8*)(xbA + lg * 8);
  hfx8 ba1 = *(const hfx8*)(xbA + 32 + lg * 8);
  hfx8 la0 = *(const hfx8*)(xlA + lg * 8);
  hfx8 la1 = *(const hfx8*)(xlA + 32 + lg * 8);
  hfx8 bb0, bb1, lb0, lb1;
  if (DUO) {
    const unsigned short* xbB = xh + (size_t)(p0 + 16 + lq) * 64;
    const unsigned short* xlB = xl + (size_t)(p0 + 16 + lq) * 64;
    bb0 = *(const hfx8*)(xbB + lg * 8);
    bb1 = *(const hfx8*)(xbB + 32 + lg * 8);
    lb0 = *(const hfx8*)(xlB + lg * 8);
    lb1 = *(const hfx8*)(xlB + 32 + lg * 8);
  }

  int part = t >> 7;
  int abyte = (t & 127) * 16;
  int wbyte = abyte ^ (((abyte >> 7) & 7) << 4);
  const unsigned short* gsrc = (part ? cb2l : cb2h) + (abyte >> 1);
  int rowoff = lq * 128;
  int x0 = (lg * 16) ^ ((lq & 7) << 4);
  int x1 = (64 + lg * 16) ^ ((lq & 7) << 4);

  float bestA = 3.4e38f, bestB = 3.4e38f;
  int jA = 0, jB = 0;

  uint4 r0 = *(const uint4*)(gsrc);
  *(uint4*)((char*)&clds[0][part][0] + wbyte) = r0;

  for (int s = 0; s < 64; ++s) {
    int cur = s & 1;
    __syncthreads();
    uint4 rn;
    if (s < 63) rn = *(const uint4*)(gsrc + (size_t)(s + 1) * 1024);
    __builtin_amdgcn_sched_barrier(0);
    const char* ph = (const char*)&clds[cur][0][0];
    const char* pl = (const char*)&clds[cur][1][0];
    hfx8 ah0 = *(const hfx8*)(ph + rowoff + x0);
    hfx8 ah1 = *(const hfx8*)(ph + rowoff + x1);
    hfx8 al0 = *(const hfx8*)(pl + rowoff + x0);
    hfx8 al1 = *(const hfx8*)(pl + rowoff + x1);
    fx4 cq = *(const fx4*)(csq + s * 16 + lg * 4);
    {
      fx4 chi = cq;
      chi = __builtin_amdgcn_mfma_f32_16x16x32_f16(ah0, ba0, chi, 0, 0, 0);
      chi = __builtin_amdgcn_mfma_f32_16x16x32_f16(ah1, ba1, chi, 0, 0, 0);
      fx4 clo = (fx4){0.f, 0.f, 0.f, 0.f};
      clo = __builtin_amdgcn_mfma_f32_16x16x32_f16(ah0, la0, clo, 0, 0, 0);
      clo = __builtin_amdgcn_mfma_f32_16x16x32_f16(ah1, la1, clo, 0, 0, 0);
      clo = __builtin_amdgcn_mfma_f32_16x16x32_f16(al0, ba0, clo, 0, 0, 0);
      clo = __builtin_amdgcn_mfma_f32_16x16x32_f16(al1, ba1, clo, 0, 0, 0);
#pragma unroll
      for (int r_ = 0; r_ < 4; ++r_) {
        int j_ = s * 16 + lg * 4 + r_;
        float d2_ = chi[r_] + clo[r_] * (1.f / 2048.f);
        if (d2_ < bestA) { bestA = d2_; jA = j_; }
      }
    }
    if (DUO) {
      fx4 chi = cq;
      chi = __builtin_amdgcn_mfma_f32_16x16x32_f16(ah0, bb0, chi, 0, 0, 0);
      chi = __builtin_amdgcn_mfma_f32_16x16x32_f16(ah1, bb1, chi, 0, 0, 0);
      fx4 clo = (fx4){0.f, 0.f, 0.f, 0.f};
      clo = __builtin_amdgcn_mfma_f32_16x16x32_f16(ah0, lb0, clo, 0, 0, 0);
      clo = __builtin_amdgcn_mfma_f32_16x16x32_f16(ah1, lb1, clo, 0, 0, 0);
      clo = __builtin_amdgcn_mfma_f32_16x16x32_f16(al0, bb0, clo, 0, 0, 0);
      clo = __builtin_amdgcn_mfma_f32_16x16x32_f16(al1, bb1, clo, 0, 0, 0);
#pragma unroll
      for (int r_ = 0; r_ < 4; ++r_) {
        int j_ = s * 16 + lg * 4 + r_;
        float d2_ = chi[r_] + clo[r_] * (1.f / 2048.f);
        if (d2_ < bestB) { bestB = d2_; jB = j_; }
      }
    }
    __builtin_amdgcn_sched_barrier(0);
    if (s < 63) *(uint4*)((char*)&clds[cur ^ 1][part][0] + wbyte) = rn;
  }

  {
    float o = __shfl_xor(bestA, 16);
    int oj = __shfl_xor(jA, 16);
    if (o < bestA || (o == bestA && oj < jA)) { bestA = o; jA = oj; }
    o = __shfl_xor(bestA, 32);
    oj = __shfl_xor(jA, 32);
    if (o < bestA || (o == bestA && oj < jA)) { bestA = o; jA = oj; }
  }
  if (DUO) {
    float o = __shfl_xor(bestB, 16);
    int oj = __shfl_xor(jB, 16);
    if (o < bestB || (o == bestB && oj < jB)) { bestB = o; jB = oj; }
    o = __shfl_xor(bestB, 32);
    oj = __shfl_xor(jB, 32);
    if (o < bestB || (o == bestB && oj < jB)) { bestB = o; jB = oj; }
  }
  if (lg == 0) {
    aout[p0 + lq] = jA;
    if (DUO) aout[p0 + 16 + lq] = jB;
  }
}

// ---------------- exact f32 L1 distance to assigned centroid -----------------
__global__ void dist_k(const float* __restrict__ x, const float* __restrict__ cent,
                       const int* __restrict__ asg, float* __restrict__ dout) {
  int t = threadIdx.x, lane = t & 63, wv = t >> 6;
  int p = blockIdx.x * 4 + wv;
  int a = asg[p];
  float v = fabsf(cent[(size_t)a * 64 + lane] - x[(size_t)p * 64 + lane]);
  for (int off = 32; off; off >>= 1) v += __shfl_xor(v, off);
  if (lane == 0) dout[p] = v;
}

// ---------------- segment sum via atomics (wave=point: coalesced) ------------
__global__ void segsum_k(const float* __restrict__ x, const int* __restrict__ asg,
                         float* __restrict__ sums, float* __restrict__ cnt) {
  int t = threadIdx.x, lane = t & 63, wv = t >> 6;
  int p = blockIdx.x * 4 + wv;
  int a = asg[p];
  float v = x[(size_t)p * 64 + lane];
  atomicAdd(&sums[a * 64 + lane], v);
  if (lane == 0) atomicAdd(&cnt[a], 1.0f);
}

// ---------------- centroid update + prep + zero (fused) ----------------------
__global__ __launch_bounds__(256) void centup_prep_k(
    float* __restrict__ cent, float* __restrict__ sums, float* __restrict__ cnt,
    float* __restrict__ csq, unsigned short* __restrict__ cb2h,
    unsigned short* __restrict__ cb2l) {
  int i = blockIdx.x * 256 + threadIdx.x;  // 65536 total; rows never span blocks
  int j = i >> 6, lane = threadIdx.x & 63;
  float c = cnt[j];
  float oldc = cent[i];
  float newc = (c > 0.f) ? sums[i] / fmaxf(c, 1.f) : oldc;
  cent[i] = newc;
  float s = newc * newc;
  for (int off = 32; off; off >>= 1) s += __shfl_xor(s, off);
  if (lane == 0) csq[j] = s;
  float m2 = -2.f * newc;
  unsigned short h = f2h_bits(m2);
  cb2h[i] = h;
  cb2l[i] = f2h_bits((m2 - h_bits2f(h)) * 2048.f);
  sums[i] = 0.f;
  if (lane == 0) cnt[j] = 0.f;
}

// ---------------- per-bh top-1024 by descending dist (stable ties) -----------
__global__ __launch_bounds__(1024) void topk_k(const float* __restrict__ dist,
                                               int* __restrict__ sel) {
  __shared__ unsigned long long keys[2048];
  int bh = blockIdx.x, t = threadIdx.x;
  for (int i = t; i < 2048; i += 1024) {
    float d = dist[bh * 2048 + i];
    unsigned int db = __float_as_uint(d);  // d >= 0 -> monotonic
    keys[i] = ((unsigned long long)db << 32) | (unsigned int)(2047 - i);
  }
  __syncthreads();
  for (int k = 2; k <= 2048; k <<= 1) {
    for (int j = k >> 1; j > 0; j >>= 1) {
      for (int i = t; i < 2048; i += 1024) {
        int ixj = i ^ j;
        if (ixj > i) {
          unsigned long long a = keys[i], b = keys[ixj];
          bool up = ((i & k) == 0);
          bool sw = up ? (a < b) : (a > b);  // descending overall
          if (sw) { keys[i] = b; keys[ixj] = a; }
        }
      }
      __syncthreads();
    }
  }
  if (t < 1024) sel[bh * 1024 + t] = 2047 - (int)(keys[t] & 0xffffffffu);
}

// ---------------- gather selected rows -> kh (f16 row-major), vT (f16 d-major)
__global__ void gatherb_k(const float* __restrict__ kbuf, const float* __restrict__ vbuf,
                          const int* __restrict__ sel, unsigned short* __restrict__ kh,
                          unsigned short* __restrict__ vT) {
  __shared__ unsigned short tile[64][66];
  int t = threadIdx.x, lane = t & 63, wv = t >> 6;
  int bh = blockIdx.y, i0 = blockIdx.x * 64;
  for (int r = 0; r < 16; ++r) {
    int i = r * 4 + wv;
    int src = sel[bh * 1024 + i0 + i];
    float kvv = kbuf[((size_t)bh * 2048 + src) * 64 + lane];
    kh[((size_t)bh * 1024 + i0 + i) * 64 + lane] = f2h_bits(kvv);
    float vv = vbuf[((size_t)bh * 2048 + src) * 64 + lane];
    tile[i][lane] = f2h_bits(vv);
  }
  __syncthreads();
  for (int r = 0; r < 16; ++r) {
    int d = r * 4 + wv;
    vT[((size_t)bh * 64 + d) * 1024 + i0 + lane] = tile[lane][d];
  }
}

// ---------------- MFMA flash attention (f16, K/V LDS-staged, XCD-mapped) -----
__global__ __launch_bounds__(256) void attn_mfma_k(
    const unsigned short* __restrict__ qh, const unsigned short* __restrict__ kh,
    const unsigned short* __restrict__ vT,
    unsigned short* __restrict__ oh, unsigned short* __restrict__ ol) {
  __shared__ __align__(16) unsigned short kvlds[2][2][4096];  // [buf][K/V][64x64]
  __shared__ __align__(16) unsigned short plds[4][16][72];
  int t = threadIdx.x, lane = t & 63, wv = t >> 6;
  int lq = lane & 15, lg = lane >> 4;
  int id = blockIdx.x;
  int bh = (id & 7) * 2 + ((id >> 3) & 1);
  int q0 = (id >> 4) * 64 + wv * 16;
  const unsigned short* qbase = qh + ((size_t)bh * 4096 + q0 + lq) * 64;
  hfx8 qf0 = *(const hfx8*)(qbase + lg * 8);
  hfx8 qf1 = *(const hfx8*)(qbase + 32 + lg * 8);
  fx4 acc[4];
  for (int nt = 0; nt < 4; ++nt) acc[nt] = (fx4){0.f, 0.f, 0.f, 0.f};
  float lsum = 0.f;
  const unsigned short* kbase = kh + (size_t)bh * 1024 * 64;
  const unsigned short* vbase = vT + (size_t)bh * 64 * 1024;

  int srow = t >> 2;
  int scolb = (t & 3) * 32;
  const char* gK = (const char*)kbase + (size_t)srow * 128 + scolb;   // + s*8192
  const char* gV = (const char*)vbase + (size_t)srow * 2048 + scolb;  // + s*128
  int sw_w = (srow & 7) << 4;
  int wb0 = srow * 128 + (scolb ^ sw_w);
  int wb1 = srow * 128 + ((scolb + 16) ^ sw_w);

  {
    uint4 k0 = *(const uint4*)(gK);
    uint4 k1 = *(const uint4*)(gK + 16);
    uint4 v0 = *(const uint4*)(gV);
    uint4 v1 = *(const uint4*)(gV + 16);
    *(uint4*)((char*)&kvlds[0][0][0] + wb0) = k0;
    *(uint4*)((char*)&kvlds[0][0][0] + wb1) = k1;
    *(uint4*)((char*)&kvlds[0][1][0] + wb0) = v0;
    *(uint4*)((char*)&kvlds[0][1][0] + wb1) = v1;
  }

  int swr = (lq & 7) << 4;
  int rc0 = (lg * 16) ^ swr;
  int rc1 = (64 + lg * 16) ^ swr;

  for (int s = 0; s < 16; ++s) {
    int cur = s & 1;
    __syncthreads();
    uint4 nk0, nk1, nv0, nv1;
    if (s < 15) {
      const char* gKn = gK + (size_t)(s + 1) * 8192;
      const char* gVn = gV + (size_t)(s + 1) * 128;
      nk0 = *(const uint4*)(gKn);
      nk1 = *(const uint4*)(gKn + 16);
      nv0 = *(const uint4*)(gVn);
      nv1 = *(const uint4*)(gVn + 16);
    }
    __builtin_amdgcn_sched_barrier(0);
    const char* Kb = (const char*)&kvlds[cur][0][0];
    const char* Vb = (const char*)&kvlds[cur][1][0];
    fx4 sS[4];
#pragma unroll
    for (int mt = 0; mt < 4; ++mt) {
      int rowb = (mt * 16 + lq) * 128;
      hfx8 a0 = *(const hfx8*)(Kb + rowb + rc0);
      hfx8 a1 = *(const hfx8*)(Kb + rowb + rc1);
      fx4 c = (fx4){0.f, 0.f, 0.f, 0.f};
      c = __builtin_amdgcn_mfma_f32_16x16x32_f16(a0, qf0, c, 0, 0, 0);
      c = __builtin_amdgcn_mfma_f32_16x16x32_f16(a1, qf1, c, 0, 0, 0);
      sS[mt] = c;
    }
#pragma unroll
    for (int mt = 0; mt < 4; ++mt) {
      float p0 = __expf(sS[mt].x), p1 = __expf(sS[mt].y);
      float p2 = __expf(sS[mt].z), p3 = __expf(sS[mt].w);
      lsum += (p0 + p1) + (p2 + p3);
      fpx2 c01 = __builtin_amdgcn_cvt_pkrtz(p0, p1);
      fpx2 c23 = __builtin_amdgcn_cvt_pkrtz(p2, p3);
      unsigned u01, u23;
      __builtin_memcpy(&u01, &c01, 4);
      __builtin_memcpy(&u23, &c23, 4);
      uint2 pk = {u01, u23};
      *(uint2*)&plds[wv][lq][mt * 16 + lg * 4] = pk;
    }
    hfx8 pa0 = *(const hfx8*)&plds[wv][lq][lg * 8];
    hfx8 pa1 = *(const hfx8*)&plds[wv][lq][32 + lg * 8];
#pragma unroll
    for (int nt = 0; nt < 4; ++nt) {
      int rowb = (nt * 16 + lq) * 128;
      hfx8 b0 = *(const hfx8*)(Vb + rowb + rc0);
      hfx8 b1 = *(const hfx8*)(Vb + rowb + rc1);
      acc[nt] = __builtin_amdgcn_mfma_f32_16x16x32_f16(pa0, b0, acc[nt], 0, 0, 0);
      acc[nt] = __builtin_amdgcn_mfma_f32_16x16x32_f16(pa1, b1, acc[nt], 0, 0, 0);
    }
    __builtin_amdgcn_sched_barrier(0);
    if (s < 15) {
      char* dK = (char*)&kvlds[cur ^ 1][0][0];
      char* dV = (char*)&kvlds[cur ^ 1][1][0];
      *(uint4*)(dK + wb0) = nk0;
      *(uint4*)(dK + wb1) = nk1;
      *(uint4*)(dV + wb0) = nv0;
      *(uint4*)(dV + wb1) = nv1;
    }
  }
  lsum += __shfl_xor(lsum, 16);
  lsum += __shfl_xor(lsum, 32);
  int bi = bh >> 3, hd = bh & 7;
  for (int r = 0; r < 4; ++r) {
    float inv = 1.f / __shfl(lsum, lg * 4 + r);
    size_t rowb = ((size_t)bi * 4096 + q0 + lg * 4 + r) * 512 + hd * 64;
    for (int nt = 0; nt < 4; ++nt) {
      float val = acc[nt][r] * inv;
      unsigned short hb = f2h_bits(val);
      oh[rowb + nt * 16 + lq] = hb;
      ol[rowb + nt * 16 + lq] = f2h_bits((val - h_bits2f(hb)) * 2048.f);
    }
  }
}

// ---------------- final LN + gamma*ln + residual (wave-split channels) -------
__global__ __launch_bounds__(256) void final_k(
    const float* __restrict__ y, const float* __restrict__ g,
    const float* __restrict__ bta, const float* __restrict__ gamma,
    const float* __restrict__ qs, float* __restrict__ out) {
  __shared__ float p1[4][64], p2[4][64];
  __shared__ float mArr[64], invArr[64];
  int t = threadIdx.x, lane = t & 63, wv = t >> 6;
  int n0 = blockIdx.x * 64, bi = blockIdx.y;
  const float* yb = y + (size_t)bi * CDIM * NQ + n0 + lane;
  float s = 0.f, s2 = 0.f;
  for (int cl = 0; cl < 64; ++cl) {
    float v = yb[(size_t)(wv * 64 + cl) * NQ];
    s += v;
    s2 += v * v;
  }
  p1[wv][lane] = s;
  p2[wv][lane] = s2;
  __syncthreads();
  if (t < 64) {
    float ts = p1[0][t] + p1[1][t] + p1[2][t] + p1[3][t];
    float ts2 = p2[0][t] + p2[1][t] + p2[2][t] + p2[3][t];
    float m = ts / CDIM;
    float var = ts2 / CDIM - m * m;
    mArr[t] = m;
    invArr[t] = 1.f / (sqrtf(fmaxf(var, 0.f)) + 1e-6f);
  }
  __syncthreads();
  float gm = gamma[0];
  float m = mArr[lane], inv = invArr[lane];
  const float* qb = qs + (size_t)bi * CDIM * NQ + n0 + lane;
  float* ob = out + (size_t)bi * CDIM * NQ + n0 + lane;
  for (int cl = 0; cl < 64; ++cl) {
    int c = wv * 64 + cl;
    float v = yb[(size_t)c * NQ];
    float ln = g[c] * (v - m) * inv + bta[c];
    ob[(size_t)c * NQ] = gm * ln + qb[(size_t)c * NQ];
  }
}

extern "C" void kernel_launch(void* const* d_in, const int* in_sizes, int n_in,
                              void* d_out, int out_size, void* d_ws, size_t ws_size,
                              hipStream_t stream) {
  const float* qsrc = (const float*)d_in[0];
  const float* ctx = (const float*)d_in[1];
  const float* w_q = (const float*)d_in[2];
  const float* w_kv = (const float*)d_in[3];
  const float* w_out = (const float*)d_in[4];
  const float* cn_g = (const float*)d_in[5];
  const float* cn_b = (const float*)d_in[6];
  const float* qn_g = (const float*)d_in[7];
  const float* qn_b = (const float*)d_in[8];
  const float* on_g = (const float*)d_in[9];
  const float* on_b = (const float*)d_in[10];
  const float* gamma = (const float*)d_in[11];

  // scratch layout (floats); total 22,267,904 floats = 89.1 MB
  if (ws_size < (size_t)22267904 * 4) return;
  float* ws = (float*)d_ws;
  float* r_ctx = ws;                      // 1,048,576 f: ctx split-f16; later kh/vT
  float* r_kv = r_ctx + 1048576;          // 4,194,304 f: kbh/kbl f16; later attnt split
  float* r_qs = r_kv + 4194304;           // 2,097,152 f: qs split-f16; later cb2h/l, ybuf
  float* r_q3 = r_qs + 2097152;           // 4,194,304 f: qbh/qbl f16
  float* qbuf = r_q3 + 4194304;           // 4,194,304 f
  float* kbuf = qbuf + 4194304;           // 2,097,152 f
  float* vbuf = kbuf + 2097152;           // 2,097,152 f
  float* cent = vbuf + 2097152;           // 65,536 f
  float* csq = cent + 65536;              // 1,024 f
  float* sums = csq + 1024;               // 65,536 f
  float* cnt = sums + 65536;              // 1,024 f
  int* asg = (int*)(cnt + 1024);          // 65,536 i
  float* dist = (float*)(asg + 65536);    // 32,768 f
  int* sel = (int*)(dist + 32768);        // 16,384 i
  float* kgreg = (float*)(sel + 16384);   // 2,097,152 f (qh f16)

  unsigned short* ctxth = (unsigned short*)r_ctx;   // [b][2048][256] f16 hi
  unsigned short* ctxtl = ctxth + (size_t)BB * NK * CDIM;  // lo
  unsigned short* qsth = (unsigned short*)r_qs;     // [b][4096][256] f16 hi
  unsigned short* qstl = qsth + (size_t)BB * NQ * CDIM;    // lo
  unsigned short* qh = (unsigned short*)kgreg;      // 4M f16
  unsigned short* kh = (unsigned short*)r_ctx;      // 1M f16 (ctx split dead)
  unsigned short* vT = kh + 1048576;                // 1M f16
  unsigned short* qbh = (unsigned short*)r_q3;      // 4M f16 (q split hi)
  unsigned short* qbl = qbh + (size_t)NPQ * 64;     // 4M f16 (lo)
  unsigned short* kbh = (unsigned short*)r_kv;      // 2M f16 (k split hi)
  unsigned short* kbl = kbh + (size_t)NPK * 64;     // 2M f16 (lo)
  unsigned short* cb2h = (unsigned short*)r_qs;     // 64K f16 (-2c hi)
  unsigned short* cb2l = cb2h + 65536;              // 64K f16 (lo)
  unsigned short* attnth = (unsigned short*)r_kv;   // [b][4096][512] f16 hi (kb split dead)
  unsigned short* attntl = attnth + (size_t)BB * NQ * 512;  // lo
  float* ybuf = r_qs;                     // [b][256][4096] f32 (cb2 dead)

  // 1. channel LayerNorms -> transposed split-f16
  chan_ln_tsplit_k<<<dim3(NK / 64, BB), 256, 0, stream>>>(ctx, cn_g, cn_b, ctxth, ctxtl, CDIM, NK);
  chan_ln_tsplit_k<<<dim3(NQ / 64, BB), 256, 0, stream>>>(qsrc, qn_g, qn_b, qsth, qstl, CDIM, NQ);
  // 2. fused MFMA projections + fold + L2-norm + format emit (LDS-pipelined)
  gemmfold_k<1><<<dim3(NK / 64, 16, BB), 256, 0, stream>>>(
      w_kv, ctxth, ctxtl, kbuf, kbh, kbl, nullptr, vbuf, CDIM, NK);
  gemmfold_k<0><<<dim3(NQ / 64, 8, BB), 256, 0, stream>>>(
      w_q, qsth, qstl, qbuf, qbh, qbl, qh, nullptr, CDIM, NQ);
  // 3. k-means: initial prep + one memset; centup_prep fuses update/prep/zero
  hipMemcpyAsync(cent, qbuf, 65536 * sizeof(float), hipMemcpyDeviceToDevice, stream);
  centprep_k<<<1024, 64, 0, stream>>>(cent, csq, cb2h, cb2l);
  hipMemsetAsync(sums, 0, (65536 + 1024) * sizeof(float), stream);
  for (int it = 0; it < 4; ++it) {
    assign_mfma_k<1><<<NPQ / 128, 256, 0, stream>>>(qbh, qbl, cb2h, cb2l, csq, asg);
    segsum_k<<<NPQ / 4, 256, 0, stream>>>(qbuf, asg, sums, cnt);
    centup_prep_k<<<65536 / 256, 256, 0, stream>>>(cent, sums, cnt, csq, cb2h, cb2l);
  }
  // 4. score keys: argmin (MFMA) -> exact f32 L1 dist -> per-head top-1024
  assign_mfma_k<0><<<NPK / 64, 256, 0, stream>>>(kbh, kbl, cb2h, cb2l, csq, asg);
  dist_k<<<NPK / 4, 256, 0, stream>>>(kbuf, cent, asg, dist);
  topk_k<<<BH, 1024, 0, stream>>>(dist, sel);
  // 5. gather (kh row-major f16, vT transposed f16)
  gatherb_k<<<dim3(TOPK / 64, BH), 256, 0, stream>>>(kbuf, vbuf, sel, kh, vT);
  // 6. MFMA attention (f16, XCD-mapped) -> split-f16 un-folded [b][n][512]
  attn_mfma_k<<<1024, 256, 0, stream>>>(qh, kh, vT, attnth, attntl);
  // 7. output projection (MFMA, LDS-staged)
  gemm_mfma_k<<<dim3(NQ / 64, 256 / 64, BB), 256, 0, stream>>>(w_out, attnth, attntl, ybuf, 256, 512, NQ);
  // 8. final LN + residual
  final_k<<<dim3(NQ / 64, BB), 256, 0, stream>>>(ybuf, on_g, on_b, gamma, qsrc, (float*)d_out);
}

// Round 17
// 504.367 us; speedup vs baseline: 1.9753x; 1.0210x over previous
//
#include <hip/hip_runtime.h>
#include <math.h>

#define BB 2
#define CDIM 256
#define NQ 4096   // 16*16*16
#define NK 2048   // 8*16*16
#define BH 16
#define TOPK 1024
#define NPQ (BH*NQ)   // 65536
#define NPK (BH*NK)   // 32768

typedef __attribute__((ext_vector_type(8))) short bfx8;
typedef __attribute__((ext_vector_type(8))) _Float16 hfx8;
typedef __attribute__((ext_vector_type(2))) __fp16 fpx2;
typedef __attribute__((ext_vector_type(4))) float fx4;
typedef __attribute__((ext_vector_type(4))) unsigned short us4;

__device__ inline unsigned short f2bf(float x) {
  unsigned u = __float_as_uint(x);
  return (unsigned short)((u + 0x7fffu + ((u >> 16) & 1u)) >> 16);
}
__device__ inline unsigned short f2h_bits(float x) {
  _Float16 h = (_Float16)x;
  unsigned short u;
  __builtin_memcpy(&u, &h, 2);
  return u;
}
__device__ inline float h_bits2f(unsigned short u) {
  _Float16 h;
  __builtin_memcpy(&h, &u, 2);
  return (float)h;
}

// ------- channel LayerNorm -> transposed split-f16 [b][n][C] (hi, lo*2048) ---
__global__ __launch_bounds__(256) void chan_ln_tsplit_k(
    const float* __restrict__ x, const float* __restrict__ g,
    const float* __restrict__ bta, unsigned short* __restrict__ yh,
    unsigned short* __restrict__ yl, int C, int N) {
  __shared__ float tile[4][64][65];
  __shared__ float p1[4][64], p2[4][64];
  __shared__ float mArr[64], invArr[64];
  int t = threadIdx.x, lane = t & 63, wv = t >> 6;
  int n0 = blockIdx.x * 64, bi = blockIdx.y;
  const float* xb = x + (size_t)bi * C * N + n0 + lane;
  float s = 0.f, s2 = 0.f;
  for (int cl = 0; cl < 64; ++cl) {
    float v = xb[(size_t)(wv * 64 + cl) * N];
    tile[wv][cl][lane] = v;
    s += v;
    s2 += v * v;
  }
  p1[wv][lane] = s;
  p2[wv][lane] = s2;
  __syncthreads();
  if (t < 64) {
    float ts = p1[0][t] + p1[1][t] + p1[2][t] + p1[3][t];
    float ts2 = p2[0][t] + p2[1][t] + p2[2][t] + p2[3][t];
    float m = ts / C;
    float var = ts2 / C - m * m;
    mArr[t] = m;
    invArr[t] = 1.f / (sqrtf(fmaxf(var, 0.f)) + 1e-6f);
  }
  __syncthreads();
  int c = wv * 64 + lane;  // lane = channel in phase 2
  float gc = g[c], bc = bta[c];
  unsigned short* ohb = yh + ((size_t)bi * N + n0) * C + c;
  unsigned short* olb = yl + ((size_t)bi * N + n0) * C + c;
  for (int pl = 0; pl < 64; ++pl) {
    float v = tile[wv][lane][pl];
    float ln = gc * (v - mArr[pl]) * invArr[pl] + bc;
    unsigned short hb = f2h_bits(ln);
    ohb[(size_t)pl * C] = hb;
    olb[(size_t)pl * C] = f2h_bits((ln - h_bits2f(hb)) * 2048.f);
  }
}

// ------- MFMA GEMM (w_out), LDS-staged X pipeline: Y[b][o][n] ----------------
__global__ __launch_bounds__(256) void gemm_mfma_k(
    const float* __restrict__ W, const unsigned short* __restrict__ Xh,
    const unsigned short* __restrict__ Xl, float* __restrict__ Y,
    int O, int C, int N) {
  __shared__ __align__(16) unsigned short xlds[2][64][64];  // [buf][row][hi32|lo32]
  int t = threadIdx.x, lane = t & 63, wv = t >> 6;
  int lq = lane & 15, lg = lane >> 4;
  int n0 = blockIdx.x * 64, o0 = blockIdx.y * 64 + wv * 16;
  int b = blockIdx.z;
  const unsigned short* xbh = Xh + ((size_t)b * N + n0) * C;
  const unsigned short* xbl = Xl + ((size_t)b * N + n0) * C;
  const float* wr = W + (size_t)(o0 + lq) * C;

  int a = t * 16;
  int srow = a >> 6;
  int schunk = (a >> 4) & 3;
  const unsigned short* gsh = xbh + (size_t)srow * C + schunk * 8;
  const unsigned short* gsl = xbl + (size_t)srow * C + schunk * 8;
  int swz = (srow & 7) << 4;
  int wbh = srow * 128 + ((schunk * 16) ^ swz);
  int wbl = srow * 128 + ((64 + schunk * 16) ^ swz);
  int rswz = (lq & 7) << 4;
  int xh0 = (lg * 16) ^ rswz;
  int xl0 = (64 + lg * 16) ^ rswz;

  fx4 ahi[4], alo[4];
  for (int nt = 0; nt < 4; ++nt) {
    ahi[nt] = (fx4){0.f, 0.f, 0.f, 0.f};
    alo[nt] = (fx4){0.f, 0.f, 0.f, 0.f};
  }

  {
    uint4 h0 = *(const uint4*)(gsh);
    uint4 l0 = *(const uint4*)(gsl);
    *(uint4*)((char*)&xlds[0][0][0] + wbh) = h0;
    *(uint4*)((char*)&xlds[0][0][0] + wbl) = l0;
  }
  float4 w0c = *(const float4*)(wr + lg * 8);
  float4 w1c = *(const float4*)(wr + lg * 8 + 4);

  int nsteps = C / 32;
  for (int s = 0; s < nsteps; ++s) {
    int cur = s & 1;
    __syncthreads();
    uint4 nh, nl;
    float4 nw0, nw1;
    if (s < nsteps - 1) {
      nh = *(const uint4*)(gsh + (s + 1) * 32);
      nl = *(const uint4*)(gsl + (s + 1) * 32);
      nw0 = *(const float4*)(wr + (s + 1) * 32 + lg * 8);
      nw1 = *(const float4*)(wr + (s + 1) * 32 + lg * 8 + 4);
    }
    __builtin_amdgcn_sched_barrier(0);
    float wv8[8] = {w0c.x, w0c.y, w0c.z, w0c.w, w1c.x, w1c.y, w1c.z, w1c.w};
    hfx8 ah, al;
#pragma unroll
    for (int i = 0; i < 8; ++i) {
      _Float16 hh = (_Float16)wv8[i];
      ah[i] = hh;
      al[i] = (_Float16)((wv8[i] - (float)hh) * 2048.f);
    }
    const char* Xb = (const char*)&xlds[cur][0][0];
#pragma unroll
    for (int nt = 0; nt < 4; ++nt) {
      int rb = (nt * 16 + lq) * 128;
      hfx8 bh = *(const hfx8*)(Xb + rb + xh0);
      hfx8 bl = *(const hfx8*)(Xb + rb + xl0);
      ahi[nt] = __builtin_amdgcn_mfma_f32_16x16x32_f16(ah, bh, ahi[nt], 0, 0, 0);
      alo[nt] = __builtin_amdgcn_mfma_f32_16x16x32_f16(al, bh, alo[nt], 0, 0, 0);
      alo[nt] = __builtin_amdgcn_mfma_f32_16x16x32_f16(ah, bl, alo[nt], 0, 0, 0);
    }
    __builtin_amdgcn_sched_barrier(0);
    if (s < nsteps - 1) {
      *(uint4*)((char*)&xlds[cur ^ 1][0][0] + wbh) = nh;
      *(uint4*)((char*)&xlds[cur ^ 1][0][0] + wbl) = nl;
      w0c = nw0;
      w1c = nw1;
    }
  }
  float* yb = Y + ((size_t)b * O + o0) * N + n0;
#pragma unroll
  for (int nt = 0; nt < 4; ++nt)
#pragma unroll
    for (int r = 0; r < 4; ++r)
      yb[(size_t)(lg * 4 + r) * N + nt * 16 + lq] = ahi[nt][r] + alo[nt][r] * (1.f / 2048.f);
}

// ------- fused GEMM + head-fold + L2-norm + multi-format emit ---------------
template <int PATH>
__global__ __launch_bounds__(256) void gemmfold_k(
    const float* __restrict__ W, const unsigned short* __restrict__ Xh,
    const unsigned short* __restrict__ Xl, float* __restrict__ fq,
    unsigned short* __restrict__ sh, unsigned short* __restrict__ sl,
    unsigned short* __restrict__ b16, float* __restrict__ fv,
    int C, int N) {
  __shared__ __align__(16) unsigned short xlds[2][64][64];  // [buf][row][hi32|lo32]
  __shared__ float ftile[64][65];
  __shared__ float part[4][64];
  __shared__ float invArr[64];
  int t = threadIdx.x, lane = t & 63, wv = t >> 6;
  int lq = lane & 15, lg = lane >> 4;
  int n0 = blockIdx.x * 64, o0 = blockIdx.y * 64 + wv * 16;
  int b = blockIdx.z;
  bool isV = (PATH == 1) && (blockIdx.y >= 8);
  int h = (PATH == 1) ? (blockIdx.y & 7) : blockIdx.y;
  const unsigned short* xbh = Xh + ((size_t)b * N + n0) * C;
  const unsigned short* xbl = Xl + ((size_t)b * N + n0) * C;
  const float* wr = W + (size_t)(o0 + lq) * C;

  int a = t * 16;
  int srow = a >> 6;
  int schunk = (a >> 4) & 3;
  const unsigned short* gsh = xbh + (size_t)srow * C + schunk * 8;
  const unsigned short* gsl = xbl + (size_t)srow * C + schunk * 8;
  int swz = (srow & 7) << 4;
  int wbh = srow * 128 + ((schunk * 16) ^ swz);
  int wbl = srow * 128 + ((64 + schunk * 16) ^ swz);
  int rswz = (lq & 7) << 4;
  int xh0 = (lg * 16) ^ rswz;
  int xl0 = (64 + lg * 16) ^ rswz;

  fx4 ahi[4], alo[4];
  for (int nt = 0; nt < 4; ++nt) {
    ahi[nt] = (fx4){0.f, 0.f, 0.f, 0.f};
    alo[nt] = (fx4){0.f, 0.f, 0.f, 0.f};
  }

  {
    uint4 h0 = *(const uint4*)(gsh);
    uint4 l0 = *(const uint4*)(gsl);
    *(uint4*)((char*)&xlds[0][0][0] + wbh) = h0;
    *(uint4*)((char*)&xlds[0][0][0] + wbl) = l0;
  }
  float4 w0c = *(const float4*)(wr + lg * 8);
  float4 w1c = *(const float4*)(wr + lg * 8 + 4);

  for (int s = 0; s < 8; ++s) {
    int cur = s & 1;
    __syncthreads();
    uint4 nh, nl;
    float4 nw0, nw1;
    if (s < 7) {
      nh = *(const uint4*)(gsh + (s + 1) * 32);
      nl = *(const uint4*)(gsl + (s + 1) * 32);
      nw0 = *(const float4*)(wr + (s + 1) * 32 + lg * 8);
      nw1 = *(const float4*)(wr + (s + 1) * 32 + lg * 8 + 4);
    }
    __builtin_amdgcn_sched_barrier(0);
    float wv8[8] = {w0c.x, w0c.y, w0c.z, w0c.w, w1c.x, w1c.y, w1c.z, w1c.w};
    hfx8 ah, al;
#pragma unroll
    for (int i = 0; i < 8; ++i) {
      _Float16 hh = (_Float16)wv8[i];
      ah[i] = hh;
      al[i] = (_Float16)((wv8[i] - (float)hh) * 2048.f);
    }
    const char* Xb = (const char*)&xlds[cur][0][0];
#pragma unroll
    for (int nt = 0; nt < 4; ++nt) {
      int rb = (nt * 16 + lq) * 128;
      hfx8 bh = *(const hfx8*)(Xb + rb + xh0);
      hfx8 bl = *(const hfx8*)(Xb + rb + xl0);
      ahi[nt] = __builtin_amdgcn_mfma_f32_16x16x32_f16(ah, bh, ahi[nt], 0, 0, 0);
      alo[nt] = __builtin_amdgcn_mfma_f32_16x16x32_f16(al, bh, alo[nt], 0, 0, 0);
      alo[nt] = __builtin_amdgcn_mfma_f32_16x16x32_f16(ah, bl, alo[nt], 0, 0, 0);
    }
    __builtin_amdgcn_sched_barrier(0);
    if (s < 7) {
      *(uint4*)((char*)&xlds[cur ^ 1][0][0] + wbh) = nh;
      *(uint4*)((char*)&xlds[cur ^ 1][0][0] + wbl) = nl;
      w0c = nw0;
      w1c = nw1;
    }
  }

  float val[4][4];
#pragma unroll
  for (int nt = 0; nt < 4; ++nt)
#pragma unroll
    for (int r = 0; r < 4; ++r)
      val[nt][r] = ahi[nt][r] + alo[nt][r] * (1.f / 2048.f);
  __syncthreads();
  if (!isV) {
#pragma unroll
    for (int nt = 0; nt < 4; ++nt) {
      float ss = val[nt][0] * val[nt][0] + val[nt][1] * val[nt][1] +
                 val[nt][2] * val[nt][2] + val[nt][3] * val[nt][3];
      ss += __shfl_xor(ss, 16);
      ss += __shfl_xor(ss, 32);
      if (lg == 0) part[wv][nt * 16 + lq] = ss;
    }
    __syncthreads();
    if (t < 64) {
      float tot = part[0][t] + part[1][t] + part[2][t] + part[3][t];
      invArr[t] = 1.f / fmaxf(sqrtf(tot), 1e-12f);
    }
    __syncthreads();
#pragma unroll
    for (int nt = 0; nt < 4; ++nt) {
      float iv = invArr[nt * 16 + lq];
#pragma unroll
      for (int r = 0; r < 4; ++r) val[nt][r] *= iv;
    }
    __syncthreads();
  }
#pragma unroll
  for (int nt = 0; nt < 4; ++nt)
#pragma unroll
    for (int r = 0; r < 4; ++r)
      ftile[nt * 16 + lq][wv * 16 + lg * 4 + r] = val[nt][r];
  __syncthreads();
  size_t rowb = (size_t)(b * 8 + h) * N + n0;
  for (int r2 = 0; r2 < 16; ++r2) {
    int n = r2 * 4 + wv;
    float v = ftile[n][lane];
    size_t idx = (rowb + n) * 64 + lane;
    if (PATH == 1 && isV) {
      fv[idx] = v;
    } else {
      fq[idx] = v;
      unsigned short hb = f2h_bits(v);
      sh[idx] = hb;
      sl[idx] = f2h_bits((v - h_bits2f(hb)) * 2048.f);
      if (PATH == 0) b16[idx] = hb;  // f16 copy for attention
    }
  }
}

// ---------------- centroid prep (initial only): csq, -2c split f16 -----------
__global__ void centprep_k(const float* __restrict__ cent, float* __restrict__ csq,
                           unsigned short* __restrict__ cb2h, unsigned short* __restrict__ cb2l) {
  int j = blockIdx.x, lane = threadIdx.x;  // blockDim = 64
  float c = cent[j * 64 + lane];
  float s = c * c;
  for (int off = 32; off; off >>= 1) s += __shfl_xor(s, off);
  if (lane == 0) csq[j] = s;
  float m2 = -2.f * c;
  unsigned short h = f2h_bits(m2);
  cb2h[j * 64 + lane] = h;
  cb2l[j * 64 + lane] = f2h_bits((m2 - h_bits2f(h)) * 2048.f);
}

// ---------------- MFMA nearest-centroid assign (f16 split, LDS-staged) -------
// Two subtiles per barrier (4 LDS buffers, subtile u in buffer u&3): half the
// barrier count, 2x (DUO: 4x) independent MFMA chains per iteration.
// Per-candidate arithmetic and scan order identical to R16 (bit-exact).
template <int DUO>
__global__ __launch_bounds__(256) void assign_mfma_k(
    const unsigned short* __restrict__ xh, const unsigned short* __restrict__ xl,
    const unsigned short* __restrict__ cb2h, const unsigned short* __restrict__ cb2l,
    const float* __restrict__ csq, int* __restrict__ aout) {
  __shared__ __align__(16) unsigned short clds[4][2][1024];  // [buf][hi/lo][16x64]
  int t = threadIdx.x, lane = t & 63, wv = t >> 6;
  int lq = lane & 15, lg = lane >> 4;
  int p0 = blockIdx.x * (DUO ? 128 : 64) + wv * (DUO ? 32 : 16);
  const unsigned short* xbA = xh + (size_t)(p0 + lq) * 64;
  const unsigned short* xlA = xl + (size_t)(p0 + lq) * 64;
  hfx8 ba0 = *(const hfx8*)(xbA + lg * 8);
  hfx8 ba1 = *(const hfx8*)(xbA + 32 + lg * 8);
  hfx8 la0 = *(const hfx8*)(xlA + lg * 8);
  hfx8 la1 = *(const hfx8*)(xlA + 32 + lg * 8);
  hfx8 bb0, bb1, lb0, lb1;
  if (DUO) {
    const unsigned short* xbB = xh + (size_t)(p0 + 16 + lq) * 64;
    const unsigned short* xlB = xl + (size_t)(p0 + 16 + lq) * 64;
    bb0 = *(const hfx8*)(xbB + lg * 8);
    bb1 = *(const hfx8*)(xbB + 32 + lg * 8);
    lb0 = *(const hfx8*)(xlB + lg * 8);
    lb1 = *(const hfx8*)(xlB + 32 + lg * 8);
  }

  int part = t >> 7;
  int abyte = (t & 127) * 16;
  int wbyte = abyte ^ (((abyte >> 7) & 7) << 4);
  const unsigned short* gsrc = (part ? cb2l : cb2h) + (abyte >> 1);
  int rowoff = lq * 128;
  int x0 = (lg * 16) ^ ((lq & 7) << 4);
  int x1 = (64 + lg * 16) ^ ((lq & 7) << 4);

  float bestA = 3.4e38f, bestB = 3.4e38f;
  int jA = 0, jB = 0;

  // prologue: stage subtiles 0 and 1
  {
    uint4 r0 = *(const uint4*)(gsrc);
    uint4 r1 = *(const uint4*)(gsrc + 1024);
    *(uint4*)((char*)&clds[0][part][0] + wbyte) = r0;
    *(uint4*)((char*)&clds[1][part][0] + wbyte) = r1;
  }

  for (int s = 0; s < 64; s += 2) {
    __syncthreads();
    uint4 rn0, rn1;
    if (s < 62) {
      rn0 = *(const uint4*)(gsrc + (size_t)(s + 2) * 1024);
      rn1 = *(const uint4*)(gsrc + (size_t)(s + 3) * 1024);
    }
    __builtin_amdgcn_sched_barrier(0);
#pragma unroll
    for (int u = 0; u < 2; ++u) {
      int st = s + u;
      const char* ph = (const char*)&clds[st & 3][0][0];
      const char* pl = (const char*)&clds[st & 3][1][0];
      hfx8 ah0 = *(const hfx8*)(ph + rowoff + x0);
      hfx8 ah1 = *(const hfx8*)(ph + rowoff + x1);
      hfx8 al0 = *(const hfx8*)(pl + rowoff + x0);
      hfx8 al1 = *(const hfx8*)(pl + rowoff + x1);
      fx4 cq = *(const fx4*)(csq + st * 16 + lg * 4);
      {
        fx4 chi = cq;
        chi = __builtin_amdgcn_mfma_f32_16x16x32_f16(ah0, ba0, chi, 0, 0, 0);
        chi = __builtin_amdgcn_mfma_f32_16x16x32_f16(ah1, ba1, chi, 0, 0, 0);
        fx4 clo = (fx4){0.f, 0.f, 0.f, 0.f};
        clo = __builtin_amdgcn_mfma_f32_16x16x32_f16(ah0, la0, clo, 0, 0, 0);
        clo = __builtin_amdgcn_mfma_f32_16x16x32_f16(ah1, la1, clo, 0, 0, 0);
        clo = __builtin_amdgcn_mfma_f32_16x16x32_f16(al0, ba0, clo, 0, 0, 0);
        clo = __builtin_amdgcn_mfma_f32_16x16x32_f16(al1, ba1, clo, 0, 0, 0);
#pragma unroll
        for (int r_ = 0; r_ < 4; ++r_) {
          int j_ = st * 16 + lg * 4 + r_;
          float d2_ = chi[r_] + clo[r_] * (1.f / 2048.f);
          if (d2_ < bestA) { bestA = d2_; jA = j_; }
        }
      }
      if (DUO) {
        fx4 chi = cq;
        chi = __builtin_amdgcn_mfma_f32_16x16x32_f16(ah0, bb0, chi, 0, 0, 0);
        chi = __builtin_amdgcn_mfma_f32_16x16x32_f16(ah1, bb1, chi, 0, 0, 0);
        fx4 clo = (fx4){0.f, 0.f, 0.f, 0.f};
        clo = __builtin_amdgcn_mfma_f32_16x16x32_f16(ah0, lb0, clo, 0, 0, 0);
        clo = __builtin_amdgcn_mfma_f32_16x16x32_f16(ah1, lb1, clo, 0, 0, 0);
        clo = __builtin_amdgcn_mfma_f32_16x16x32_f16(al0, bb0, clo, 0, 0, 0);
        clo = __builtin_amdgcn_mfma_f32_16x16x32_f16(al1, bb1, clo, 0, 0, 0);
#pragma unroll
        for (int r_ = 0; r_ < 4; ++r_) {
          int j_ = st * 16 + lg * 4 + r_;
          float d2_ = chi[r_] + clo[r_] * (1.f / 2048.f);
          if (d2_ < bestB) { bestB = d2_; jB = j_; }
        }
      }
    }
    __builtin_amdgcn_sched_barrier(0);
    if (s < 62) {
      *(uint4*)((char*)&clds[(s + 2) & 3][part][0] + wbyte) = rn0;
      *(uint4*)((char*)&clds[(s + 3) & 3][part][0] + wbyte) = rn1;
    }
  }

  {
    float o = __shfl_xor(bestA, 16);
    int oj = __shfl_xor(jA, 16);
    if (o < bestA || (o == bestA && oj < jA)) { bestA = o; jA = oj; }
    o = __shfl_xor(bestA, 32);
    oj = __shfl_xor(jA, 32);
    if (o < bestA || (o == bestA && oj < jA)) { bestA = o; jA = oj; }
  }
  if (DUO) {
    float o = __shfl_xor(bestB, 16);
    int oj = __shfl_xor(jB, 16);
    if (o < bestB || (o == bestB && oj < jB)) { bestB = o; jB = oj; }
    o = __shfl_xor(bestB, 32);
    oj = __shfl_xor(jB, 32);
    if (o < bestB || (o == bestB && oj < jB)) { bestB = o; jB = oj; }
  }
  if (lg == 0) {
    aout[p0 + lq] = jA;
    if (DUO) aout[p0 + 16 + lq] = jB;
  }
}

// ---------------- exact f32 L1 distance to assigned centroid -----------------
__global__ void dist_k(const float* __restrict__ x, const float* __restrict__ cent,
                       const int* __restrict__ asg, float* __restrict__ dout) {
  int t = threadIdx.x, lane = t & 63, wv = t >> 6;
  int p = blockIdx.x * 4 + wv;
  int a = asg[p];
  float v = fabsf(cent[(size_t)a * 64 + lane] - x[(size_t)p * 64 + lane]);
  for (int off = 32; off; off >>= 1) v += __shfl_xor(v, off);
  if (lane == 0) dout[p] = v;
}

// ---------------- segment sum via atomics (wave=point: coalesced) ------------
__global__ void segsum_k(const float* __restrict__ x, const int* __restrict__ asg,
                         float* __restrict__ sums, float* __restrict__ cnt) {
  int t = threadIdx.x, lane = t & 63, wv = t >> 6;
  int p = blockIdx.x * 4 + wv;
  int a = asg[p];
  float v = x[(size_t)p * 64 + lane];
  atomicAdd(&sums[a * 64 + lane], v);
  if (lane == 0) atomicAdd(&cnt[a], 1.0f);
}

// ---------------- centroid update + prep + zero (fused) ----------------------
__global__ __launch_bounds__(256) void centup_prep_k(
    float* __restrict__ cent, float* __restrict__ sums, float* __restrict__ cnt,
    float* __restrict__ csq, unsigned short* __restrict__ cb2h,
    unsigned short* __restrict__ cb2l) {
  int i = blockIdx.x * 256 + threadIdx.x;  // 65536 total; rows never span blocks
  int j = i >> 6, lane = threadIdx.x & 63;
  float c = cnt[j];
  float oldc = cent[i];
  float newc = (c > 0.f) ? sums[i] / fmaxf(c, 1.f) : oldc;
  cent[i] = newc;
  float s = newc * newc;
  for (int off = 32; off; off >>= 1) s += __shfl_xor(s, off);
  if (lane == 0) csq[j] = s;
  float m2 = -2.f * newc;
  unsigned short h = f2h_bits(m2);
  cb2h[i] = h;
  cb2l[i] = f2h_bits((m2 - h_bits2f(h)) * 2048.f);
  sums[i] = 0.f;
  if (lane == 0) cnt[j] = 0.f;
}

// ---------------- per-bh top-1024 by descending dist (stable ties) -----------
__global__ __launch_bounds__(1024) void topk_k(const float* __restrict__ dist,
                                               int* __restrict__ sel) {
  __shared__ unsigned long long keys[2048];
  int bh = blockIdx.x, t = threadIdx.x;
  for (int i = t; i < 2048; i += 1024) {
    float d = dist[bh * 2048 + i];
    unsigned int db = __float_as_uint(d);  // d >= 0 -> monotonic
    keys[i] = ((unsigned long long)db << 32) | (unsigned int)(2047 - i);
  }
  __syncthreads();
  for (int k = 2; k <= 2048; k <<= 1) {
    for (int j = k >> 1; j > 0; j >>= 1) {
      for (int i = t; i < 2048; i += 1024) {
        int ixj = i ^ j;
        if (ixj > i) {
          unsigned long long a = keys[i], b = keys[ixj];
          bool up = ((i & k) == 0);
          bool sw = up ? (a < b) : (a > b);  // descending overall
          if (sw) { keys[i] = b; keys[ixj] = a; }
        }
      }
      __syncthreads();
    }
  }
  if (t < 1024) sel[bh * 1024 + t] = 2047 - (int)(keys[t] & 0xffffffffu);
}

// ---------------- gather selected rows -> kh (f16 row-major), vT (f16 d-major)
__global__ void gatherb_k(const float* __restrict__ kbuf, const float* __restrict__ vbuf,
                          const int* __restrict__ sel, unsigned short* __restrict__ kh,
                          unsigned short* __restrict__ vT) {
  __shared__ unsigned short tile[64][66];
  int t = threadIdx.x, lane = t & 63, wv = t >> 6;
  int bh = blockIdx.y, i0 = blockIdx.x * 64;
  for (int r = 0; r < 16; ++r) {
    int i = r * 4 + wv;
    int src = sel[bh * 1024 + i0 + i];
    float kvv = kbuf[((size_t)bh * 2048 + src) * 64 + lane];
    kh[((size_t)bh * 1024 + i0 + i) * 64 + lane] = f2h_bits(kvv);
    float vv = vbuf[((size_t)bh * 2048 + src) * 64 + lane];
    tile[i][lane] = f2h_bits(vv);
  }
  __syncthreads();
  for (int r = 0; r < 16; ++r) {
    int d = r * 4 + wv;
    vT[((size_t)bh * 64 + d) * 1024 + i0 + lane] = tile[lane][d];
  }
}

// ---------------- MFMA flash attention (f16, K/V LDS-staged, XCD-mapped) -----
__global__ __launch_bounds__(256) void attn_mfma_k(
    const unsigned short* __restrict__ qh, const unsigned short* __restrict__ kh,
    const unsigned short* __restrict__ vT,
    unsigned short* __restrict__ oh, unsigned short* __restrict__ ol) {
  __shared__ __align__(16) unsigned short kvlds[2][2][4096];  // [buf][K/V][64x64]
  __shared__ __align__(16) unsigned short plds[4][16][72];
  int t = threadIdx.x, lane = t & 63, wv = t >> 6;
  int lq = lane & 15, lg = lane >> 4;
  int id = blockIdx.x;
  int bh = (id & 7) * 2 + ((id >> 3) & 1);
  int q0 = (id >> 4) * 64 + wv * 16;
  const unsigned short* qbase = qh + ((size_t)bh * 4096 + q0 + lq) * 64;
  hfx8 qf0 = *(const hfx8*)(qbase + lg * 8);
  hfx8 qf1 = *(const hfx8*)(qbase + 32 + lg * 8);
  fx4 acc[4];
  for (int nt = 0; nt < 4; ++nt) acc[nt] = (fx4){0.f, 0.f, 0.f, 0.f};
  float lsum = 0.f;
  const unsigned short* kbase = kh + (size_t)bh * 1024 * 64;
  const unsigned short* vbase = vT + (size_t)bh * 64 * 1024;

  int srow = t >> 2;
  int scolb = (t & 3) * 32;
  const char* gK = (const char*)kbase + (size_t)srow * 128 + scolb;   // + s*8192
  const char* gV = (const char*)vbase + (size_t)srow * 2048 + scolb;  // + s*128
  int sw_w = (srow & 7) << 4;
  int wb0 = srow * 128 + (scolb ^ sw_w);
  int wb1 = srow * 128 + ((scolb + 16) ^ sw_w);

  {
    uint4 k0 = *(const uint4*)(gK);
    uint4 k1 = *(const uint4*)(gK + 16);
    uint4 v0 = *(const uint4*)(gV);
    uint4 v1 = *(const uint4*)(gV + 16);
    *(uint4*)((char*)&kvlds[0][0][0] + wb0) = k0;
    *(uint4*)((char*)&kvlds[0][0][0] + wb1) = k1;
    *(uint4*)((char*)&kvlds[0][1][0] + wb0) = v0;
    *(uint4*)((char*)&kvlds[0][1][0] + wb1) = v1;
  }

  int swr = (lq & 7) << 4;
  int rc0 = (lg * 16) ^ swr;
  int rc1 = (64 + lg * 16) ^ swr;

  for (int s = 0; s < 16; ++s) {
    int cur = s & 1;
    __syncthreads();
    uint4 nk0, nk1, nv0, nv1;
    if (s < 15) {
      const char* gKn = gK + (size_t)(s + 1) * 8192;
      const char* gVn = gV + (size_t)(s + 1) * 128;
      nk0 = *(const uint4*)(gKn);
      nk1 = *(const uint4*)(gKn + 16);
      nv0 = *(const uint4*)(gVn);
      nv1 = *(const uint4*)(gVn + 16);
    }
    __builtin_amdgcn_sched_barrier(0);
    const char* Kb = (const char*)&kvlds[cur][0][0];
    const char* Vb = (const char*)&kvlds[cur][1][0];
    fx4 sS[4];
#pragma unroll
    for (int mt = 0; mt < 4; ++mt) {
      int rowb = (mt * 16 + lq) * 128;
      hfx8 a0 = *(const hfx8*)(Kb + rowb + rc0);
      hfx8 a1 = *(const hfx8*)(Kb + rowb + rc1);
      fx4 c = (fx4){0.f, 0.f, 0.f, 0.f};
      c = __builtin_amdgcn_mfma_f32_16x16x32_f16(a0, qf0, c, 0, 0, 0);
      c = __builtin_amdgcn_mfma_f32_16x16x32_f16(a1, qf1, c, 0, 0, 0);
      sS[mt] = c;
    }
#pragma unroll
    for (int mt = 0; mt < 4; ++mt) {
      float p0 = __expf(sS[mt].x), p1 = __expf(sS[mt].y);
      float p2 = __expf(sS[mt].z), p3 = __expf(sS[mt].w);
      lsum += (p0 + p1) + (p2 + p3);
      fpx2 c01 = __builtin_amdgcn_cvt_pkrtz(p0, p1);
      fpx2 c23 = __builtin_amdgcn_cvt_pkrtz(p2, p3);
      unsigned u01, u23;
      __builtin_memcpy(&u01, &c01, 4);
      __builtin_memcpy(&u23, &c23, 4);
      uint2 pk = {u01, u23};
      *(uint2*)&plds[wv][lq][mt * 16 + lg * 4] = pk;
    }
    hfx8 pa0 = *(const hfx8*)&plds[wv][lq][lg * 8];
    hfx8 pa1 = *(const hfx8*)&plds[wv][lq][32 + lg * 8];
#pragma unroll
    for (int nt = 0; nt < 4; ++nt) {
      int rowb = (nt * 16 + lq) * 128;
      hfx8 b0 = *(const hfx8*)(Vb + rowb + rc0);
      hfx8 b1 = *(const hfx8*)(Vb + rowb + rc1);
      acc[nt] = __builtin_amdgcn_mfma_f32_16x16x32_f16(pa0, b0, acc[nt], 0, 0, 0);
      acc[nt] = __builtin_amdgcn_mfma_f32_16x16x32_f16(pa1, b1, acc[nt], 0, 0, 0);
    }
    __builtin_amdgcn_sched_barrier(0);
    if (s < 15) {
      char* dK = (char*)&kvlds[cur ^ 1][0][0];
      char* dV = (char*)&kvlds[cur ^ 1][1][0];
      *(uint4*)(dK + wb0) = nk0;
      *(uint4*)(dK + wb1) = nk1;
      *(uint4*)(dV + wb0) = nv0;
      *(uint4*)(dV + wb1) = nv1;
    }
  }
  lsum += __shfl_xor(lsum, 16);
  lsum += __shfl_xor(lsum, 32);
  int bi = bh >> 3, hd = bh & 7;
  for (int r = 0; r < 4; ++r) {
    float inv = 1.f / __shfl(lsum, lg * 4 + r);
    size_t rowb = ((size_t)bi * 4096 + q0 + lg * 4 + r) * 512 + hd * 64;
    for (int nt = 0; nt < 4; ++nt) {
      float val = acc[nt][r] * inv;
      unsigned short hb = f2h_bits(val);
      oh[rowb + nt * 16 + lq] = hb;
      ol[rowb + nt * 16 + lq] = f2h_bits((val - h_bits2f(hb)) * 2048.f);
    }
  }
}

// ---------------- final LN + gamma*ln + residual (wave-split channels) -------
__global__ __launch_bounds__(256) void final_k(
    const float* __restrict__ y, const float* __restrict__ g,
    const float* __restrict__ bta, const float* __restrict__ gamma,
    const float* __restrict__ qs, float* __restrict__ out) {
  __shared__ float p1[4][64], p2[4][64];
  __shared__ float mArr[64], invArr[64];
  int t = threadIdx.x, lane = t & 63, wv = t >> 6;
  int n0 = blockIdx.x * 64, bi = blockIdx.y;
  const float* yb = y + (size_t)bi * CDIM * NQ + n0 + lane;
  float s = 0.f, s2 = 0.f;
  for (int cl = 0; cl < 64; ++cl) {
    float v = yb[(size_t)(wv * 64 + cl) * NQ];
    s += v;
    s2 += v * v;
  }
  p1[wv][lane] = s;
  p2[wv][lane] = s2;
  __syncthreads();
  if (t < 64) {
    float ts = p1[0][t] + p1[1][t] + p1[2][t] + p1[3][t];
    float ts2 = p2[0][t] + p2[1][t] + p2[2][t] + p2[3][t];
    float m = ts / CDIM;
    float var = ts2 / CDIM - m * m;
    mArr[t] = m;
    invArr[t] = 1.f / (sqrtf(fmaxf(var, 0.f)) + 1e-6f);
  }
  __syncthreads();
  float gm = gamma[0];
  float m = mArr[lane], inv = invArr[lane];
  const float* qb = qs + (size_t)bi * CDIM * NQ + n0 + lane;
  float* ob = out + (size_t)bi * CDIM * NQ + n0 + lane;
  for (int cl = 0; cl < 64; ++cl) {
    int c = wv * 64 + cl;
    float v = yb[(size_t)c * NQ];
    float ln = g[c] * (v - m) * inv + bta[c];
    ob[(size_t)c * NQ] = gm * ln + qb[(size_t)c * NQ];
  }
}

extern "C" void kernel_launch(void* const* d_in, const int* in_sizes, int n_in,
                              void* d_out, int out_size, void* d_ws, size_t ws_size,
                              hipStream_t stream) {
  const float* qsrc = (const float*)d_in[0];
  const float* ctx = (const float*)d_in[1];
  const float* w_q = (const float*)d_in[2];
  const float* w_kv = (const float*)d_in[3];
  const float* w_out = (const float*)d_in[4];
  const float* cn_g = (const float*)d_in[5];
  const float* cn_b = (const float*)d_in[6];
  const float* qn_g = (const float*)d_in[7];
  const float* qn_b = (const float*)d_in[8];
  const float* on_g = (const float*)d_in[9];
  const float* on_b = (const float*)d_in[10];
  const float* gamma = (const float*)d_in[11];

  // scratch layout (floats); total 22,267,904 floats = 89.1 MB
  if (ws_size < (size_t)22267904 * 4) return;
  float* ws = (float*)d_ws;
  float* r_ctx = ws;                      // 1,048,576 f: ctx split-f16; later kh/vT
  float* r_kv = r_ctx + 1048576;          // 4,194,304 f: kbh/kbl f16; later attnt split
  float* r_qs = r_kv + 4194304;           // 2,097,152 f: qs split-f16; later cb2h/l, ybuf
  float* r_q3 = r_qs + 2097152;           // 4,194,304 f: qbh/qbl f16
  float* qbuf = r_q3 + 4194304;           // 4,194,304 f
  float* kbuf = qbuf + 4194304;           // 2,097,152 f
  float* vbuf = kbuf + 2097152;           // 2,097,152 f
  float* cent = vbuf + 2097152;           // 65,536 f
  float* csq = cent + 65536;              // 1,024 f
  float* sums = csq + 1024;               // 65,536 f
  float* cnt = sums + 65536;              // 1,024 f
  int* asg = (int*)(cnt + 1024);          // 65,536 i
  float* dist = (float*)(asg + 65536);    // 32,768 f
  int* sel = (int*)(dist + 32768);        // 16,384 i
  float* kgreg = (float*)(sel + 16384);   // 2,097,152 f (qh f16)

  unsigned short* ctxth = (unsigned short*)r_ctx;   // [b][2048][256] f16 hi
  unsigned short* ctxtl = ctxth + (size_t)BB * NK * CDIM;  // lo
  unsigned short* qsth = (unsigned short*)r_qs;     // [b][4096][256] f16 hi
  unsigned short* qstl = qsth + (size_t)BB * NQ * CDIM;    // lo
  unsigned short* qh = (unsigned short*)kgreg;      // 4M f16
  unsigned short* kh = (unsigned short*)r_ctx;      // 1M f16 (ctx split dead)
  unsigned short* vT = kh + 1048576;                // 1M f16
  unsigned short* qbh = (unsigned short*)r_q3;      // 4M f16 (q split hi)
  unsigned short* qbl = qbh + (size_t)NPQ * 64;     // 4M f16 (lo)
  unsigned short* kbh = (unsigned short*)r_kv;      // 2M f16 (k split hi)
  unsigned short* kbl = kbh + (size_t)NPK * 64;     // 2M f16 (lo)
  unsigned short* cb2h = (unsigned short*)r_qs;     // 64K f16 (-2c hi)
  unsigned short* cb2l = cb2h + 65536;              // 64K f16 (lo)
  unsigned short* attnth = (unsigned short*)r_kv;   // [b][4096][512] f16 hi (kb split dead)
  unsigned short* attntl = attnth + (size_t)BB * NQ * 512;  // lo
  float* ybuf = r_qs;                     // [b][256][4096] f32 (cb2 dead)

  // 1. channel LayerNorms -> transposed split-f16
  chan_ln_tsplit_k<<<dim3(NK / 64, BB), 256, 0, stream>>>(ctx, cn_g, cn_b, ctxth, ctxtl, CDIM, NK);
  chan_ln_tsplit_k<<<dim3(NQ / 64, BB), 256, 0, stream>>>(qsrc, qn_g, qn_b, qsth, qstl, CDIM, NQ);
  // 2. fused MFMA projections + fold + L2-norm + format emit (LDS-pipelined)
  gemmfold_k<1><<<dim3(NK / 64, 16, BB), 256, 0, stream>>>(
      w_kv, ctxth, ctxtl, kbuf, kbh, kbl, nullptr, vbuf, CDIM, NK);
  gemmfold_k<0><<<dim3(NQ / 64, 8, BB), 256, 0, stream>>>(
      w_q, qsth, qstl, qbuf, qbh, qbl, qh, nullptr, CDIM, NQ);
  // 3. k-means: initial prep + one memset; centup_prep fuses update/prep/zero
  hipMemcpyAsync(cent, qbuf, 65536 * sizeof(float), hipMemcpyDeviceToDevice, stream);
  centprep_k<<<1024, 64, 0, stream>>>(cent, csq, cb2h, cb2l);
  hipMemsetAsync(sums, 0, (65536 + 1024) * sizeof(float), stream);
  for (int it = 0; it < 4; ++it) {
    assign_mfma_k<1><<<NPQ / 128, 256, 0, stream>>>(qbh, qbl, cb2h, cb2l, csq, asg);
    segsum_k<<<NPQ / 4, 256, 0, stream>>>(qbuf, asg, sums, cnt);
    centup_prep_k<<<65536 / 256, 256, 0, stream>>>(cent, sums, cnt, csq, cb2h, cb2l);
  }
  // 4. score keys: argmin (MFMA) -> exact f32 L1 dist -> per-head top-1024
  assign_mfma_k<0><<<NPK / 64, 256, 0, stream>>>(kbh, kbl, cb2h, cb2l, csq, asg);
  dist_k<<<NPK / 4, 256, 0, stream>>>(kbuf, cent, asg, dist);
  topk_k<<<BH, 1024, 0, stream>>>(dist, sel);
  // 5. gather (kh row-major f16, vT transposed f16)
  gatherb_k<<<dim3(TOPK / 64, BH), 256, 0, stream>>>(kbuf, vbuf, sel, kh, vT);
  // 6. MFMA attention (f16, XCD-mapped) -> split-f16 un-folded [b][n][512]
  attn_mfma_k<<<1024, 256, 0, stream>>>(qh, kh, vT, attnth, attntl);
  // 7. output projection (MFMA, LDS-staged)
  gemm_mfma_k<<<dim3(NQ / 64, 256 / 64, BB), 256, 0, stream>>>(w_out, attnth, attntl, ybuf, 256, 512, NQ);
  // 8. final LN + residual
  final_k<<<dim3(NQ / 64, BB), 256, 0, stream>>>(ybuf, on_g, on_b, gamma, qsrc, (float*)d_out);
}

// Round 18
// 482.929 us; speedup vs baseline: 2.0630x; 1.0444x over previous
//
#include <hip/hip_runtime.h>
#include <math.h>

#define BB 2
#define CDIM 256
#define NQ 4096   // 16*16*16
#define NK 2048   // 8*16*16
#define BH 16
#define TOPK 1024
#define NPQ (BH*NQ)   // 65536
#define NPK (BH*NK)   // 32768

typedef __attribute__((ext_vector_type(8))) short bfx8;
typedef __attribute__((ext_vector_type(8))) _Float16 hfx8;
typedef __attribute__((ext_vector_type(2))) __fp16 fpx2;
typedef __attribute__((ext_vector_type(4))) float fx4;
typedef __attribute__((ext_vector_type(4))) unsigned short us4;

__device__ inline unsigned short f2bf(float x) {
  unsigned u = __float_as_uint(x);
  return (unsigned short)((u + 0x7fffu + ((u >> 16) & 1u)) >> 16);
}
__device__ inline unsigned short f2h_bits(float x) {
  _Float16 h = (_Float16)x;
  unsigned short u;
  __builtin_memcpy(&u, &h, 2);
  return u;
}
__device__ inline float h_bits2f(unsigned short u) {
  _Float16 h;
  __builtin_memcpy(&h, &u, 2);
  return (float)h;
}

// ------- channel LayerNorm -> transposed split-f16 [b][n][C] (hi, lo*2048) ---
__global__ __launch_bounds__(256) void chan_ln_tsplit_k(
    const float* __restrict__ x, const float* __restrict__ g,
    const float* __restrict__ bta, unsigned short* __restrict__ yh,
    unsigned short* __restrict__ yl, int C, int N) {
  __shared__ float tile[4][64][65];
  __shared__ float p1[4][64], p2[4][64];
  __shared__ float mArr[64], invArr[64];
  int t = threadIdx.x, lane = t & 63, wv = t >> 6;
  int n0 = blockIdx.x * 64, bi = blockIdx.y;
  const float* xb = x + (size_t)bi * C * N + n0 + lane;
  float s = 0.f, s2 = 0.f;
  for (int cl = 0; cl < 64; ++cl) {
    float v = xb[(size_t)(wv * 64 + cl) * N];
    tile[wv][cl][lane] = v;
    s += v;
    s2 += v * v;
  }
  p1[wv][lane] = s;
  p2[wv][lane] = s2;
  __syncthreads();
  if (t < 64) {
    float ts = p1[0][t] + p1[1][t] + p1[2][t] + p1[3][t];
    float ts2 = p2[0][t] + p2[1][t] + p2[2][t] + p2[3][t];
    float m = ts / C;
    float var = ts2 / C - m * m;
    mArr[t] = m;
    invArr[t] = 1.f / (sqrtf(fmaxf(var, 0.f)) + 1e-6f);
  }
  __syncthreads();
  int c = wv * 64 + lane;  // lane = channel in phase 2
  float gc = g[c], bc = bta[c];
  unsigned short* ohb = yh + ((size_t)bi * N + n0) * C + c;
  unsigned short* olb = yl + ((size_t)bi * N + n0) * C + c;
  for (int pl = 0; pl < 64; ++pl) {
    float v = tile[wv][lane][pl];
    float ln = gc * (v - mArr[pl]) * invArr[pl] + bc;
    unsigned short hb = f2h_bits(ln);
    ohb[(size_t)pl * C] = hb;
    olb[(size_t)pl * C] = f2h_bits((ln - h_bits2f(hb)) * 2048.f);
  }
}

// ------- MFMA GEMM (w_out), LDS-staged X pipeline: Y[b][o][n] ----------------
__global__ __launch_bounds__(256) void gemm_mfma_k(
    const float* __restrict__ W, const unsigned short* __restrict__ Xh,
    const unsigned short* __restrict__ Xl, float* __restrict__ Y,
    int O, int C, int N) {
  __shared__ __align__(16) unsigned short xlds[2][64][64];  // [buf][row][hi32|lo32]
  int t = threadIdx.x, lane = t & 63, wv = t >> 6;
  int lq = lane & 15, lg = lane >> 4;
  int n0 = blockIdx.x * 64, o0 = blockIdx.y * 64 + wv * 16;
  int b = blockIdx.z;
  const unsigned short* xbh = Xh + ((size_t)b * N + n0) * C;
  const unsigned short* xbl = Xl + ((size_t)b * N + n0) * C;
  const float* wr = W + (size_t)(o0 + lq) * C;

  int a = t * 16;
  int srow = a >> 6;
  int schunk = (a >> 4) & 3;
  const unsigned short* gsh = xbh + (size_t)srow * C + schunk * 8;
  const unsigned short* gsl = xbl + (size_t)srow * C + schunk * 8;
  int swz = (srow & 7) << 4;
  int wbh = srow * 128 + ((schunk * 16) ^ swz);
  int wbl = srow * 128 + ((64 + schunk * 16) ^ swz);
  int rswz = (lq & 7) << 4;
  int xh0 = (lg * 16) ^ rswz;
  int xl0 = (64 + lg * 16) ^ rswz;

  fx4 ahi[4], alo[4];
  for (int nt = 0; nt < 4; ++nt) {
    ahi[nt] = (fx4){0.f, 0.f, 0.f, 0.f};
    alo[nt] = (fx4){0.f, 0.f, 0.f, 0.f};
  }

  {
    uint4 h0 = *(const uint4*)(gsh);
    uint4 l0 = *(const uint4*)(gsl);
    *(uint4*)((char*)&xlds[0][0][0] + wbh) = h0;
    *(uint4*)((char*)&xlds[0][0][0] + wbl) = l0;
  }
  float4 w0c = *(const float4*)(wr + lg * 8);
  float4 w1c = *(const float4*)(wr + lg * 8 + 4);

  int nsteps = C / 32;
  for (int s = 0; s < nsteps; ++s) {
    int cur = s & 1;
    __syncthreads();
    uint4 nh, nl;
    float4 nw0, nw1;
    if (s < nsteps - 1) {
      nh = *(const uint4*)(gsh + (s + 1) * 32);
      nl = *(const uint4*)(gsl + (s + 1) * 32);
      nw0 = *(const float4*)(wr + (s + 1) * 32 + lg * 8);
      nw1 = *(const float4*)(wr + (s + 1) * 32 + lg * 8 + 4);
    }
    __builtin_amdgcn_sched_barrier(0);
    float wv8[8] = {w0c.x, w0c.y, w0c.z, w0c.w, w1c.x, w1c.y, w1c.z, w1c.w};
    hfx8 ah, al;
#pragma unroll
    for (int i = 0; i < 8; ++i) {
      _Float16 hh = (_Float16)wv8[i];
      ah[i] = hh;
      al[i] = (_Float16)((wv8[i] - (float)hh) * 2048.f);
    }
    const char* Xb = (const char*)&xlds[cur][0][0];
#pragma unroll
    for (int nt = 0; nt < 4; ++nt) {
      int rb = (nt * 16 + lq) * 128;
      hfx8 bh = *(const hfx8*)(Xb + rb + xh0);
      hfx8 bl = *(const hfx8*)(Xb + rb + xl0);
      ahi[nt] = __builtin_amdgcn_mfma_f32_16x16x32_f16(ah, bh, ahi[nt], 0, 0, 0);
      alo[nt] = __builtin_amdgcn_mfma_f32_16x16x32_f16(al, bh, alo[nt], 0, 0, 0);
      alo[nt] = __builtin_amdgcn_mfma_f32_16x16x32_f16(ah, bl, alo[nt], 0, 0, 0);
    }
    __builtin_amdgcn_sched_barrier(0);
    if (s < nsteps - 1) {
      *(uint4*)((char*)&xlds[cur ^ 1][0][0] + wbh) = nh;
      *(uint4*)((char*)&xlds[cur ^ 1][0][0] + wbl) = nl;
      w0c = nw0;
      w1c = nw1;
    }
  }
  float* yb = Y + ((size_t)b * O + o0) * N + n0;
#pragma unroll
  for (int nt = 0; nt < 4; ++nt)
#pragma unroll
    for (int r = 0; r < 4; ++r)
      yb[(size_t)(lg * 4 + r) * N + nt * 16 + lq] = ahi[nt][r] + alo[nt][r] * (1.f / 2048.f);
}

// ------- fused GEMM + head-fold + L2-norm + multi-format emit ---------------
template <int PATH>
__global__ __launch_bounds__(256) void gemmfold_k(
    const float* __restrict__ W, const unsigned short* __restrict__ Xh,
    const unsigned short* __restrict__ Xl, float* __restrict__ fq,
    unsigned short* __restrict__ sh, unsigned short* __restrict__ sl,
    unsigned short* __restrict__ b16, float* __restrict__ fv,
    int C, int N) {
  __shared__ __align__(16) unsigned short xlds[2][64][64];  // [buf][row][hi32|lo32]
  __shared__ float ftile[64][65];
  __shared__ float part[4][64];
  __shared__ float invArr[64];
  int t = threadIdx.x, lane = t & 63, wv = t >> 6;
  int lq = lane & 15, lg = lane >> 4;
  int n0 = blockIdx.x * 64, o0 = blockIdx.y * 64 + wv * 16;
  int b = blockIdx.z;
  bool isV = (PATH == 1) && (blockIdx.y >= 8);
  int h = (PATH == 1) ? (blockIdx.y & 7) : blockIdx.y;
  const unsigned short* xbh = Xh + ((size_t)b * N + n0) * C;
  const unsigned short* xbl = Xl + ((size_t)b * N + n0) * C;
  const float* wr = W + (size_t)(o0 + lq) * C;

  int a = t * 16;
  int srow = a >> 6;
  int schunk = (a >> 4) & 3;
  const unsigned short* gsh = xbh + (size_t)srow * C + schunk * 8;
  const unsigned short* gsl = xbl + (size_t)srow * C + schunk * 8;
  int swz = (srow & 7) << 4;
  int wbh = srow * 128 + ((schunk * 16) ^ swz);
  int wbl = srow * 128 + ((64 + schunk * 16) ^ swz);
  int rswz = (lq & 7) << 4;
  int xh0 = (lg * 16) ^ rswz;
  int xl0 = (64 + lg * 16) ^ rswz;

  fx4 ahi[4], alo[4];
  for (int nt = 0; nt < 4; ++nt) {
    ahi[nt] = (fx4){0.f, 0.f, 0.f, 0.f};
    alo[nt] = (fx4){0.f, 0.f, 0.f, 0.f};
  }

  {
    uint4 h0 = *(const uint4*)(gsh);
    uint4 l0 = *(const uint4*)(gsl);
    *(uint4*)((char*)&xlds[0][0][0] + wbh) = h0;
    *(uint4*)((char*)&xlds[0][0][0] + wbl) = l0;
  }
  float4 w0c = *(const float4*)(wr + lg * 8);
  float4 w1c = *(const float4*)(wr + lg * 8 + 4);

  for (int s = 0; s < 8; ++s) {
    int cur = s & 1;
    __syncthreads();
    uint4 nh, nl;
    float4 nw0, nw1;
    if (s < 7) {
      nh = *(const uint4*)(gsh + (s + 1) * 32);
      nl = *(const uint4*)(gsl + (s + 1) * 32);
      nw0 = *(const float4*)(wr + (s + 1) * 32 + lg * 8);
      nw1 = *(const float4*)(wr + (s + 1) * 32 + lg * 8 + 4);
    }
    __builtin_amdgcn_sched_barrier(0);
    float wv8[8] = {w0c.x, w0c.y, w0c.z, w0c.w, w1c.x, w1c.y, w1c.z, w1c.w};
    hfx8 ah, al;
#pragma unroll
    for (int i = 0; i < 8; ++i) {
      _Float16 hh = (_Float16)wv8[i];
      ah[i] = hh;
      al[i] = (_Float16)((wv8[i] - (float)hh) * 2048.f);
    }
    const char* Xb = (const char*)&xlds[cur][0][0];
#pragma unroll
    for (int nt = 0; nt < 4; ++nt) {
      int rb = (nt * 16 + lq) * 128;
      hfx8 bh = *(const hfx8*)(Xb + rb + xh0);
      hfx8 bl = *(const hfx8*)(Xb + rb + xl0);
      ahi[nt] = __builtin_amdgcn_mfma_f32_16x16x32_f16(ah, bh, ahi[nt], 0, 0, 0);
      alo[nt] = __builtin_amdgcn_mfma_f32_16x16x32_f16(al, bh, alo[nt], 0, 0, 0);
      alo[nt] = __builtin_amdgcn_mfma_f32_16x16x32_f16(ah, bl, alo[nt], 0, 0, 0);
    }
    __builtin_amdgcn_sched_barrier(0);
    if (s < 7) {
      *(uint4*)((char*)&xlds[cur ^ 1][0][0] + wbh) = nh;
      *(uint4*)((char*)&xlds[cur ^ 1][0][0] + wbl) = nl;
      w0c = nw0;
      w1c = nw1;
    }
  }

  float val[4][4];
#pragma unroll
  for (int nt = 0; nt < 4; ++nt)
#pragma unroll
    for (int r = 0; r < 4; ++r)
      val[nt][r] = ahi[nt][r] + alo[nt][r] * (1.f / 2048.f);
  __syncthreads();
  if (!isV) {
#pragma unroll
    for (int nt = 0; nt < 4; ++nt) {
      float ss = val[nt][0] * val[nt][0] + val[nt][1] * val[nt][1] +
                 val[nt][2] * val[nt][2] + val[nt][3] * val[nt][3];
      ss += __shfl_xor(ss, 16);
      ss += __shfl_xor(ss, 32);
      if (lg == 0) part[wv][nt * 16 + lq] = ss;
    }
    __syncthreads();
    if (t < 64) {
      float tot = part[0][t] + part[1][t] + part[2][t] + part[3][t];
      invArr[t] = 1.f / fmaxf(sqrtf(tot), 1e-12f);
    }
    __syncthreads();
#pragma unroll
    for (int nt = 0; nt < 4; ++nt) {
      float iv = invArr[nt * 16 + lq];
#pragma unroll
      for (int r = 0; r < 4; ++r) val[nt][r] *= iv;
    }
    __syncthreads();
  }
#pragma unroll
  for (int nt = 0; nt < 4; ++nt)
#pragma unroll
    for (int r = 0; r < 4; ++r)
      ftile[nt * 16 + lq][wv * 16 + lg * 4 + r] = val[nt][r];
  __syncthreads();
  size_t rowb = (size_t)(b * 8 + h) * N + n0;
  for (int r2 = 0; r2 < 16; ++r2) {
    int n = r2 * 4 + wv;
    float v = ftile[n][lane];
    size_t idx = (rowb + n) * 64 + lane;
    if (PATH == 1 && isV) {
      fv[idx] = v;
    } else {
      fq[idx] = v;
      unsigned short hb = f2h_bits(v);
      sh[idx] = hb;
      sl[idx] = f2h_bits((v - h_bits2f(hb)) * 2048.f);
      if (PATH == 0) b16[idx] = hb;  // f16 copy for attention
    }
  }
}

// ---------------- centroid prep (initial only): csq, -2c split f16 -----------
__global__ void centprep_k(const float* __restrict__ cent, float* __restrict__ csq,
                           unsigned short* __restrict__ cb2h, unsigned short* __restrict__ cb2l) {
  int j = blockIdx.x, lane = threadIdx.x;  // blockDim = 64
  float c = cent[j * 64 + lane];
  float s = c * c;
  for (int off = 32; off; off >>= 1) s += __shfl_xor(s, off);
  if (lane == 0) csq[j] = s;
  float m2 = -2.f * c;
  unsigned short h = f2h_bits(m2);
  cb2h[j * 64 + lane] = h;
  cb2l[j * 64 + lane] = f2h_bits((m2 - h_bits2f(h)) * 2048.f);
}

// ---------------- MFMA nearest-centroid assign (f16 split, LDS-staged) -------
// Deferred-compare pipeline: iteration i's (chi,clo) results are compared
// during iteration i+2's MFMA issue (register-resident, independent) so the
// VALU compare burst overlaps the matrix pipe. Arithmetic and compare ORDER
// are unchanged vs R17 (bit-exact assignments).
template <int DUO>
__global__ __launch_bounds__(256) void assign_mfma_k(
    const unsigned short* __restrict__ xh, const unsigned short* __restrict__ xl,
    const unsigned short* __restrict__ cb2h, const unsigned short* __restrict__ cb2l,
    const float* __restrict__ csq, int* __restrict__ aout) {
  __shared__ __align__(16) unsigned short clds[4][2][1024];  // [buf][hi/lo][16x64]
  int t = threadIdx.x, lane = t & 63, wv = t >> 6;
  int lq = lane & 15, lg = lane >> 4;
  int p0 = blockIdx.x * (DUO ? 128 : 64) + wv * (DUO ? 32 : 16);
  const unsigned short* xbA = xh + (size_t)(p0 + lq) * 64;
  const unsigned short* xlA = xl + (size_t)(p0 + lq) * 64;
  hfx8 ba0 = *(const hfx8*)(xbA + lg * 8);
  hfx8 ba1 = *(const hfx8*)(xbA + 32 + lg * 8);
  hfx8 la0 = *(const hfx8*)(xlA + lg * 8);
  hfx8 la1 = *(const hfx8*)(xlA + 32 + lg * 8);
  hfx8 bb0, bb1, lb0, lb1;
  if (DUO) {
    const unsigned short* xbB = xh + (size_t)(p0 + 16 + lq) * 64;
    const unsigned short* xlB = xl + (size_t)(p0 + 16 + lq) * 64;
    bb0 = *(const hfx8*)(xbB + lg * 8);
    bb1 = *(const hfx8*)(xbB + 32 + lg * 8);
    lb0 = *(const hfx8*)(xlB + lg * 8);
    lb1 = *(const hfx8*)(xlB + 32 + lg * 8);
  }

  int part = t >> 7;
  int abyte = (t & 127) * 16;
  int wbyte = abyte ^ (((abyte >> 7) & 7) << 4);
  const unsigned short* gsrc = (part ? cb2l : cb2h) + (abyte >> 1);
  int rowoff = lq * 128;
  int x0 = (lg * 16) ^ ((lq & 7) << 4);
  int x1 = (64 + lg * 16) ^ ((lq & 7) << 4);

  float bestA = 3.4e38f, bestB = 3.4e38f;
  int jA = 0, jB = 0;

  // carried (prev-iteration) results: [u][group]
  fx4 pchi0A, pclo0A, pchi1A, pclo1A;
  fx4 pchi0B, pclo0B, pchi1B, pclo1B;

  // prologue: stage subtiles 0 and 1
  {
    uint4 r0 = *(const uint4*)(gsrc);
    uint4 r1 = *(const uint4*)(gsrc + 1024);
    *(uint4*)((char*)&clds[0][part][0] + wbyte) = r0;
    *(uint4*)((char*)&clds[1][part][0] + wbyte) = r1;
  }

#define COMPARE_PREV(SBASE)                                                    \
  {                                                                            \
    _Pragma("unroll")                                                          \
    for (int u = 0; u < 2; ++u) {                                              \
      int st_ = (SBASE) + u;                                                   \
      fx4 chi_ = u ? pchi1A : pchi0A;                                          \
      fx4 clo_ = u ? pclo1A : pclo0A;                                          \
      _Pragma("unroll")                                                        \
      for (int r_ = 0; r_ < 4; ++r_) {                                         \
        int j_ = st_ * 16 + lg * 4 + r_;                                       \
        float d2_ = chi_[r_] + clo_[r_] * (1.f / 2048.f);                      \
        if (d2_ < bestA) { bestA = d2_; jA = j_; }                             \
      }                                                                        \
      if (DUO) {                                                               \
        fx4 chiB_ = u ? pchi1B : pchi0B;                                       \
        fx4 cloB_ = u ? pclo1B : pclo0B;                                       \
        _Pragma("unroll")                                                      \
        for (int r_ = 0; r_ < 4; ++r_) {                                       \
          int j_ = st_ * 16 + lg * 4 + r_;                                     \
          float d2_ = chiB_[r_] + cloB_[r_] * (1.f / 2048.f);                  \
          if (d2_ < bestB) { bestB = d2_; jB = j_; }                           \
        }                                                                      \
      }                                                                        \
    }                                                                          \
  }

  for (int s = 0; s < 64; s += 2) {
    __syncthreads();
    uint4 rn0, rn1;
    if (s < 62) {
      rn0 = *(const uint4*)(gsrc + (size_t)(s + 2) * 1024);
      rn1 = *(const uint4*)(gsrc + (size_t)(s + 3) * 1024);
    }
    __builtin_amdgcn_sched_barrier(0);
    fx4 cchi0A, cclo0A, cchi1A, cclo1A;
    fx4 cchi0B, cclo0B, cchi1B, cclo1B;
#pragma unroll
    for (int u = 0; u < 2; ++u) {
      int st = s + u;
      const char* ph = (const char*)&clds[st & 3][0][0];
      const char* pl = (const char*)&clds[st & 3][1][0];
      hfx8 ah0 = *(const hfx8*)(ph + rowoff + x0);
      hfx8 ah1 = *(const hfx8*)(ph + rowoff + x1);
      hfx8 al0 = *(const hfx8*)(pl + rowoff + x0);
      hfx8 al1 = *(const hfx8*)(pl + rowoff + x1);
      fx4 cq = *(const fx4*)(csq + st * 16 + lg * 4);
      {
        fx4 chi = cq;
        chi = __builtin_amdgcn_mfma_f32_16x16x32_f16(ah0, ba0, chi, 0, 0, 0);
        chi = __builtin_amdgcn_mfma_f32_16x16x32_f16(ah1, ba1, chi, 0, 0, 0);
        fx4 clo = (fx4){0.f, 0.f, 0.f, 0.f};
        clo = __builtin_amdgcn_mfma_f32_16x16x32_f16(ah0, la0, clo, 0, 0, 0);
        clo = __builtin_amdgcn_mfma_f32_16x16x32_f16(ah1, la1, clo, 0, 0, 0);
        clo = __builtin_amdgcn_mfma_f32_16x16x32_f16(al0, ba0, clo, 0, 0, 0);
        clo = __builtin_amdgcn_mfma_f32_16x16x32_f16(al1, ba1, clo, 0, 0, 0);
        if (u == 0) { cchi0A = chi; cclo0A = clo; } else { cchi1A = chi; cclo1A = clo; }
      }
      if (DUO) {
        fx4 chi = cq;
        chi = __builtin_amdgcn_mfma_f32_16x16x32_f16(ah0, bb0, chi, 0, 0, 0);
        chi = __builtin_amdgcn_mfma_f32_16x16x32_f16(ah1, bb1, chi, 0, 0, 0);
        fx4 clo = (fx4){0.f, 0.f, 0.f, 0.f};
        clo = __builtin_amdgcn_mfma_f32_16x16x32_f16(ah0, lb0, clo, 0, 0, 0);
        clo = __builtin_amdgcn_mfma_f32_16x16x32_f16(ah1, lb1, clo, 0, 0, 0);
        clo = __builtin_amdgcn_mfma_f32_16x16x32_f16(al0, lb0 * (_Float16)0 + bb0, clo, 0, 0, 0);
        clo = __builtin_amdgcn_mfma_f32_16x16x32_f16(al1, bb1, clo, 0, 0, 0);
        if (u == 0) { cchi0B = chi; cclo0B = clo; } else { cchi1B = chi; cclo1B = clo; }
      }
    }
    // deferred compares of PREVIOUS iteration (independent of the MFMAs above)
    if (s > 0) COMPARE_PREV(s - 2);
    // carry current -> prev
    pchi0A = cchi0A; pclo0A = cclo0A; pchi1A = cchi1A; pclo1A = cclo1A;
    if (DUO) { pchi0B = cchi0B; pclo0B = cclo0B; pchi1B = cchi1B; pclo1B = cclo1B; }
    __builtin_amdgcn_sched_barrier(0);
    if (s < 62) {
      *(uint4*)((char*)&clds[(s + 2) & 3][part][0] + wbyte) = rn0;
      *(uint4*)((char*)&clds[(s + 3) & 3][part][0] + wbyte) = rn1;
    }
  }
  // epilogue: compares for the final iteration (subtiles 62,63)
  COMPARE_PREV(62);
#undef COMPARE_PREV

  {
    float o = __shfl_xor(bestA, 16);
    int oj = __shfl_xor(jA, 16);
    if (o < bestA || (o == bestA && oj < jA)) { bestA = o; jA = oj; }
    o = __shfl_xor(bestA, 32);
    oj = __shfl_xor(jA, 32);
    if (o < bestA || (o == bestA && oj < jA)) { bestA = o; jA = oj; }
  }
  if (DUO) {
    float o = __shfl_xor(bestB, 16);
    int oj = __shfl_xor(jB, 16);
    if (o < bestB || (o == bestB && oj < jB)) { bestB = o; jB = oj; }
    o = __shfl_xor(bestB, 32);
    oj = __shfl_xor(jB, 32);
    if (o < bestB || (o == bestB && oj < jB)) { bestB = o; jB = oj; }
  }
  if (lg == 0) {
    aout[p0 + lq] = jA;
    if (DUO) aout[p0 + 16 + lq] = jB;
  }
}

// ---------------- exact f32 L1 distance to assigned centroid -----------------
__global__ void dist_k(const float* __restrict__ x, const float* __restrict__ cent,
                       const int* __restrict__ asg, float* __restrict__ dout) {
  int t = threadIdx.x, lane = t & 63, wv = t >> 6;
  int p = blockIdx.x * 4 + wv;
  int a = asg[p];
  float v = fabsf(cent[(size_t)a * 64 + lane] - x[(size_t)p * 64 + lane]);
  for (int off = 32; off; off >>= 1) v += __shfl_xor(v, off);
  if (lane == 0) dout[p] = v;
}

// ---------------- segment sum via atomics (wave=point: coalesced) ------------
__global__ void segsum_k(const float* __restrict__ x, const int* __restrict__ asg,
                         float* __restrict__ sums, float* __restrict__ cnt) {
  int t = threadIdx.x, lane = t & 63, wv = t >> 6;
  int p = blockIdx.x * 4 + wv;
  int a = asg[p];
  float v = x[(size_t)p * 64 + lane];
  atomicAdd(&sums[a * 64 + lane], v);
  if (lane == 0) atomicAdd(&cnt[a], 1.0f);
}

// ---------------- centroid update + prep + zero (fused) ----------------------
__global__ __launch_bounds__(256) void centup_prep_k(
    float* __restrict__ cent, float* __restrict__ sums, float* __restrict__ cnt,
    float* __restrict__ csq, unsigned short* __restrict__ cb2h,
    unsigned short* __restrict__ cb2l) {
  int i = blockIdx.x * 256 + threadIdx.x;  // 65536 total; rows never span blocks
  int j = i >> 6, lane = threadIdx.x & 63;
  float c = cnt[j];
  float oldc = cent[i];
  float newc = (c > 0.f) ? sums[i] / fmaxf(c, 1.f) : oldc;
  cent[i] = newc;
  float s = newc * newc;
  for (int off = 32; off; off >>= 1) s += __shfl_xor(s, off);
  if (lane == 0) csq[j] = s;
  float m2 = -2.f * newc;
  unsigned short h = f2h_bits(m2);
  cb2h[i] = h;
  cb2l[i] = f2h_bits((m2 - h_bits2f(h)) * 2048.f);
  sums[i] = 0.f;
  if (lane == 0) cnt[j] = 0.f;
}

// ---------------- per-bh top-1024 by descending dist (stable ties) -----------
__global__ __launch_bounds__(1024) void topk_k(const float* __restrict__ dist,
                                               int* __restrict__ sel) {
  __shared__ unsigned long long keys[2048];
  int bh = blockIdx.x, t = threadIdx.x;
  for (int i = t; i < 2048; i += 1024) {
    float d = dist[bh * 2048 + i];
    unsigned int db = __float_as_uint(d);  // d >= 0 -> monotonic
    keys[i] = ((unsigned long long)db << 32) | (unsigned int)(2047 - i);
  }
  __syncthreads();
  for (int k = 2; k <= 2048; k <<= 1) {
    for (int j = k >> 1; j > 0; j >>= 1) {
      for (int i = t; i < 2048; i += 1024) {
        int ixj = i ^ j;
        if (ixj > i) {
          unsigned long long a = keys[i], b = keys[ixj];
          bool up = ((i & k) == 0);
          bool sw = up ? (a < b) : (a > b);  // descending overall
          if (sw) { keys[i] = b; keys[ixj] = a; }
        }
      }
      __syncthreads();
    }
  }
  if (t < 1024) sel[bh * 1024 + t] = 2047 - (int)(keys[t] & 0xffffffffu);
}

// ---------------- gather selected rows -> kh (f16 row-major), vT (f16 d-major)
__global__ void gatherb_k(const float* __restrict__ kbuf, const float* __restrict__ vbuf,
                          const int* __restrict__ sel, unsigned short* __restrict__ kh,
                          unsigned short* __restrict__ vT) {
  __shared__ unsigned short tile[64][66];
  int t = threadIdx.x, lane = t & 63, wv = t >> 6;
  int bh = blockIdx.y, i0 = blockIdx.x * 64;
  for (int r = 0; r < 16; ++r) {
    int i = r * 4 + wv;
    int src = sel[bh * 1024 + i0 + i];
    float kvv = kbuf[((size_t)bh * 2048 + src) * 64 + lane];
    kh[((size_t)bh * 1024 + i0 + i) * 64 + lane] = f2h_bits(kvv);
    float vv = vbuf[((size_t)bh * 2048 + src) * 64 + lane];
    tile[i][lane] = f2h_bits(vv);
  }
  __syncthreads();
  for (int r = 0; r < 16; ++r) {
    int d = r * 4 + wv;
    vT[((size_t)bh * 64 + d) * 1024 + i0 + lane] = tile[lane][d];
  }
}

// ---------------- MFMA flash attention (f16, K/V LDS-staged, XCD-mapped) -----
__global__ __launch_bounds__(256) void attn_mfma_k(
    const unsigned short* __restrict__ qh, const unsigned short* __restrict__ kh,
    const unsigned short* __restrict__ vT,
    unsigned short* __restrict__ oh, unsigned short* __restrict__ ol) {
  __shared__ __align__(16) unsigned short kvlds[2][2][4096];  // [buf][K/V][64x64]
  __shared__ __align__(16) unsigned short plds[4][16][72];
  int t = threadIdx.x, lane = t & 63, wv = t >> 6;
  int lq = lane & 15, lg = lane >> 4;
  int id = blockIdx.x;
  int bh = (id & 7) * 2 + ((id >> 3) & 1);
  int q0 = (id >> 4) * 64 + wv * 16;
  const unsigned short* qbase = qh + ((size_t)bh * 4096 + q0 + lq) * 64;
  hfx8 qf0 = *(const hfx8*)(qbase + lg * 8);
  hfx8 qf1 = *(const hfx8*)(qbase + 32 + lg * 8);
  fx4 acc[4];
  for (int nt = 0; nt < 4; ++nt) acc[nt] = (fx4){0.f, 0.f, 0.f, 0.f};
  float lsum = 0.f;
  const unsigned short* kbase = kh + (size_t)bh * 1024 * 64;
  const unsigned short* vbase = vT + (size_t)bh * 64 * 1024;

  int srow = t >> 2;
  int scolb = (t & 3) * 32;
  const char* gK = (const char*)kbase + (size_t)srow * 128 + scolb;   // + s*8192
  const char* gV = (const char*)vbase + (size_t)srow * 2048 + scolb;  // + s*128
  int sw_w = (srow & 7) << 4;
  int wb0 = srow * 128 + (scolb ^ sw_w);
  int wb1 = srow * 128 + ((scolb + 16) ^ sw_w);

  {
    uint4 k0 = *(const uint4*)(gK);
    uint4 k1 = *(const uint4*)(gK + 16);
    uint4 v0 = *(const uint4*)(gV);
    uint4 v1 = *(const uint4*)(gV + 16);
    *(uint4*)((char*)&kvlds[0][0][0] + wb0) = k0;
    *(uint4*)((char*)&kvlds[0][0][0] + wb1) = k1;
    *(uint4*)((char*)&kvlds[0][1][0] + wb0) = v0;
    *(uint4*)((char*)&kvlds[0][1][0] + wb1) = v1;
  }

  int swr = (lq & 7) << 4;
  int rc0 = (lg * 16) ^ swr;
  int rc1 = (64 + lg * 16) ^ swr;

  for (int s = 0; s < 16; ++s) {
    int cur = s & 1;
    __syncthreads();
    uint4 nk0, nk1, nv0, nv1;
    if (s < 15) {
      const char* gKn = gK + (size_t)(s + 1) * 8192;
      const char* gVn = gV + (size_t)(s + 1) * 128;
      nk0 = *(const uint4*)(gKn);
      nk1 = *(const uint4*)(gKn + 16);
      nv0 = *(const uint4*)(gVn);
      nv1 = *(const uint4*)(gVn + 16);
    }
    __builtin_amdgcn_sched_barrier(0);
    const char* Kb = (const char*)&kvlds[cur][0][0];
    const char* Vb = (const char*)&kvlds[cur][1][0];
    fx4 sS[4];
#pragma unroll
    for (int mt = 0; mt < 4; ++mt) {
      int rowb = (mt * 16 + lq) * 128;
      hfx8 a0 = *(const hfx8*)(Kb + rowb + rc0);
      hfx8 a1 = *(const hfx8*)(Kb + rowb + rc1);
      fx4 c = (fx4){0.f, 0.f, 0.f, 0.f};
      c = __builtin_amdgcn_mfma_f32_16x16x32_f16(a0, qf0, c, 0, 0, 0);
      c = __builtin_amdgcn_mfma_f32_16x16x32_f16(a1, qf1, c, 0, 0, 0);
      sS[mt] = c;
    }
#pragma unroll
    for (int mt = 0; mt < 4; ++mt) {
      float p0 = __expf(sS[mt].x), p1 = __expf(sS[mt].y);
      float p2 = __expf(sS[mt].z), p3 = __expf(sS[mt].w);
      lsum += (p0 + p1) + (p2 + p3);
      fpx2 c01 = __builtin_amdgcn_cvt_pkrtz(p0, p1);
      fpx2 c23 = __builtin_amdgcn_cvt_pkrtz(p2, p3);
      unsigned u01, u23;
      __builtin_memcpy(&u01, &c01, 4);
      __builtin_memcpy(&u23, &c23, 4);
      uint2 pk = {u01, u23};
      *(uint2*)&plds[wv][lq][mt * 16 + lg * 4] = pk;
    }
    hfx8 pa0 = *(const hfx8*)&plds[wv][lq][lg * 8];
    hfx8 pa1 = *(const hfx8*)&plds[wv][lq][32 + lg * 8];
#pragma unroll
    for (int nt = 0; nt < 4; ++nt) {
      int rowb = (nt * 16 + lq) * 128;
      hfx8 b0 = *(const hfx8*)(Vb + rowb + rc0);
      hfx8 b1 = *(const hfx8*)(Vb + rowb + rc1);
      acc[nt] = __builtin_amdgcn_mfma_f32_16x16x32_f16(pa0, b0, acc[nt], 0, 0, 0);
      acc[nt] = __builtin_amdgcn_mfma_f32_16x16x32_f16(pa1, b1, acc[nt], 0, 0, 0);
    }
    __builtin_amdgcn_sched_barrier(0);
    if (s < 15) {
      char* dK = (char*)&kvlds[cur ^ 1][0][0];
      char* dV = (char*)&kvlds[cur ^ 1][1][0];
      *(uint4*)(dK + wb0) = nk0;
      *(uint4*)(dK + wb1) = nk1;
      *(uint4*)(dV + wb0) = nv0;
      *(uint4*)(dV + wb1) = nv1;
    }
  }
  lsum += __shfl_xor(lsum, 16);
  lsum += __shfl_xor(lsum, 32);
  int bi = bh >> 3, hd = bh & 7;
  for (int r = 0; r < 4; ++r) {
    float inv = 1.f / __shfl(lsum, lg * 4 + r);
    size_t rowb = ((size_t)bi * 4096 + q0 + lg * 4 + r) * 512 + hd * 64;
    for (int nt = 0; nt < 4; ++nt) {
      float val = acc[nt][r] * inv;
      unsigned short hb = f2h_bits(val);
      oh[rowb + nt * 16 + lq] = hb;
      ol[rowb + nt * 16 + lq] = f2h_bits((val - h_bits2f(hb)) * 2048.f);
    }
  }
}

// ---------------- final LN + gamma*ln + residual (wave-split channels) -------
__global__ __launch_bounds__(256) void final_k(
    const float* __restrict__ y, const float* __restrict__ g,
    const float* __restrict__ bta, const float* __restrict__ gamma,
    const float* __restrict__ qs, float* __restrict__ out) {
  __shared__ float p1[4][64], p2[4][64];
  __shared__ float mArr[64], invArr[64];
  int t = threadIdx.x, lane = t & 63, wv = t >> 6;
  int n0 = blockIdx.x * 64, bi = blockIdx.y;
  const float* yb = y + (size_t)bi * CDIM * NQ + n0 + lane;
  float s = 0.f, s2 = 0.f;
  for (int cl = 0; cl < 64; ++cl) {
    float v = yb[(size_t)(wv * 64 + cl) * NQ];
    s += v;
    s2 += v * v;
  }
  p1[wv][lane] = s;
  p2[wv][lane] = s2;
  __syncthreads();
  if (t < 64) {
    float ts = p1[0][t] + p1[1][t] + p1[2][t] + p1[3][t];
    float ts2 = p2[0][t] + p2[1][t] + p2[2][t] + p2[3][t];
    float m = ts / CDIM;
    float var = ts2 / CDIM - m * m;
    mArr[t] = m;
    invArr[t] = 1.f / (sqrtf(fmaxf(var, 0.f)) + 1e-6f);
  }
  __syncthreads();
  float gm = gamma[0];
  float m = mArr[lane], inv = invArr[lane];
  const float* qb = qs + (size_t)bi * CDIM * NQ + n0 + lane;
  float* ob = out + (size_t)bi * CDIM * NQ + n0 + lane;
  for (int cl = 0; cl < 64; ++cl) {
    int c = wv * 64 + cl;
    float v = yb[(size_t)c * NQ];
    float ln = g[c] * (v - m) * inv + bta[c];
    ob[(size_t)c * NQ] = gm * ln + qb[(size_t)c * NQ];
  }
}

extern "C" void kernel_launch(void* const* d_in, const int* in_sizes, int n_in,
                              void* d_out, int out_size, void* d_ws, size_t ws_size,
                              hipStream_t stream) {
  const float* qsrc = (const float*)d_in[0];
  const float* ctx = (const float*)d_in[1];
  const float* w_q = (const float*)d_in[2];
  const float* w_kv = (const float*)d_in[3];
  const float* w_out = (const float*)d_in[4];
  const float* cn_g = (const float*)d_in[5];
  const float* cn_b = (const float*)d_in[6];
  const float* qn_g = (const float*)d_in[7];
  const float* qn_b = (const float*)d_in[8];
  const float* on_g = (const float*)d_in[9];
  const float* on_b = (const float*)d_in[10];
  const float* gamma = (const float*)d_in[11];

  // scratch layout (floats); total 22,267,904 floats = 89.1 MB
  if (ws_size < (size_t)22267904 * 4) return;
  float* ws = (float*)d_ws;
  float* r_ctx = ws;                      // 1,048,576 f: ctx split-f16; later kh/vT
  float* r_kv = r_ctx + 1048576;          // 4,194,304 f: kbh/kbl f16; later attnt split
  float* r_qs = r_kv + 4194304;           // 2,097,152 f: qs split-f16; later cb2h/l, ybuf
  float* r_q3 = r_qs + 2097152;           // 4,194,304 f: qbh/qbl f16
  float* qbuf = r_q3 + 4194304;           // 4,194,304 f
  float* kbuf = qbuf + 4194304;           // 2,097,152 f
  float* vbuf = kbuf + 2097152;           // 2,097,152 f
  float* cent = vbuf + 2097152;           // 65,536 f
  float* csq = cent + 65536;              // 1,024 f
  float* sums = csq + 1024;               // 65,536 f
  float* cnt = sums + 65536;              // 1,024 f
  int* asg = (int*)(cnt + 1024);          // 65,536 i
  float* dist = (float*)(asg + 65536);    // 32,768 f
  int* sel = (int*)(dist + 32768);        // 16,384 i
  float* kgreg = (float*)(sel + 16384);   // 2,097,152 f (qh f16)

  unsigned short* ctxth = (unsigned short*)r_ctx;   // [b][2048][256] f16 hi
  unsigned short* ctxtl = ctxth + (size_t)BB * NK * CDIM;  // lo
  unsigned short* qsth = (unsigned short*)r_qs;     // [b][4096][256] f16 hi
  unsigned short* qstl = qsth + (size_t)BB * NQ * CDIM;    // lo
  unsigned short* qh = (unsigned short*)kgreg;      // 4M f16
  unsigned short* kh = (unsigned short*)r_ctx;      // 1M f16 (ctx split dead)
  unsigned short* vT = kh + 1048576;                // 1M f16
  unsigned short* qbh = (unsigned short*)r_q3;      // 4M f16 (q split hi)
  unsigned short* qbl = qbh + (size_t)NPQ * 64;     // 4M f16 (lo)
  unsigned short* kbh = (unsigned short*)r_kv;      // 2M f16 (k split hi)
  unsigned short* kbl = kbh + (size_t)NPK * 64;     // 2M f16 (lo)
  unsigned short* cb2h = (unsigned short*)r_qs;     // 64K f16 (-2c hi)
  unsigned short* cb2l = cb2h + 65536;              // 64K f16 (lo)
  unsigned short* attnth = (unsigned short*)r_kv;   // [b][4096][512] f16 hi (kb split dead)
  unsigned short* attntl = attnth + (size_t)BB * NQ * 512;  // lo
  float* ybuf = r_qs;                     // [b][256][4096] f32 (cb2 dead)

  // 1. channel LayerNorms -> transposed split-f16
  chan_ln_tsplit_k<<<dim3(NK / 64, BB), 256, 0, stream>>>(ctx, cn_g, cn_b, ctxth, ctxtl, CDIM, NK);
  chan_ln_tsplit_k<<<dim3(NQ / 64, BB), 256, 0, stream>>>(qsrc, qn_g, qn_b, qsth, qstl, CDIM, NQ);
  // 2. fused MFMA projections + fold + L2-norm + format emit (LDS-pipelined)
  gemmfold_k<1><<<dim3(NK / 64, 16, BB), 256, 0, stream>>>(
      w_kv, ctxth, ctxtl, kbuf, kbh, kbl, nullptr, vbuf, CDIM, NK);
  gemmfold_k<0><<<dim3(NQ / 64, 8, BB), 256, 0, stream>>>(
      w_q, qsth, qstl, qbuf, qbh, qbl, qh, nullptr, CDIM, NQ);
  // 3. k-means: initial prep + one memset; centup_prep fuses update/prep/zero
  hipMemcpyAsync(cent, qbuf, 65536 * sizeof(float), hipMemcpyDeviceToDevice, stream);
  centprep_k<<<1024, 64, 0, stream>>>(cent, csq, cb2h, cb2l);
  hipMemsetAsync(sums, 0, (65536 + 1024) * sizeof(float), stream);
  for (int it = 0; it < 4; ++it) {
    assign_mfma_k<1><<<NPQ / 128, 256, 0, stream>>>(qbh, qbl, cb2h, cb2l, csq, asg);
    segsum_k<<<NPQ / 4, 256, 0, stream>>>(qbuf, asg, sums, cnt);
    centup_prep_k<<<65536 / 256, 256, 0, stream>>>(cent, sums, cnt, csq, cb2h, cb2l);
  }
  // 4. score keys: argmin (MFMA) -> exact f32 L1 dist -> per-head top-1024
  assign_mfma_k<0><<<NPK / 64, 256, 0, stream>>>(kbh, kbl, cb2h, cb2l, csq, asg);
  dist_k<<<NPK / 4, 256, 0, stream>>>(kbuf, cent, asg, dist);
  topk_k<<<BH, 1024, 0, stream>>>(dist, sel);
  // 5. gather (kh row-major f16, vT transposed f16)
  gatherb_k<<<dim3(TOPK / 64, BH), 256, 0, stream>>>(kbuf, vbuf, sel, kh, vT);
  // 6. MFMA attention (f16, XCD-mapped) -> split-f16 un-folded [b][n][512]
  attn_mfma_k<<<1024, 256, 0, stream>>>(qh, kh, vT, attnth, attntl);
  // 7. output projection (MFMA, LDS-staged)
  gemm_mfma_k<<<dim3(NQ / 64, 256 / 64, BB), 256, 0, stream>>>(w_out, attnth, attntl, ybuf, 256, 512, NQ);
  // 8. final LN + residual
  final_k<<<dim3(NQ / 64, BB), 256, 0, stream>>>(ybuf, on_g, on_b, gamma, qsrc, (float*)d_out);
}